// Round 2
// 768.967 us; speedup vs baseline: 1.0339x; 1.0339x over previous
//
#include <hip/hip_runtime.h>
#include <hip/hip_fp16.h>

#define N_NODES 65536
#define N_EDGES 2097152
#define NB      1024
#define FXD     78
#define DIM     32
#define EMBD    128
#define OUTD    128
#define VOCAB   26
#define PLEN    1000
#define KS      8
#define CLEN    121      // EMBD-KS+1
#define NF      32
#define FCX     (NF*CLEN)  // 3872
#define NBKT    256
#define EPB     8192     // edges per bucketA block (N_EDGES/256)
#define NSLICE  256      // stats partial slices
#define EROW2   156      // emb row stride (floats): f(t)=t+4*(t>>4), f(127)=155
#define ECHUNK  13       // emb rows staged per chunk (2 chunks x 13 = 26)

// ---------------- bucket sort (dst>>8) ----------------

__global__ __launch_bounds__(256) void k_bhist(
    const int* __restrict__ ei, int* __restrict__ bktCnt)
{
    __shared__ int h[NBKT];
    int tid = threadIdx.x;
    h[tid] = 0;
    __syncthreads();
    int base = blockIdx.x*1024;
    #pragma unroll
    for (int q=0; q<4; ++q) {
        int d = ei[N_EDGES + base + q*256 + tid];
        atomicAdd(&h[d>>8], 1);
    }
    __syncthreads();
    atomicAdd(&bktCnt[tid], h[tid]);
}

__global__ __launch_bounds__(256) void k_bscan(
    const int* __restrict__ bktCnt, int* __restrict__ bktBase, int* __restrict__ bktCur)
{
    __shared__ int s[NBKT];
    int t = threadIdx.x;
    int v = bktCnt[t];
    s[t] = v;
    __syncthreads();
    for (int off=1; off<256; off<<=1) {
        int tv = (t >= off) ? s[t-off] : 0;
        __syncthreads();
        s[t] += tv;
        __syncthreads();
    }
    int ex = s[t] - v;
    bktBase[t] = ex;
    bktCur[t] = ex;
    if (t == 255) bktBase[256] = s[255];   // == N_EDGES
}

// LDS-sort 8192 edges by bucket, write packed (dst<<16|src) in coalesced runs
__global__ __launch_bounds__(256) void k_bucketA(
    const int* __restrict__ ei, int* __restrict__ bktCur, unsigned int* __restrict__ pairs)
{
    __shared__ unsigned int raw[EPB];       // 32 KB
    __shared__ unsigned int srt[EPB];       // 32 KB
    __shared__ unsigned char bOf[EPB];      // 8 KB
    __shared__ int hist[NBKT], sc[NBKT], lcur[NBKT], gbase[NBKT];
    int tid = threadIdx.x;
    hist[tid] = 0;
    __syncthreads();
    int eb = blockIdx.x * EPB;
    for (int i=tid; i<EPB; i+=256) {
        int s = ei[eb+i];
        int d = ei[N_EDGES+eb+i];
        raw[i] = ((unsigned int)d<<16) | (unsigned int)s;
        atomicAdd(&hist[d>>8], 1);
    }
    __syncthreads();
    int v = hist[tid];
    sc[tid] = v;
    __syncthreads();
    for (int off=1; off<256; off<<=1) {
        int tv = (tid >= off) ? sc[tid-off] : 0;
        __syncthreads();
        sc[tid] += tv;
        __syncthreads();
    }
    int ex = sc[tid] - v;
    sc[tid] = ex;            // exclusive local base
    lcur[tid] = ex;
    gbase[tid] = atomicAdd(&bktCur[tid], v);
    __syncthreads();
    for (int i=tid; i<EPB; i+=256) {
        unsigned int p = raw[i];
        int k = p >> 24;
        int pos = atomicAdd(&lcur[k], 1);
        srt[pos] = p;
        bOf[pos] = (unsigned char)k;
    }
    __syncthreads();
    for (int i=tid; i<EPB; i+=256) {
        int k = bOf[i];
        pairs[gbase[k] + (i - sc[k])] = srt[i];
    }
}

// per bucket: build rowptr (LDS histogram + scan) and scatter srcs into the
// bucket's contiguous CSR segment.
__global__ __launch_bounds__(256) void k_fillB(
    const int* __restrict__ bktBase, const unsigned int* __restrict__ pairs,
    int* __restrict__ rowptr, int* __restrict__ csr)
{
    __shared__ int hist[256], sc[256], cur[256];
    int b = blockIdx.x, tid = threadIdx.x;
    int node0 = b*256;
    hist[tid] = 0;
    __syncthreads();
    int s = bktBase[b], e = bktBase[b+1];
    for (int i = s + tid; i < e; i += 256)
        atomicAdd(&hist[(pairs[i] >> 16) & 255], 1);
    __syncthreads();
    int v = hist[tid];
    sc[tid] = v;
    __syncthreads();
    for (int off=1; off<256; off<<=1) {
        int tv = (tid >= off) ? sc[tid-off] : 0;
        __syncthreads();
        sc[tid] += tv;
        __syncthreads();
    }
    int base = s + sc[tid] - v;     // exclusive
    rowptr[node0 + tid] = base;
    cur[tid] = base;
    if (b == NBKT-1 && tid == 255) rowptr[N_NODES] = N_EDGES;
    __syncthreads();
    for (int i = s + tid; i < e; i += 256) {
        unsigned int p = pairs[i];
        int pos = atomicAdd(&cur[(p >> 16) & 255], 1);
        csr[pos] = (int)(p & 0xFFFFu);
    }
}

// ---------------- GIN layer kernels ----------------

// Layer-1 transform: t = x @ w1a  (fp16 out)
__global__ __launch_bounds__(256) void k_l1_transform(
    const float* __restrict__ x, const float* __restrict__ w,
    __half* __restrict__ t)
{
    __shared__ float wS[FXD*DIM];
    for (int i = threadIdx.x; i < FXD*DIM; i += 256) wS[i] = w[i];
    __syncthreads();
    int node = blockIdx.x*256 + threadIdx.x;
    float acc[DIM];
    #pragma unroll
    for (int d=0; d<DIM; ++d) acc[d] = 0.f;
    const float* xr = x + (long)node*FXD;
    for (int j=0; j<FXD; ++j) {
        float xv = xr[j];
        #pragma unroll
        for (int d=0; d<DIM; ++d) acc[d] += xv * wS[j*DIM+d];
    }
    union { __half2 h2[16]; uint4 u4[4]; } pk;
    #pragma unroll
    for (int q=0; q<16; ++q) pk.h2[q] = __floats2half2_rn(acc[2*q], acc[2*q+1]);
    uint4* dst4 = (uint4*)(t + (long)node*DIM);
    #pragma unroll
    for (int q=0; q<4; ++q) dst4[q] = pk.u4[q];
}

// Layers 2-5: h = BN(z) via scale/shift; t = h @ w  (fp16 out)
__global__ __launch_bounds__(256) void k_transform(
    const float* __restrict__ z, const float* __restrict__ ss,
    const float* __restrict__ w, __half* __restrict__ t)
{
    __shared__ float wS[DIM*DIM];
    __shared__ float sS[2*DIM];
    for (int i = threadIdx.x; i < DIM*DIM; i += 256) wS[i] = w[i];
    if (threadIdx.x < 2*DIM) sS[threadIdx.x] = ss[threadIdx.x];
    __syncthreads();
    int node = blockIdx.x*256 + threadIdx.x;
    float h[DIM];
    const float4* z4 = (const float4*)(z + (long)node*DIM);
    #pragma unroll
    for (int q=0; q<DIM/4; ++q) {
        float4 v = z4[q];
        h[q*4+0]=v.x; h[q*4+1]=v.y; h[q*4+2]=v.z; h[q*4+3]=v.w;
    }
    #pragma unroll
    for (int d=0; d<DIM; ++d) h[d] = h[d]*sS[d] + sS[DIM+d];
    float acc[DIM];
    #pragma unroll
    for (int d=0; d<DIM; ++d) acc[d] = 0.f;
    #pragma unroll
    for (int j=0; j<DIM; ++j) {
        float hv = h[j];
        #pragma unroll
        for (int d=0; d<DIM; ++d) acc[d] += hv * wS[j*DIM+d];
    }
    union { __half2 h2[16]; uint4 u4[4]; } pk;
    #pragma unroll
    for (int q=0; q<16; ++q) pk.h2[q] = __floats2half2_rn(acc[2*q], acc[2*q+1]);
    uint4* dst4 = (uint4*)(t + (long)node*DIM);
    #pragma unroll
    for (int q=0; q<4; ++q) dst4[q] = pk.u4[q];
}

// Gather (CSR) + self + MLP + ReLU + BN-stats partials.
__global__ __launch_bounds__(256) void k_gather_mlp(
    const int* __restrict__ rowptr, const int* __restrict__ csr,
    const __half* __restrict__ t,
    const float* __restrict__ bi, const float* __restrict__ wo, const float* __restrict__ bo,
    float* __restrict__ z, float* __restrict__ part)
{
    __shared__ float wS[DIM*DIM];
    __shared__ float bS[2*DIM];
    __shared__ float stS[2*DIM];
    int tid = threadIdx.x;
    for (int i=tid; i<DIM*DIM; i+=256) wS[i]=wo[i];
    if (tid<DIM) bS[tid]=bi[tid];
    else if (tid<2*DIM) bS[tid]=bo[tid-DIM];
    if (tid<2*DIM) stS[tid]=0.f;
    __syncthreads();
    int g = tid >> 3;           // node 0..31 within block
    int l = tid & 7;            // lane in group; owns channels 4l..4l+3
    int node = blockIdx.x*32 + g;
    const uint2* t4 = (const uint2*)t;   // 8B = 4 halfs; 8 entries per row
    uint2 sv = t4[(long)node*8 + l];     // self term
    float2 p0 = __half22float2(*(const __half2*)&sv.x);
    float2 p1 = __half22float2(*(const __half2*)&sv.y);
    float a0=p0.x, a1=p0.y, a2=p1.x, a3=p1.y;
    float c0=0.f, c1=0.f, c2=0.f, c3=0.f;
    int s0 = rowptr[node], s1 = rowptr[node+1];
    int e = s0;
    for (; e+8 <= s1; e+=8) {
        int myIdx = csr[e + l];          // 8 consecutive, coalesced
        #pragma unroll
        for (int k=0; k<8; ++k) {
            int idx = __shfl(myIdx, k, 8);
            uint2 v = t4[(long)idx*8 + l];
            float2 q0 = __half22float2(*(const __half2*)&v.x);
            float2 q1 = __half22float2(*(const __half2*)&v.y);
            if (k & 1) { c0+=q0.x; c1+=q0.y; c2+=q1.x; c3+=q1.y; }
            else       { a0+=q0.x; a1+=q0.y; a2+=q1.x; a3+=q1.y; }
        }
    }
    if (e+4 <= s1) {
        int myIdx = csr[e + (l & 3)];
        #pragma unroll
        for (int k=0; k<4; ++k) {
            int idx = __shfl(myIdx, k, 8);
            uint2 v = t4[(long)idx*8 + l];
            float2 q0 = __half22float2(*(const __half2*)&v.x);
            float2 q1 = __half22float2(*(const __half2*)&v.y);
            if (k & 1) { c0+=q0.x; c1+=q0.y; c2+=q1.x; c3+=q1.y; }
            else       { a0+=q0.x; a1+=q0.y; a2+=q1.x; a3+=q1.y; }
        }
        e += 4;
    }
    for (; e<s1; ++e) {
        uint2 v = t4[(long)csr[e]*8 + l];
        float2 q0 = __half22float2(*(const __half2*)&v.x);
        float2 q1 = __half22float2(*(const __half2*)&v.y);
        a0+=q0.x; a1+=q0.y; a2+=q1.x; a3+=q1.y;
    }
    float ua[4];
    ua[0] = fmaxf(a0+c0 + bS[4*l+0], 0.f);
    ua[1] = fmaxf(a1+c1 + bS[4*l+1], 0.f);
    ua[2] = fmaxf(a2+c2 + bS[4*l+2], 0.f);
    ua[3] = fmaxf(a3+c3 + bS[4*l+3], 0.f);
    float zz[4];
    #pragma unroll
    for (int q=0; q<4; ++q) zz[q] = bS[DIM + 4*l + q];
    const float4* w4 = (const float4*)wS;
    #pragma unroll
    for (int j=0; j<DIM; ++j) {
        float uj = __shfl(ua[j & 3], j >> 2, 8);
        float4 wv = w4[j*8 + l];
        zz[0]+=uj*wv.x; zz[1]+=uj*wv.y; zz[2]+=uj*wv.z; zz[3]+=uj*wv.w;
    }
    #pragma unroll
    for (int q=0; q<4; ++q) zz[q] = fmaxf(zz[q], 0.f);
    ((float4*)z)[(long)node*8 + l] = make_float4(zz[0], zz[1], zz[2], zz[3]);
    // stats: reduce the 8 node-groups of each wave down to 8 lanes
    float sr[4], qr[4];
    #pragma unroll
    for (int q=0; q<4; ++q) { sr[q] = zz[q]; qr[q] = zz[q]*zz[q]; }
    #pragma unroll
    for (int q=0; q<4; ++q) {
        sr[q] += __shfl_down(sr[q], 32, 64); qr[q] += __shfl_down(qr[q], 32, 64);
        sr[q] += __shfl_down(sr[q], 16, 64); qr[q] += __shfl_down(qr[q], 16, 64);
        sr[q] += __shfl_down(sr[q],  8, 64); qr[q] += __shfl_down(qr[q],  8, 64);
    }
    if ((tid & 63) < 8) {
        #pragma unroll
        for (int q=0; q<4; ++q) {
            atomicAdd(&stS[4*l+q],       sr[q]);
            atomicAdd(&stS[DIM+4*l+q],   qr[q]);
        }
    }
    __syncthreads();
    if (tid < 2*DIM)
        atomicAdd(&part[((blockIdx.x & (NSLICE-1))<<6) + tid], stS[tid]);
}

// reduce partial stats -> scale/shift; re-zero partials for next layer
__global__ __launch_bounds__(256) void k_scaleshift(
    float* __restrict__ part,
    const float* __restrict__ gamma, const float* __restrict__ beta,
    int layer, float* __restrict__ ss)
{
    __shared__ float red[4][64];
    __shared__ float totS[64];
    int t = threadIdx.x;
    int ch = t & 63, q = t >> 6;
    float s = 0.f;
    for (int i = q*64; i < q*64 + 64; ++i) s += part[(i<<6) + ch];
    red[q][ch] = s;
    __syncthreads();
    if (t < 64) totS[t] = red[0][t]+red[1][t]+red[2][t]+red[3][t];
    __syncthreads();
    if (t < DIM) {
        float mean = totS[t] * (1.f/N_NODES);
        float var  = totS[DIM+t] * (1.f/N_NODES) - mean*mean;
        float sc = gamma[layer*DIM+t] * rsqrtf(var + 1e-5f);
        ss[t] = sc;
        ss[DIM+t] = beta[layer*DIM+t] - mean*sc;
    }
    for (int i = t; i < NSLICE*64; i += 256) part[i] = 0.f;
}

// Global add pool with BN applied: hg[batch[n]] += BN(z[n]).
// batch is sorted -> a wave's 8 nodes usually share one graph: wave-reduce
// then 1/8 the atomics.
__global__ __launch_bounds__(256) void k_pool(
    const float* __restrict__ z, const float* __restrict__ ss,
    const int* __restrict__ batch, float* __restrict__ hg)
{
    int tid = threadIdx.x;
    int node = blockIdx.x*32 + (tid>>3);
    int cq = tid & 7;                      // channels 4cq..4cq+3
    float4 v = ((const float4*)z)[(long)node*8 + cq];
    float4 sc = ((const float4*)ss)[cq];
    float4 sh = ((const float4*)ss)[8 + cq];
    v.x = v.x*sc.x + sh.x; v.y = v.y*sc.y + sh.y;
    v.z = v.z*sc.z + sh.z; v.w = v.w*sc.w + sh.w;
    int b = batch[node];
    int b0 = __shfl(b, 0, 64);
    int b7 = __shfl(b, 63, 64);
    if (b0 == b7) {
        #pragma unroll
        for (int off=8; off<64; off<<=1) {
            v.x += __shfl_xor(v.x, off, 64);
            v.y += __shfl_xor(v.y, off, 64);
            v.z += __shfl_xor(v.z, off, 64);
            v.w += __shfl_xor(v.w, off, 64);
        }
        if ((tid & 63) < 8) {
            float* dst = hg + (long)b0*DIM + cq*4;
            atomicAdd(dst+0, v.x); atomicAdd(dst+1, v.y);
            atomicAdd(dst+2, v.z); atomicAdd(dst+3, v.w);
        }
    } else {
        float* dst = hg + (long)b*DIM + cq*4;
        atomicAdd(dst+0, v.x); atomicAdd(dst+1, v.y);
        atomicAdd(dst+2, v.z); atomicAdd(dst+3, v.w);
    }
}

// xd = ReLU(hg @ w_fcxd + b) -> xc[:, 0:128]
__global__ __launch_bounds__(128) void k_xd(
    const float* __restrict__ hg, const float* __restrict__ w,
    const float* __restrict__ bias, float* __restrict__ xc)
{
    int b = blockIdx.x, n = threadIdx.x;
    __shared__ float hS[DIM];
    if (n < DIM) hS[n] = hg[b*DIM+n];
    __syncthreads();
    float acc = bias[n];
    #pragma unroll
    for (int r=0; r<DIM; ++r) acc += hS[r]*w[r*OUTD+n];
    xc[b*256 + n] = fmaxf(acc, 0.f);
}

// ---------------- protein branch ----------------

// conv_w (OIH fp32) -> cwT (fp16, layout [i][o*8+k], row = 256 halfs = 512B)
__global__ __launch_bounds__(256) void k_cw_transpose(
    const float* __restrict__ cw, __half* __restrict__ cwT)
{
    int g = blockIdx.x*256 + threadIdx.x;   // 256000 total
    int i = g >> 8;
    int j = g & 255;
    int o = j >> 3, k = j & 7;
    cwT[g] = __float2half(cw[o*(PLEN*KS) + i*KS + k]);
}

// Phase 1: LDS counting-sort of 1000 tokens by vocab.
// Phase 2: wave-per-row fp16 cwT accumulate; buckets partitioned over the
//          4 waves by seg[v]/250 -> register acc, no atomics, direct store.
// Phase 3: conv as G x emb with b128 LDS reads; emb staged in 2 chunks of 13
//          rows (stride 156, skew f(t)=t+4*(t>>4): 16B-aligned + bank-clean).
__global__ __launch_bounds__(256) void k_conv(
    const int* __restrict__ target, const float* __restrict__ emb,
    const __half* __restrict__ cwTh, const float* __restrict__ conv_b,
    float* __restrict__ c)
{
    __shared__ __align__(16) float Gs[VOCAB*256];   // 26,624B; reused as out-stage
    __shared__ __align__(16) float U[2080];         // 8,320B: sortedS ∪ emb chunk
    __shared__ int meta[3*VOCAB+2];                 // cnt / seg / cur
    __shared__ float cbS[NF];
    int* sortedS = (int*)U;
    int* cntS = meta;
    int* segS = meta + VOCAB;          // [VOCAB+1]
    int* curS = meta + 2*VOCAB + 1;
    int b = blockIdx.x, j = threadIdx.x;
    if (j < VOCAB) cntS[j] = 0;
    if (j < NF) cbS[j] = conv_b[j];
    __syncthreads();
    // ---- phase 1: counting sort ----
    int tloc[4];
    #pragma unroll
    for (int q=0; q<4; ++q) {
        int i = j + q*256;
        if (i < PLEN) {
            tloc[q] = target[b*PLEN+i];
            atomicAdd(&cntS[tloc[q]], 1);
        } else tloc[q] = -1;
    }
    __syncthreads();
    if (j == 0) {
        int run = 0;
        for (int v=0; v<VOCAB; ++v) { segS[v]=run; run += cntS[v]; }
        segS[VOCAB] = run;
    }
    __syncthreads();
    if (j < VOCAB) curS[j] = segS[j];
    __syncthreads();
    #pragma unroll
    for (int q=0; q<4; ++q) {
        int i = j + q*256;
        if (i < PLEN) {
            int pos = atomicAdd(&curS[tloc[q]], 1);
            sortedS[pos] = i;
        }
    }
    __syncthreads();
    // ---- phase 2: wave-per-row fp16 accumulate, buckets split over waves ----
    int w = j >> 6;
    int lane = j & 63;                   // owns columns 4*lane..4*lane+3
    const uint2* cw2 = (const uint2*)cwTh;   // row = 64 uint2 (512B)
#define ACC4(Q, X0,X1,X2,X3) { \
    float2 f_ = __half22float2(*(const __half2*)&(Q).x); X0+=f_.x; X1+=f_.y; \
    f_ = __half22float2(*(const __half2*)&(Q).y); X2+=f_.x; X3+=f_.y; }
    for (int v=0; v<VOCAB; ++v) {
        int s = segS[v], e2 = segS[v+1];
        int wv = s / 250; if (wv > 3) wv = 3;
        if (wv != w) continue;
        float a0=0.f,a1=0.f,a2=0.f,a3=0.f;
        float c0=0.f,c1=0.f,c2=0.f,c3=0.f;
        int p = s;
        for (; p+8 <= e2; p += 8) {
            int i0=sortedS[p+0], i1=sortedS[p+1], i2=sortedS[p+2], i3=sortedS[p+3];
            int i4=sortedS[p+4], i5=sortedS[p+5], i6=sortedS[p+6], i7=sortedS[p+7];
            uint2 q0=cw2[i0*64+lane], q1=cw2[i1*64+lane];
            uint2 q2=cw2[i2*64+lane], q3=cw2[i3*64+lane];
            uint2 q4=cw2[i4*64+lane], q5=cw2[i5*64+lane];
            uint2 q6=cw2[i6*64+lane], q7=cw2[i7*64+lane];
            ACC4(q0,a0,a1,a2,a3); ACC4(q1,c0,c1,c2,c3);
            ACC4(q2,a0,a1,a2,a3); ACC4(q3,c0,c1,c2,c3);
            ACC4(q4,a0,a1,a2,a3); ACC4(q5,c0,c1,c2,c3);
            ACC4(q6,a0,a1,a2,a3); ACC4(q7,c0,c1,c2,c3);
        }
        for (; p < e2; ++p) {
            uint2 qq = cw2[sortedS[p]*64+lane];
            ACC4(qq,a0,a1,a2,a3);
        }
        ((float4*)(Gs + v*256))[lane] = make_float4(a0+c0, a1+c1, a2+c2, a3+c3);
    }
#undef ACC4
    // ---- phase 3: conv, emb chunked through U ----
    int o = j >> 3, pg = j & 7;
    int t0 = pg*16;
    int tcnt = (t0+16 <= CLEN) ? 16 : (CLEN - t0);   // 16 or 9
    float out[16];
    #pragma unroll
    for (int q=0; q<16; ++q) out[q] = cbS[o];
    for (int ch=0; ch<2; ++ch) {
        __syncthreads();     // chunk 0: protect sortedS; chunk 1: protect prev emb
        for (int i=j; i<ECHUNK*EMBD; i+=256) {
            int v = i >> 7, tt = i & 127;
            U[v*EROW2 + tt + 4*(tt>>4)] = emb[(ch*ECHUNK + v)*EMBD + tt];
        }
        __syncthreads();
        for (int vv=0; vv<ECHUNK; ++vv) {
            const float4* gp = (const float4*)(Gs + (ch*ECHUNK+vv)*256 + o*8);
            float4 g0 = gp[0], g1 = gp[1];
            float g[8] = {g0.x,g0.y,g0.z,g0.w,g1.x,g1.y,g1.z,g1.w};
            const float* ev = &U[vv*EROW2 + 20*pg];
            float4 E0 = *(const float4*)(ev);
            float4 E1 = *(const float4*)(ev+4);
            float4 E2 = *(const float4*)(ev+8);
            float4 E3 = *(const float4*)(ev+12);
            float4 E4 = *(const float4*)(ev+20);
            float4 E5 = *(const float4*)(ev+24);
            float e[24] = {E0.x,E0.y,E0.z,E0.w, E1.x,E1.y,E1.z,E1.w,
                           E2.x,E2.y,E2.z,E2.w, E3.x,E3.y,E3.z,E3.w,
                           E4.x,E4.y,E4.z,E4.w, E5.x,E5.y,E5.z,E5.w};
            #pragma unroll
            for (int q=0; q<16; ++q) {
                float s = 0.f;
                #pragma unroll
                for (int k=0; k<KS; ++k) s += e[q+k]*g[k];
                out[q] += s;
            }
        }
    }
    __syncthreads();
    float* stage = Gs;
    for (int q=0; q<tcnt; ++q) stage[o*CLEN + t0 + q] = out[q];
    __syncthreads();
    for (int idx=j; idx<FCX; idx+=256)
        c[(long)b*FCX + idx] = stage[idx];
}

// xt: [1024 x 3872] @ [3872 x 128] tiled GEMM with 8-way K-split.
#define XT_KSL 484
#define XT_BK  44
__global__ __launch_bounds__(256) void k_xt(
    const float* __restrict__ c, const float* __restrict__ w,
    const float* __restrict__ bias, float* __restrict__ xc)
{
    __shared__ float cS[32][XT_BK];
    __shared__ float wS[XT_BK][128];
    int b0 = blockIdx.x * 32;
    int ks0 = blockIdx.y * XT_KSL;
    int tid = threadIdx.x;
    int cg = tid >> 5;          // graph group 0..7
    int co = tid & 31;          // col group 0..31
    float acc[4][4];
    #pragma unroll
    for (int i2=0;i2<4;++i2)
      #pragma unroll
      for (int j2=0;j2<4;++j2) acc[i2][j2]=0.f;
    for (int ch=0; ch<11; ++ch) {
        int k0 = ks0 + ch*XT_BK;
        for (int idx=tid; idx<32*XT_BK; idx+=256) {
            int g = idx / XT_BK, kk = idx - g*XT_BK;
            cS[g][kk] = c[(long)(b0+g)*FCX + k0 + kk];
        }
        for (int idx=tid; idx<XT_BK*128; idx+=256) {
            int kk = idx >> 7, n = idx & 127;
            wS[kk][n] = w[(long)(k0+kk)*OUTD + n];
        }
        __syncthreads();
        #pragma unroll 4
        for (int kk=0; kk<XT_BK; ++kk) {
            float cv[4], wv[4];
            #pragma unroll
            for (int q=0;q<4;++q) cv[q] = cS[cg*4+q][kk];
            #pragma unroll
            for (int p=0;p<4;++p) wv[p] = wS[kk][co*4+p];
            #pragma unroll
            for (int q=0;q<4;++q)
              #pragma unroll
              for (int p=0;p<4;++p) acc[q][p] += cv[q]*wv[p];
        }
        __syncthreads();
    }
    #pragma unroll
    for (int q=0;q<4;++q) {
        int g = b0 + cg*4 + q;
        #pragma unroll
        for (int p=0;p<4;++p) {
            int n = co*4 + p;
            float v = acc[q][p];
            if (blockIdx.y == 0) v += bias[n];
            atomicAdd(&xc[g*256 + 128 + n], v);
        }
    }
}

// ---------------- joint head ----------------

__global__ __launch_bounds__(256) void k_fc1(
    const float* __restrict__ xc, const float* __restrict__ w,
    const float* __restrict__ bias, float* __restrict__ y)
{
    __shared__ float xS[4][256];
    int b0 = blockIdx.x*4, n = threadIdx.x;
    #pragma unroll
    for (int q=0; q<4; ++q) xS[q][n] = xc[(b0+q)*256 + n];
    __syncthreads();
    float acc[4][4];
    #pragma unroll
    for (int m=0; m<4; ++m) {
        float bv = bias[m*256+n];
        #pragma unroll
        for (int q=0; q<4; ++q) acc[q][m] = bv;
    }
    for (int r=0; r<256; ++r) {
        float x0=xS[0][r], x1=xS[1][r], x2=xS[2][r], x3=xS[3][r];
        #pragma unroll
        for (int m=0; m<4; ++m) {
            float wv = w[r*1024 + m*256 + n];
            acc[0][m]+=x0*wv; acc[1][m]+=x1*wv; acc[2][m]+=x2*wv; acc[3][m]+=x3*wv;
        }
    }
    #pragma unroll
    for (int q=0; q<4; ++q)
        #pragma unroll
        for (int m=0; m<4; ++m)
            y[(b0+q)*1024 + m*256 + n] = fmaxf(acc[q][m], 0.f);
}

__global__ __launch_bounds__(256) void k_fc2(
    const float* __restrict__ y, const float* __restrict__ w,
    const float* __restrict__ bias, float* __restrict__ y2)
{
    __shared__ float xS[4][1024];
    int b0 = blockIdx.x*4, n = threadIdx.x;
    #pragma unroll
    for (int q=0; q<4; ++q)
        for (int i=n; i<1024; i+=256) xS[q][i] = y[(b0+q)*1024 + i];
    __syncthreads();
    float acc[4];
    #pragma unroll
    for (int q=0; q<4; ++q) acc[q] = bias[n];
    for (int r=0; r<1024; ++r) {
        float wv = w[r*256 + n];
        #pragma unroll
        for (int q=0; q<4; ++q) acc[q] += xS[q][r]*wv;
    }
    #pragma unroll
    for (int q=0; q<4; ++q) y2[(b0+q)*256 + n] = fmaxf(acc[q], 0.f);
}

__global__ __launch_bounds__(256) void k_out(
    const float* __restrict__ y2, const float* __restrict__ w,
    const float* __restrict__ bias, float* __restrict__ out)
{
    int b = blockIdx.x, n = threadIdx.x;
    float v = y2[b*256 + n] * w[n];
    #pragma unroll
    for (int off=32; off; off>>=1) v += __shfl_down(v, off, 64);
    __shared__ float red[4];
    if ((n & 63) == 0) red[n >> 6] = v;
    __syncthreads();
    if (n == 0) out[b] = red[0]+red[1]+red[2]+red[3] + bias[0];
}

// ---------------- launch ----------------

extern "C" void kernel_launch(void* const* d_in, const int* in_sizes, int n_in,
                              void* d_out, int out_size, void* d_ws, size_t ws_size,
                              hipStream_t stream) {
    const float* x      = (const float*)d_in[0];
    const int*   ei     = (const int*)  d_in[1];
    const int*   batch  = (const int*)  d_in[2];
    const int*   target = (const int*)  d_in[3];
    const float* w1a    = (const float*)d_in[4];
    const float* b1a    = (const float*)d_in[5];
    const float* w1b    = (const float*)d_in[6];
    const float* b1b    = (const float*)d_in[7];
    const float* wa     = (const float*)d_in[8];
    const float* ba     = (const float*)d_in[9];
    const float* wb     = (const float*)d_in[10];
    const float* bb     = (const float*)d_in[11];
    const float* gamma  = (const float*)d_in[12];
    const float* beta   = (const float*)d_in[13];
    const float* w_fcxd = (const float*)d_in[14];
    const float* b_fcxd = (const float*)d_in[15];
    const float* emb    = (const float*)d_in[16];
    const float* conv_w = (const float*)d_in[17];
    const float* conv_b = (const float*)d_in[18];
    const float* w_fcxt = (const float*)d_in[19];
    const float* b_fcxt = (const float*)d_in[20];
    const float* w_fc1  = (const float*)d_in[21];
    const float* b_fc1  = (const float*)d_in[22];
    const float* w_fc2  = (const float*)d_in[23];
    const float* b_fc2  = (const float*)d_in[24];
    const float* w_out  = (const float*)d_in[25];
    const float* b_out  = (const float*)d_in[26];

    float* ws      = (float*)d_ws;
    __half* tH     = (__half*)ws;                          // N*32 halfs = 1,048,576 float-slots
    float* z       = ws + 1048576;                         // N*32 floats
    unsigned int* pairs = (unsigned int*)(z + (size_t)N_NODES*DIM);  // E uints
    int*   csr     = (int*)(pairs + N_EDGES);              // E ints
    int*   rowptr  = csr + N_EDGES;                        // N+1 (+pad)
    int*   bktCnt  = rowptr + (N_NODES + 8);               // 256
    int*   bktBase = bktCnt + 256;                         // 257 (+pad)
    int*   bktCur  = bktBase + 264;                        // 256
    float* ss      = (float*)(bktCur + 256);               // 64
    float* hg      = ss + 64;                              // 32768
    float* cwT     = hg + (size_t)NB*DIM;                  // 256000 float-slots (fp16 uses half)
    float* cbuf    = cwT + 256000;                         // 3964928
    float* xc      = cbuf + (size_t)NB*FCX;                // 262144
    float* y1      = xc + (size_t)NB*256;                  // 1048576
    float* y2      = y1 + (size_t)NB*1024;                 // 262144
    float* part    = y2 + (size_t)NB*256;                  // 256*64
    __half* cwTh   = (__half*)cwT;

    // ---- CSR build: bucket sort (coalesced) + fused rowptr/scatter ----
    hipMemsetAsync(bktCnt, 0, 256*sizeof(int), stream);
    k_bhist<<<N_EDGES/1024, 256, 0, stream>>>(ei, bktCnt);
    k_bscan<<<1, 256, 0, stream>>>(bktCnt, bktBase, bktCur);
    k_bucketA<<<NBKT, 256, 0, stream>>>(ei, bktCur, pairs);
    k_fillB<<<NBKT, 256, 0, stream>>>(bktBase, pairs, rowptr, csr);

    // ---- protein branch ----
    hipMemsetAsync(xc, 0, (size_t)NB*256*sizeof(float), stream);
    k_cw_transpose<<<1000, 256, 0, stream>>>(conv_w, cwTh);
    k_conv<<<NB, 256, 0, stream>>>(target, emb, cwTh, conv_b, cbuf);
    k_xt<<<dim3(32, 8), 256, 0, stream>>>(cbuf, w_fcxt, b_fcxt, xc);

    // ---- GIN layers ----
    hipMemsetAsync(part, 0, NSLICE*64*sizeof(float), stream);
    for (int l=0; l<5; ++l) {
        if (l == 0)
            k_l1_transform<<<N_NODES/256, 256, 0, stream>>>(x, w1a, tH);
        else
            k_transform<<<N_NODES/256, 256, 0, stream>>>(z, ss, wa + (size_t)(l-1)*DIM*DIM, tH);
        const float* bi = (l==0) ? b1a : ba + (size_t)(l-1)*DIM;
        const float* wo = (l==0) ? w1b : wb + (size_t)(l-1)*DIM*DIM;
        const float* bo = (l==0) ? b1b : bb + (size_t)(l-1)*DIM;
        k_gather_mlp<<<N_NODES/32, 256, 0, stream>>>(rowptr, csr, tH, bi, wo, bo, z, part);
        k_scaleshift<<<1, 256, 0, stream>>>(part, gamma, beta, l, ss);
    }

    // ---- pool + drug head ----
    hipMemsetAsync(hg, 0, (size_t)NB*DIM*sizeof(float), stream);
    k_pool<<<N_NODES/32, 256, 0, stream>>>(z, ss, batch, hg);
    k_xd<<<NB, 128, 0, stream>>>(hg, w_fcxd, b_fcxd, xc);

    // ---- joint head ----
    k_fc1<<<NB/4, 256, 0, stream>>>(xc, w_fc1, b_fc1, y1);
    k_fc2<<<NB/4, 256, 0, stream>>>(y1, w_fc2, b_fc2, y2);
    k_out<<<NB, 256, 0, stream>>>(y2, w_out, b_out, (float*)d_out);
}

// Round 3
// 761.777 us; speedup vs baseline: 1.0437x; 1.0094x over previous
//
#include <hip/hip_runtime.h>
#include <hip/hip_fp16.h>

#define N_NODES 65536
#define N_EDGES 2097152
#define NB      1024
#define FXD     78
#define DIM     32
#define EMBD    128
#define OUTD    128
#define VOCAB   26
#define PLEN    1000
#define KS      8
#define CLEN    121      // EMBD-KS+1
#define NF      32
#define FCX     (NF*CLEN)  // 3872
#define NBKT    256
#define EPB     8192     // edges per bucketA block (N_EDGES/256)
#define NSLICE  256      // stats partial slices
#define EROW2   156      // emb row stride (floats): f(t)=t+4*(t>>4), f(127)=155
#define ECHUNK  13       // emb rows staged per chunk (2 chunks x 13 = 26)

// ---------------- bucket sort (dst>>8) ----------------

__global__ __launch_bounds__(256) void k_bhist(
    const int* __restrict__ ei, int* __restrict__ bktCnt)
{
    __shared__ int h[NBKT];
    int tid = threadIdx.x;
    h[tid] = 0;
    __syncthreads();
    int base = blockIdx.x*1024;
    #pragma unroll
    for (int q=0; q<4; ++q) {
        int d = ei[N_EDGES + base + q*256 + tid];
        atomicAdd(&h[d>>8], 1);
    }
    __syncthreads();
    atomicAdd(&bktCnt[tid], h[tid]);
}

__global__ __launch_bounds__(256) void k_bscan(
    const int* __restrict__ bktCnt, int* __restrict__ bktBase, int* __restrict__ bktCur)
{
    __shared__ int s[NBKT];
    int t = threadIdx.x;
    int v = bktCnt[t];
    s[t] = v;
    __syncthreads();
    for (int off=1; off<256; off<<=1) {
        int tv = (t >= off) ? s[t-off] : 0;
        __syncthreads();
        s[t] += tv;
        __syncthreads();
    }
    int ex = s[t] - v;
    bktBase[t] = ex;
    bktCur[t] = ex;
    if (t == 255) bktBase[256] = s[255];   // == N_EDGES
}

// LDS-sort 8192 edges by bucket, write packed (dst<<16|src) in coalesced runs
__global__ __launch_bounds__(256) void k_bucketA(
    const int* __restrict__ ei, int* __restrict__ bktCur, unsigned int* __restrict__ pairs)
{
    __shared__ unsigned int raw[EPB];       // 32 KB
    __shared__ unsigned int srt[EPB];       // 32 KB
    __shared__ unsigned char bOf[EPB];      // 8 KB
    __shared__ int hist[NBKT], sc[NBKT], lcur[NBKT], gbase[NBKT];
    int tid = threadIdx.x;
    hist[tid] = 0;
    __syncthreads();
    int eb = blockIdx.x * EPB;
    for (int i=tid; i<EPB; i+=256) {
        int s = ei[eb+i];
        int d = ei[N_EDGES+eb+i];
        raw[i] = ((unsigned int)d<<16) | (unsigned int)s;
        atomicAdd(&hist[d>>8], 1);
    }
    __syncthreads();
    int v = hist[tid];
    sc[tid] = v;
    __syncthreads();
    for (int off=1; off<256; off<<=1) {
        int tv = (tid >= off) ? sc[tid-off] : 0;
        __syncthreads();
        sc[tid] += tv;
        __syncthreads();
    }
    int ex = sc[tid] - v;
    sc[tid] = ex;            // exclusive local base
    lcur[tid] = ex;
    gbase[tid] = atomicAdd(&bktCur[tid], v);
    __syncthreads();
    for (int i=tid; i<EPB; i+=256) {
        unsigned int p = raw[i];
        int k = p >> 24;
        int pos = atomicAdd(&lcur[k], 1);
        srt[pos] = p;
        bOf[pos] = (unsigned char)k;
    }
    __syncthreads();
    for (int i=tid; i<EPB; i+=256) {
        int k = bOf[i];
        pairs[gbase[k] + (i - sc[k])] = srt[i];
    }
}

// per bucket: build rowptr (LDS histogram + scan) and scatter srcs into the
// bucket's contiguous CSR segment.
__global__ __launch_bounds__(256) void k_fillB(
    const int* __restrict__ bktBase, const unsigned int* __restrict__ pairs,
    int* __restrict__ rowptr, int* __restrict__ csr)
{
    __shared__ int hist[256], sc[256], cur[256];
    int b = blockIdx.x, tid = threadIdx.x;
    int node0 = b*256;
    hist[tid] = 0;
    __syncthreads();
    int s = bktBase[b], e = bktBase[b+1];
    for (int i = s + tid; i < e; i += 256)
        atomicAdd(&hist[(pairs[i] >> 16) & 255], 1);
    __syncthreads();
    int v = hist[tid];
    sc[tid] = v;
    __syncthreads();
    for (int off=1; off<256; off<<=1) {
        int tv = (tid >= off) ? sc[tid-off] : 0;
        __syncthreads();
        sc[tid] += tv;
        __syncthreads();
    }
    int base = s + sc[tid] - v;     // exclusive
    rowptr[node0 + tid] = base;
    cur[tid] = base;
    if (b == NBKT-1 && tid == 255) rowptr[N_NODES] = N_EDGES;
    __syncthreads();
    for (int i = s + tid; i < e; i += 256) {
        unsigned int p = pairs[i];
        int pos = atomicAdd(&cur[(p >> 16) & 255], 1);
        csr[pos] = (int)(p & 0xFFFFu);
    }
}

// ---------------- GIN layer kernels ----------------

// Layer-1 transform: t = x @ w1a  (fp16 out)
__global__ __launch_bounds__(256) void k_l1_transform(
    const float* __restrict__ x, const float* __restrict__ w,
    __half* __restrict__ t)
{
    __shared__ float wS[FXD*DIM];
    for (int i = threadIdx.x; i < FXD*DIM; i += 256) wS[i] = w[i];
    __syncthreads();
    int node = blockIdx.x*256 + threadIdx.x;
    float acc[DIM];
    #pragma unroll
    for (int d=0; d<DIM; ++d) acc[d] = 0.f;
    const float* xr = x + (long)node*FXD;
    for (int j=0; j<FXD; ++j) {
        float xv = xr[j];
        #pragma unroll
        for (int d=0; d<DIM; ++d) acc[d] += xv * wS[j*DIM+d];
    }
    union { __half2 h2[16]; uint4 u4[4]; } pk;
    #pragma unroll
    for (int q=0; q<16; ++q) pk.h2[q] = __floats2half2_rn(acc[2*q], acc[2*q+1]);
    uint4* dst4 = (uint4*)(t + (long)node*DIM);
    #pragma unroll
    for (int q=0; q<4; ++q) dst4[q] = pk.u4[q];
}

// Layers 2-5: h = BN(z) via scale/shift; t = h @ w  (fp16 out)
__global__ __launch_bounds__(256) void k_transform(
    const float* __restrict__ z, const float* __restrict__ ss,
    const float* __restrict__ w, __half* __restrict__ t)
{
    __shared__ float wS[DIM*DIM];
    __shared__ float sS[2*DIM];
    for (int i = threadIdx.x; i < DIM*DIM; i += 256) wS[i] = w[i];
    if (threadIdx.x < 2*DIM) sS[threadIdx.x] = ss[threadIdx.x];
    __syncthreads();
    int node = blockIdx.x*256 + threadIdx.x;
    float h[DIM];
    const float4* z4 = (const float4*)(z + (long)node*DIM);
    #pragma unroll
    for (int q=0; q<DIM/4; ++q) {
        float4 v = z4[q];
        h[q*4+0]=v.x; h[q*4+1]=v.y; h[q*4+2]=v.z; h[q*4+3]=v.w;
    }
    #pragma unroll
    for (int d=0; d<DIM; ++d) h[d] = h[d]*sS[d] + sS[DIM+d];
    float acc[DIM];
    #pragma unroll
    for (int d=0; d<DIM; ++d) acc[d] = 0.f;
    #pragma unroll
    for (int j=0; j<DIM; ++j) {
        float hv = h[j];
        #pragma unroll
        for (int d=0; d<DIM; ++d) acc[d] += hv * wS[j*DIM+d];
    }
    union { __half2 h2[16]; uint4 u4[4]; } pk;
    #pragma unroll
    for (int q=0; q<16; ++q) pk.h2[q] = __floats2half2_rn(acc[2*q], acc[2*q+1]);
    uint4* dst4 = (uint4*)(t + (long)node*DIM);
    #pragma unroll
    for (int q=0; q<4; ++q) dst4[q] = pk.u4[q];
}

// Gather (CSR) + self + MLP + ReLU + BN-stats partials.
__global__ __launch_bounds__(256) void k_gather_mlp(
    const int* __restrict__ rowptr, const int* __restrict__ csr,
    const __half* __restrict__ t,
    const float* __restrict__ bi, const float* __restrict__ wo, const float* __restrict__ bo,
    float* __restrict__ z, float* __restrict__ part)
{
    __shared__ float wS[DIM*DIM];
    __shared__ float bS[2*DIM];
    __shared__ float stS[2*DIM];
    int tid = threadIdx.x;
    for (int i=tid; i<DIM*DIM; i+=256) wS[i]=wo[i];
    if (tid<DIM) bS[tid]=bi[tid];
    else if (tid<2*DIM) bS[tid]=bo[tid-DIM];
    if (tid<2*DIM) stS[tid]=0.f;
    __syncthreads();
    int g = tid >> 3;           // node 0..31 within block
    int l = tid & 7;            // lane in group; owns channels 4l..4l+3
    int node = blockIdx.x*32 + g;
    const uint2* t4 = (const uint2*)t;   // 8B = 4 halfs; 8 entries per row
    uint2 sv = t4[(long)node*8 + l];     // self term
    float2 p0 = __half22float2(*(const __half2*)&sv.x);
    float2 p1 = __half22float2(*(const __half2*)&sv.y);
    float a0=p0.x, a1=p0.y, a2=p1.x, a3=p1.y;
    float c0=0.f, c1=0.f, c2=0.f, c3=0.f;
    int s0 = rowptr[node], s1 = rowptr[node+1];
    int e = s0;
    for (; e+8 <= s1; e+=8) {
        int myIdx = csr[e + l];          // 8 consecutive, coalesced
        #pragma unroll
        for (int k=0; k<8; ++k) {
            int idx = __shfl(myIdx, k, 8);
            uint2 v = t4[(long)idx*8 + l];
            float2 q0 = __half22float2(*(const __half2*)&v.x);
            float2 q1 = __half22float2(*(const __half2*)&v.y);
            if (k & 1) { c0+=q0.x; c1+=q0.y; c2+=q1.x; c3+=q1.y; }
            else       { a0+=q0.x; a1+=q0.y; a2+=q1.x; a3+=q1.y; }
        }
    }
    if (e+4 <= s1) {
        int myIdx = csr[e + (l & 3)];
        #pragma unroll
        for (int k=0; k<4; ++k) {
            int idx = __shfl(myIdx, k, 8);
            uint2 v = t4[(long)idx*8 + l];
            float2 q0 = __half22float2(*(const __half2*)&v.x);
            float2 q1 = __half22float2(*(const __half2*)&v.y);
            if (k & 1) { c0+=q0.x; c1+=q0.y; c2+=q1.x; c3+=q1.y; }
            else       { a0+=q0.x; a1+=q0.y; a2+=q1.x; a3+=q1.y; }
        }
        e += 4;
    }
    for (; e<s1; ++e) {
        uint2 v = t4[(long)csr[e]*8 + l];
        float2 q0 = __half22float2(*(const __half2*)&v.x);
        float2 q1 = __half22float2(*(const __half2*)&v.y);
        a0+=q0.x; a1+=q0.y; a2+=q1.x; a3+=q1.y;
    }
    float ua[4];
    ua[0] = fmaxf(a0+c0 + bS[4*l+0], 0.f);
    ua[1] = fmaxf(a1+c1 + bS[4*l+1], 0.f);
    ua[2] = fmaxf(a2+c2 + bS[4*l+2], 0.f);
    ua[3] = fmaxf(a3+c3 + bS[4*l+3], 0.f);
    float zz[4];
    #pragma unroll
    for (int q=0; q<4; ++q) zz[q] = bS[DIM + 4*l + q];
    const float4* w4 = (const float4*)wS;
    #pragma unroll
    for (int j=0; j<DIM; ++j) {
        float uj = __shfl(ua[j & 3], j >> 2, 8);
        float4 wv = w4[j*8 + l];
        zz[0]+=uj*wv.x; zz[1]+=uj*wv.y; zz[2]+=uj*wv.z; zz[3]+=uj*wv.w;
    }
    #pragma unroll
    for (int q=0; q<4; ++q) zz[q] = fmaxf(zz[q], 0.f);
    ((float4*)z)[(long)node*8 + l] = make_float4(zz[0], zz[1], zz[2], zz[3]);
    // stats: reduce the 8 node-groups of each wave down to 8 lanes
    float sr[4], qr[4];
    #pragma unroll
    for (int q=0; q<4; ++q) { sr[q] = zz[q]; qr[q] = zz[q]*zz[q]; }
    #pragma unroll
    for (int q=0; q<4; ++q) {
        sr[q] += __shfl_down(sr[q], 32, 64); qr[q] += __shfl_down(qr[q], 32, 64);
        sr[q] += __shfl_down(sr[q], 16, 64); qr[q] += __shfl_down(qr[q], 16, 64);
        sr[q] += __shfl_down(sr[q],  8, 64); qr[q] += __shfl_down(qr[q],  8, 64);
    }
    if ((tid & 63) < 8) {
        #pragma unroll
        for (int q=0; q<4; ++q) {
            atomicAdd(&stS[4*l+q],       sr[q]);
            atomicAdd(&stS[DIM+4*l+q],   qr[q]);
        }
    }
    __syncthreads();
    if (tid < 2*DIM)
        atomicAdd(&part[((blockIdx.x & (NSLICE-1))<<6) + tid], stS[tid]);
}

// reduce partial stats -> scale/shift; re-zero partials for next layer
__global__ __launch_bounds__(256) void k_scaleshift(
    float* __restrict__ part,
    const float* __restrict__ gamma, const float* __restrict__ beta,
    int layer, float* __restrict__ ss)
{
    __shared__ float red[4][64];
    __shared__ float totS[64];
    int t = threadIdx.x;
    int ch = t & 63, q = t >> 6;
    float s = 0.f;
    for (int i = q*64; i < q*64 + 64; ++i) s += part[(i<<6) + ch];
    red[q][ch] = s;
    __syncthreads();
    if (t < 64) totS[t] = red[0][t]+red[1][t]+red[2][t]+red[3][t];
    __syncthreads();
    if (t < DIM) {
        float mean = totS[t] * (1.f/N_NODES);
        float var  = totS[DIM+t] * (1.f/N_NODES) - mean*mean;
        float sc = gamma[layer*DIM+t] * rsqrtf(var + 1e-5f);
        ss[t] = sc;
        ss[DIM+t] = beta[layer*DIM+t] - mean*sc;
    }
    for (int i = t; i < NSLICE*64; i += 256) part[i] = 0.f;
}

// Global add pool with BN applied: hg[batch[n]] += BN(z[n]).
// batch is sorted -> a wave's 8 nodes usually share one graph: wave-reduce
// then 1/8 the atomics.
__global__ __launch_bounds__(256) void k_pool(
    const float* __restrict__ z, const float* __restrict__ ss,
    const int* __restrict__ batch, float* __restrict__ hg)
{
    int tid = threadIdx.x;
    int node = blockIdx.x*32 + (tid>>3);
    int cq = tid & 7;                      // channels 4cq..4cq+3
    float4 v = ((const float4*)z)[(long)node*8 + cq];
    float4 sc = ((const float4*)ss)[cq];
    float4 sh = ((const float4*)ss)[8 + cq];
    v.x = v.x*sc.x + sh.x; v.y = v.y*sc.y + sh.y;
    v.z = v.z*sc.z + sh.z; v.w = v.w*sc.w + sh.w;
    int b = batch[node];
    int b0 = __shfl(b, 0, 64);
    int b7 = __shfl(b, 63, 64);
    if (b0 == b7) {
        #pragma unroll
        for (int off=8; off<64; off<<=1) {
            v.x += __shfl_xor(v.x, off, 64);
            v.y += __shfl_xor(v.y, off, 64);
            v.z += __shfl_xor(v.z, off, 64);
            v.w += __shfl_xor(v.w, off, 64);
        }
        if ((tid & 63) < 8) {
            float* dst = hg + (long)b0*DIM + cq*4;
            atomicAdd(dst+0, v.x); atomicAdd(dst+1, v.y);
            atomicAdd(dst+2, v.z); atomicAdd(dst+3, v.w);
        }
    } else {
        float* dst = hg + (long)b*DIM + cq*4;
        atomicAdd(dst+0, v.x); atomicAdd(dst+1, v.y);
        atomicAdd(dst+2, v.z); atomicAdd(dst+3, v.w);
    }
}

// xd = ReLU(hg @ w_fcxd + b) -> xc[:, 0:128]
__global__ __launch_bounds__(128) void k_xd(
    const float* __restrict__ hg, const float* __restrict__ w,
    const float* __restrict__ bias, float* __restrict__ xc)
{
    int b = blockIdx.x, n = threadIdx.x;
    __shared__ float hS[DIM];
    if (n < DIM) hS[n] = hg[b*DIM+n];
    __syncthreads();
    float acc = bias[n];
    #pragma unroll
    for (int r=0; r<DIM; ++r) acc += hS[r]*w[r*OUTD+n];
    xc[b*256 + n] = fmaxf(acc, 0.f);
}

// ---------------- protein branch ----------------

// conv_w (OIH fp32) -> cwT (fp16, layout [i][o*8+k], row = 256 halfs = 512B)
__global__ __launch_bounds__(256) void k_cw_transpose(
    const float* __restrict__ cw, __half* __restrict__ cwT)
{
    int g = blockIdx.x*256 + threadIdx.x;   // 256000 total
    int i = g >> 8;
    int j = g & 255;
    int o = j >> 3, k = j & 7;
    cwT[g] = __float2half(cw[o*(PLEN*KS) + i*KS + k]);
}

// Phase 1: LDS counting-sort of 1000 tokens by vocab.
// Phase 2: row-PAIR uint4 loads (lanes 0-31 even row, 32-63 odd row) + fp16
//          8-deep tree accumulate (v_pk_add_f16) flushed to fp32; cross-half
//          merge via shfl_xor(32). Buckets partitioned over the 4 waves.
// Phase 3: conv as G x emb with b128 LDS reads; emb staged in 2 chunks of 13
//          rows (stride 156, skew f(t)=t+4*(t>>4): 16B-aligned + bank-clean).
__global__ __launch_bounds__(256) void k_conv(
    const int* __restrict__ target, const float* __restrict__ emb,
    const __half* __restrict__ cwTh, const float* __restrict__ conv_b,
    float* __restrict__ c)
{
    __shared__ __align__(16) float Gs[VOCAB*256];   // 26,624B; reused as out-stage
    __shared__ __align__(16) float U[2080];         // 8,320B: sortedS ∪ emb chunk
    __shared__ int meta[3*VOCAB+2];                 // cnt / seg / cur
    __shared__ float cbS[NF];
    int* sortedS = (int*)U;
    int* cntS = meta;
    int* segS = meta + VOCAB;          // [VOCAB+1]
    int* curS = meta + 2*VOCAB + 1;
    int b = blockIdx.x, j = threadIdx.x;
    if (j < VOCAB) cntS[j] = 0;
    if (j < NF) cbS[j] = conv_b[j];
    __syncthreads();
    // ---- phase 1: counting sort ----
    int tloc[4];
    #pragma unroll
    for (int q=0; q<4; ++q) {
        int i = j + q*256;
        if (i < PLEN) {
            tloc[q] = target[b*PLEN+i];
            atomicAdd(&cntS[tloc[q]], 1);
        } else tloc[q] = -1;
    }
    __syncthreads();
    if (j == 0) {
        int run = 0;
        for (int v=0; v<VOCAB; ++v) { segS[v]=run; run += cntS[v]; }
        segS[VOCAB] = run;
    }
    __syncthreads();
    if (j < VOCAB) curS[j] = segS[j];
    __syncthreads();
    #pragma unroll
    for (int q=0; q<4; ++q) {
        int i = j + q*256;
        if (i < PLEN) {
            int pos = atomicAdd(&curS[tloc[q]], 1);
            sortedS[pos] = i;
        }
    }
    __syncthreads();
    // ---- phase 2: row-pair uint4 accumulate, buckets split over waves ----
    int w = j >> 6;
    int lane = j & 63;
    int half32 = lane >> 5;              // 0: even-index rows, 1: odd
    int c32 = lane & 31;                 // owns cols 8*c32..8*c32+7
    const uint4* cw4 = (const uint4*)cwTh;   // row = 32 uint4 (512B)
    __half2 hz = __float2half2_rn(0.f);
    for (int v=0; v<VOCAB; ++v) {
        int s = segS[v], e2 = segS[v+1];
        int wv = s / 250; if (wv > 3) wv = 3;
        if (wv != w) continue;
        float facc[8];
        #pragma unroll
        for (int q=0; q<8; ++q) facc[q] = 0.f;
        int p = s;
        for (; p+16 <= e2; p += 16) {    // 8 pairs; each lane sums 8 rows in fp16
            __half2 h0=hz, h1=hz, h2=hz, h3=hz;
            #pragma unroll
            for (int u=0; u<8; ++u) {
                int i0 = sortedS[p+2*u], i1 = sortedS[p+2*u+1];
                int row = half32 ? i1 : i0;
                uint4 q4 = cw4[row*32 + c32];
                const __half2* hh = (const __half2*)&q4;
                h0 = __hadd2(h0, hh[0]); h1 = __hadd2(h1, hh[1]);
                h2 = __hadd2(h2, hh[2]); h3 = __hadd2(h3, hh[3]);
            }
            float2 f0=__half22float2(h0), f1=__half22float2(h1),
                   f2=__half22float2(h2), f3=__half22float2(h3);
            facc[0]+=f0.x; facc[1]+=f0.y; facc[2]+=f1.x; facc[3]+=f1.y;
            facc[4]+=f2.x; facc[5]+=f2.y; facc[6]+=f3.x; facc[7]+=f3.y;
        }
        for (; p+2 <= e2; p += 2) {      // tail pairs in fp32
            int i0 = sortedS[p], i1 = sortedS[p+1];
            int row = half32 ? i1 : i0;
            uint4 q4 = cw4[row*32 + c32];
            const __half2* hh = (const __half2*)&q4;
            float2 f0=__half22float2(hh[0]), f1=__half22float2(hh[1]),
                   f2=__half22float2(hh[2]), f3=__half22float2(hh[3]);
            facc[0]+=f0.x; facc[1]+=f0.y; facc[2]+=f1.x; facc[3]+=f1.y;
            facc[4]+=f2.x; facc[5]+=f2.y; facc[6]+=f3.x; facc[7]+=f3.y;
        }
        if (p < e2 && half32 == 0) {     // leftover single row, lower half only
            uint4 q4 = cw4[sortedS[p]*32 + c32];
            const __half2* hh = (const __half2*)&q4;
            float2 f0=__half22float2(hh[0]), f1=__half22float2(hh[1]),
                   f2=__half22float2(hh[2]), f3=__half22float2(hh[3]);
            facc[0]+=f0.x; facc[1]+=f0.y; facc[2]+=f1.x; facc[3]+=f1.y;
            facc[4]+=f2.x; facc[5]+=f2.y; facc[6]+=f3.x; facc[7]+=f3.y;
        }
        #pragma unroll
        for (int q=0; q<8; ++q) facc[q] += __shfl_xor(facc[q], 32, 64);
        if (half32 == 0) {
            float4* gp = (float4*)(Gs + v*256 + c32*8);
            gp[0] = make_float4(facc[0], facc[1], facc[2], facc[3]);
            gp[1] = make_float4(facc[4], facc[5], facc[6], facc[7]);
        }
    }
    // ---- phase 3: conv, emb chunked through U ----
    int o = j >> 3, pg = j & 7;
    int t0 = pg*16;
    int tcnt = (t0+16 <= CLEN) ? 16 : (CLEN - t0);   // 16 or 9
    float out[16];
    #pragma unroll
    for (int q=0; q<16; ++q) out[q] = cbS[o];
    for (int ch=0; ch<2; ++ch) {
        __syncthreads();     // chunk 0: protect sortedS; chunk 1: protect prev emb
        for (int i=j; i<ECHUNK*EMBD; i+=256) {
            int v = i >> 7, tt = i & 127;
            U[v*EROW2 + tt + 4*(tt>>4)] = emb[(ch*ECHUNK + v)*EMBD + tt];
        }
        __syncthreads();
        for (int vv=0; vv<ECHUNK; ++vv) {
            const float4* gp = (const float4*)(Gs + (ch*ECHUNK+vv)*256 + o*8);
            float4 g0 = gp[0], g1 = gp[1];
            float g[8] = {g0.x,g0.y,g0.z,g0.w,g1.x,g1.y,g1.z,g1.w};
            const float* ev = &U[vv*EROW2 + 20*pg];
            float4 E0 = *(const float4*)(ev);
            float4 E1 = *(const float4*)(ev+4);
            float4 E2 = *(const float4*)(ev+8);
            float4 E3 = *(const float4*)(ev+12);
            float4 E4 = *(const float4*)(ev+20);
            float4 E5 = *(const float4*)(ev+24);
            float e[24] = {E0.x,E0.y,E0.z,E0.w, E1.x,E1.y,E1.z,E1.w,
                           E2.x,E2.y,E2.z,E2.w, E3.x,E3.y,E3.z,E3.w,
                           E4.x,E4.y,E4.z,E4.w, E5.x,E5.y,E5.z,E5.w};
            #pragma unroll
            for (int q=0; q<16; ++q) {
                float s = 0.f;
                #pragma unroll
                for (int k=0; k<KS; ++k) s += e[q+k]*g[k];
                out[q] += s;
            }
        }
    }
    __syncthreads();
    float* stage = Gs;
    for (int q=0; q<tcnt; ++q) stage[o*CLEN + t0 + q] = out[q];
    __syncthreads();
    for (int idx=j; idx<FCX; idx+=256)
        c[(long)b*FCX + idx] = stage[idx];
}

// xt: [1024 x 3872] @ [3872 x 128], grid (64 graph-tiles x 16 K-splits) =
// 1024 blocks -> 4 blocks/CU (was 256 blocks = 1/CU, latency-bound).
// Per block: 16 graphs x 242-K slice, 11 chunks of BK=22; 2x4 register tile.
#define XT_GB  16
#define XT_NS  16
#define XT_KS  (FCX/XT_NS)   // 242
#define XT_BK  22
#define XT_NCH (XT_KS/XT_BK) // 11
__global__ __launch_bounds__(256) void k_xt(
    const float* __restrict__ c, const float* __restrict__ w,
    const float* __restrict__ bias, float* __restrict__ xc)
{
    __shared__ float cS[XT_GB][XT_BK];    // 1.4 KB
    __shared__ float wS[XT_BK][128];      // 11.3 KB
    int b0 = blockIdx.x * XT_GB;
    int ks0 = blockIdx.y * XT_KS;
    int tid = threadIdx.x;
    int g2 = tid >> 5;          // graph pair 0..7 -> graphs 2g2, 2g2+1
    int co = tid & 31;          // cols co*4..co*4+3
    float acc[2][4];
    #pragma unroll
    for (int q=0; q<2; ++q)
      #pragma unroll
      for (int p=0; p<4; ++p) acc[q][p] = 0.f;
    for (int ch=0; ch<XT_NCH; ++ch) {
        int k0 = ks0 + ch*XT_BK;
        for (int idx=tid; idx<XT_GB*XT_BK; idx+=256) {
            int g = idx / XT_BK, kk = idx - g*XT_BK;
            cS[g][kk] = c[(long)(b0+g)*FCX + k0 + kk];
        }
        for (int idx=tid; idx<XT_BK*128; idx+=256) {
            int kk = idx >> 7, n = idx & 127;
            wS[kk][n] = w[(long)(k0+kk)*OUTD + n];
        }
        __syncthreads();
        #pragma unroll
        for (int k2=0; k2<XT_BK/2; ++k2) {
            float2 cv0 = *(const float2*)&cS[2*g2  ][2*k2];
            float2 cv1 = *(const float2*)&cS[2*g2+1][2*k2];
            float4 wv0 = *(const float4*)&wS[2*k2  ][co*4];
            float4 wv1 = *(const float4*)&wS[2*k2+1][co*4];
            acc[0][0]+=cv0.x*wv0.x; acc[0][1]+=cv0.x*wv0.y;
            acc[0][2]+=cv0.x*wv0.z; acc[0][3]+=cv0.x*wv0.w;
            acc[1][0]+=cv1.x*wv0.x; acc[1][1]+=cv1.x*wv0.y;
            acc[1][2]+=cv1.x*wv0.z; acc[1][3]+=cv1.x*wv0.w;
            acc[0][0]+=cv0.y*wv1.x; acc[0][1]+=cv0.y*wv1.y;
            acc[0][2]+=cv0.y*wv1.z; acc[0][3]+=cv0.y*wv1.w;
            acc[1][0]+=cv1.y*wv1.x; acc[1][1]+=cv1.y*wv1.y;
            acc[1][2]+=cv1.y*wv1.z; acc[1][3]+=cv1.y*wv1.w;
        }
        __syncthreads();
    }
    #pragma unroll
    for (int q=0; q<2; ++q) {
        int g = b0 + 2*g2 + q;
        #pragma unroll
        for (int p=0; p<4; ++p) {
            int n = co*4 + p;
            float v = acc[q][p];
            if (blockIdx.y == 0) v += bias[n];
            atomicAdd(&xc[g*256 + 128 + n], v);
        }
    }
}

// ---------------- joint head ----------------

__global__ __launch_bounds__(256) void k_fc1(
    const float* __restrict__ xc, const float* __restrict__ w,
    const float* __restrict__ bias, float* __restrict__ y)
{
    __shared__ float xS[4][256];
    int b0 = blockIdx.x*4, n = threadIdx.x;
    #pragma unroll
    for (int q=0; q<4; ++q) xS[q][n] = xc[(b0+q)*256 + n];
    __syncthreads();
    float acc[4][4];
    #pragma unroll
    for (int m=0; m<4; ++m) {
        float bv = bias[m*256+n];
        #pragma unroll
        for (int q=0; q<4; ++q) acc[q][m] = bv;
    }
    for (int r=0; r<256; ++r) {
        float x0=xS[0][r], x1=xS[1][r], x2=xS[2][r], x3=xS[3][r];
        #pragma unroll
        for (int m=0; m<4; ++m) {
            float wv = w[r*1024 + m*256 + n];
            acc[0][m]+=x0*wv; acc[1][m]+=x1*wv; acc[2][m]+=x2*wv; acc[3][m]+=x3*wv;
        }
    }
    #pragma unroll
    for (int q=0; q<4; ++q)
        #pragma unroll
        for (int m=0; m<4; ++m)
            y[(b0+q)*1024 + m*256 + n] = fmaxf(acc[q][m], 0.f);
}

__global__ __launch_bounds__(256) void k_fc2(
    const float* __restrict__ y, const float* __restrict__ w,
    const float* __restrict__ bias, float* __restrict__ y2)
{
    __shared__ float xS[4][1024];
    int b0 = blockIdx.x*4, n = threadIdx.x;
    #pragma unroll
    for (int q=0; q<4; ++q)
        for (int i=n; i<1024; i+=256) xS[q][i] = y[(b0+q)*1024 + i];
    __syncthreads();
    float acc[4];
    #pragma unroll
    for (int q=0; q<4; ++q) acc[q] = bias[n];
    for (int r=0; r<1024; ++r) {
        float wv = w[r*256 + n];
        #pragma unroll
        for (int q=0; q<4; ++q) acc[q] += xS[q][r]*wv;
    }
    #pragma unroll
    for (int q=0; q<4; ++q) y2[(b0+q)*256 + n] = fmaxf(acc[q], 0.f);
}

__global__ __launch_bounds__(256) void k_out(
    const float* __restrict__ y2, const float* __restrict__ w,
    const float* __restrict__ bias, float* __restrict__ out)
{
    int b = blockIdx.x, n = threadIdx.x;
    float v = y2[b*256 + n] * w[n];
    #pragma unroll
    for (int off=32; off; off>>=1) v += __shfl_down(v, off, 64);
    __shared__ float red[4];
    if ((n & 63) == 0) red[n >> 6] = v;
    __syncthreads();
    if (n == 0) out[b] = red[0]+red[1]+red[2]+red[3] + bias[0];
}

// ---------------- launch ----------------

extern "C" void kernel_launch(void* const* d_in, const int* in_sizes, int n_in,
                              void* d_out, int out_size, void* d_ws, size_t ws_size,
                              hipStream_t stream) {
    const float* x      = (const float*)d_in[0];
    const int*   ei     = (const int*)  d_in[1];
    const int*   batch  = (const int*)  d_in[2];
    const int*   target = (const int*)  d_in[3];
    const float* w1a    = (const float*)d_in[4];
    const float* b1a    = (const float*)d_in[5];
    const float* w1b    = (const float*)d_in[6];
    const float* b1b    = (const float*)d_in[7];
    const float* wa     = (const float*)d_in[8];
    const float* ba     = (const float*)d_in[9];
    const float* wb     = (const float*)d_in[10];
    const float* bb     = (const float*)d_in[11];
    const float* gamma  = (const float*)d_in[12];
    const float* beta   = (const float*)d_in[13];
    const float* w_fcxd = (const float*)d_in[14];
    const float* b_fcxd = (const float*)d_in[15];
    const float* emb    = (const float*)d_in[16];
    const float* conv_w = (const float*)d_in[17];
    const float* conv_b = (const float*)d_in[18];
    const float* w_fcxt = (const float*)d_in[19];
    const float* b_fcxt = (const float*)d_in[20];
    const float* w_fc1  = (const float*)d_in[21];
    const float* b_fc1  = (const float*)d_in[22];
    const float* w_fc2  = (const float*)d_in[23];
    const float* b_fc2  = (const float*)d_in[24];
    const float* w_out  = (const float*)d_in[25];
    const float* b_out  = (const float*)d_in[26];

    float* ws      = (float*)d_ws;
    __half* tH     = (__half*)ws;                          // N*32 halfs = 1,048,576 float-slots
    float* z       = ws + 1048576;                         // N*32 floats
    unsigned int* pairs = (unsigned int*)(z + (size_t)N_NODES*DIM);  // E uints
    int*   csr     = (int*)(pairs + N_EDGES);              // E ints
    int*   rowptr  = csr + N_EDGES;                        // N+1 (+pad)
    int*   bktCnt  = rowptr + (N_NODES + 8);               // 256
    int*   bktBase = bktCnt + 256;                         // 257 (+pad)
    int*   bktCur  = bktBase + 264;                        // 256
    float* ss      = (float*)(bktCur + 256);               // 64
    float* hg      = ss + 64;                              // 32768
    float* cwT     = hg + (size_t)NB*DIM;                  // 256000 float-slots (fp16 uses half)
    float* cbuf    = cwT + 256000;                         // 3964928
    float* xc      = cbuf + (size_t)NB*FCX;                // 262144
    float* y1      = xc + (size_t)NB*256;                  // 1048576
    float* y2      = y1 + (size_t)NB*1024;                 // 262144
    float* part    = y2 + (size_t)NB*256;                  // 256*64
    __half* cwTh   = (__half*)cwT;

    // ---- CSR build: bucket sort (coalesced) + fused rowptr/scatter ----
    hipMemsetAsync(bktCnt, 0, 256*sizeof(int), stream);
    k_bhist<<<N_EDGES/1024, 256, 0, stream>>>(ei, bktCnt);
    k_bscan<<<1, 256, 0, stream>>>(bktCnt, bktBase, bktCur);
    k_bucketA<<<NBKT, 256, 0, stream>>>(ei, bktCur, pairs);
    k_fillB<<<NBKT, 256, 0, stream>>>(bktBase, pairs, rowptr, csr);

    // ---- protein branch ----
    hipMemsetAsync(xc, 0, (size_t)NB*256*sizeof(float), stream);
    k_cw_transpose<<<1000, 256, 0, stream>>>(conv_w, cwTh);
    k_conv<<<NB, 256, 0, stream>>>(target, emb, cwTh, conv_b, cbuf);
    k_xt<<<dim3(NB/XT_GB, XT_NS), 256, 0, stream>>>(cbuf, w_fcxt, b_fcxt, xc);

    // ---- GIN layers ----
    hipMemsetAsync(part, 0, NSLICE*64*sizeof(float), stream);
    for (int l=0; l<5; ++l) {
        if (l == 0)
            k_l1_transform<<<N_NODES/256, 256, 0, stream>>>(x, w1a, tH);
        else
            k_transform<<<N_NODES/256, 256, 0, stream>>>(z, ss, wa + (size_t)(l-1)*DIM*DIM, tH);
        const float* bi = (l==0) ? b1a : ba + (size_t)(l-1)*DIM;
        const float* wo = (l==0) ? w1b : wb + (size_t)(l-1)*DIM*DIM;
        const float* bo = (l==0) ? b1b : bb + (size_t)(l-1)*DIM;
        k_gather_mlp<<<N_NODES/32, 256, 0, stream>>>(rowptr, csr, tH, bi, wo, bo, z, part);
        k_scaleshift<<<1, 256, 0, stream>>>(part, gamma, beta, l, ss);
    }

    // ---- pool + drug head ----
    hipMemsetAsync(hg, 0, (size_t)NB*DIM*sizeof(float), stream);
    k_pool<<<N_NODES/32, 256, 0, stream>>>(z, ss, batch, hg);
    k_xd<<<NB, 128, 0, stream>>>(hg, w_fcxd, b_fcxd, xc);

    // ---- joint head ----
    k_fc1<<<NB/4, 256, 0, stream>>>(xc, w_fc1, b_fc1, y1);
    k_fc2<<<NB/4, 256, 0, stream>>>(y1, w_fc2, b_fc2, y2);
    k_out<<<NB, 256, 0, stream>>>(y2, w_out, b_out, (float*)d_out);
}

// Round 5
// 738.887 us; speedup vs baseline: 1.0760x; 1.0310x over previous
//
#include <hip/hip_runtime.h>
#include <hip/hip_fp16.h>

#define N_NODES 65536
#define N_EDGES 2097152
#define NB      1024
#define FXD     78
#define DIM     32
#define EMBD    128
#define OUTD    128
#define VOCAB   26
#define PLEN    1000
#define KS      8
#define CLEN    121      // EMBD-KS+1
#define NF      32
#define FCX     (NF*CLEN)  // 3872
#define NBKT    256
#define EPB     8192     // edges per bucketA block (N_EDGES/256)
#define NSLICE  256      // stats partial slices
#define EROW2   156      // emb row stride (floats): f(t)=t+4*(t>>4), f(127)=155
#define ECHUNK  13       // emb rows staged per chunk (2 chunks x 13 = 26)

// ---------------- bucket sort (dst>>8) ----------------

__global__ __launch_bounds__(256) void k_bhist(
    const int* __restrict__ ei, int* __restrict__ bktCnt)
{
    __shared__ int h[NBKT];
    int tid = threadIdx.x;
    h[tid] = 0;
    __syncthreads();
    int base = blockIdx.x*1024;
    #pragma unroll
    for (int q=0; q<4; ++q) {
        int d = ei[N_EDGES + base + q*256 + tid];
        atomicAdd(&h[d>>8], 1);
    }
    __syncthreads();
    atomicAdd(&bktCnt[tid], h[tid]);
}

__global__ __launch_bounds__(256) void k_bscan(
    const int* __restrict__ bktCnt, int* __restrict__ bktBase, int* __restrict__ bktCur)
{
    __shared__ int s[NBKT];
    int t = threadIdx.x;
    int v = bktCnt[t];
    s[t] = v;
    __syncthreads();
    for (int off=1; off<256; off<<=1) {
        int tv = (t >= off) ? s[t-off] : 0;
        __syncthreads();
        s[t] += tv;
        __syncthreads();
    }
    int ex = s[t] - v;
    bktBase[t] = ex;
    bktCur[t] = ex;
    if (t == 255) bktBase[256] = s[255];   // == N_EDGES
}

// LDS-sort 8192 edges by bucket, write packed (dst<<16|src) in coalesced runs
__global__ __launch_bounds__(256) void k_bucketA(
    const int* __restrict__ ei, int* __restrict__ bktCur, unsigned int* __restrict__ pairs)
{
    __shared__ unsigned int raw[EPB];       // 32 KB
    __shared__ unsigned int srt[EPB];       // 32 KB
    __shared__ unsigned char bOf[EPB];      // 8 KB
    __shared__ int hist[NBKT], sc[NBKT], lcur[NBKT], gbase[NBKT];
    int tid = threadIdx.x;
    hist[tid] = 0;
    __syncthreads();
    int eb = blockIdx.x * EPB;
    for (int i=tid; i<EPB; i+=256) {
        int s = ei[eb+i];
        int d = ei[N_EDGES+eb+i];
        raw[i] = ((unsigned int)d<<16) | (unsigned int)s;
        atomicAdd(&hist[d>>8], 1);
    }
    __syncthreads();
    int v = hist[tid];
    sc[tid] = v;
    __syncthreads();
    for (int off=1; off<256; off<<=1) {
        int tv = (tid >= off) ? sc[tid-off] : 0;
        __syncthreads();
        sc[tid] += tv;
        __syncthreads();
    }
    int ex = sc[tid] - v;
    sc[tid] = ex;            // exclusive local base
    lcur[tid] = ex;
    gbase[tid] = atomicAdd(&bktCur[tid], v);
    __syncthreads();
    for (int i=tid; i<EPB; i+=256) {
        unsigned int p = raw[i];
        int k = p >> 24;
        int pos = atomicAdd(&lcur[k], 1);
        srt[pos] = p;
        bOf[pos] = (unsigned char)k;
    }
    __syncthreads();
    for (int i=tid; i<EPB; i+=256) {
        int k = bOf[i];
        pairs[gbase[k] + (i - sc[k])] = srt[i];
    }
}

// per bucket: build rowptr (LDS histogram + scan) and scatter srcs into the
// bucket's contiguous CSR segment.
__global__ __launch_bounds__(256) void k_fillB(
    const int* __restrict__ bktBase, const unsigned int* __restrict__ pairs,
    int* __restrict__ rowptr, int* __restrict__ csr)
{
    __shared__ int hist[256], sc[256], cur[256];
    int b = blockIdx.x, tid = threadIdx.x;
    int node0 = b*256;
    hist[tid] = 0;
    __syncthreads();
    int s = bktBase[b], e = bktBase[b+1];
    for (int i = s + tid; i < e; i += 256)
        atomicAdd(&hist[(pairs[i] >> 16) & 255], 1);
    __syncthreads();
    int v = hist[tid];
    sc[tid] = v;
    __syncthreads();
    for (int off=1; off<256; off<<=1) {
        int tv = (tid >= off) ? sc[tid-off] : 0;
        __syncthreads();
        sc[tid] += tv;
        __syncthreads();
    }
    int base = s + sc[tid] - v;     // exclusive
    rowptr[node0 + tid] = base;
    cur[tid] = base;
    if (b == NBKT-1 && tid == 255) rowptr[N_NODES] = N_EDGES;
    __syncthreads();
    for (int i = s + tid; i < e; i += 256) {
        unsigned int p = pairs[i];
        int pos = atomicAdd(&cur[(p >> 16) & 255], 1);
        csr[pos] = (int)(p & 0xFFFFu);
    }
}

// ---------------- GIN layer kernels ----------------

// Layer-1 transform: t = x @ w1a  (fp16 out)
__global__ __launch_bounds__(256) void k_l1_transform(
    const float* __restrict__ x, const float* __restrict__ w,
    __half* __restrict__ t)
{
    __shared__ float wS[FXD*DIM];
    for (int i = threadIdx.x; i < FXD*DIM; i += 256) wS[i] = w[i];
    __syncthreads();
    int node = blockIdx.x*256 + threadIdx.x;
    float acc[DIM];
    #pragma unroll
    for (int d=0; d<DIM; ++d) acc[d] = 0.f;
    const float* xr = x + (long)node*FXD;
    for (int j=0; j<FXD; ++j) {
        float xv = xr[j];
        #pragma unroll
        for (int d=0; d<DIM; ++d) acc[d] += xv * wS[j*DIM+d];
    }
    union { __half2 h2[16]; uint4 u4[4]; } pk;
    #pragma unroll
    for (int q=0; q<16; ++q) pk.h2[q] = __floats2half2_rn(acc[2*q], acc[2*q+1]);
    uint4* dst4 = (uint4*)(t + (long)node*DIM);
    #pragma unroll
    for (int q=0; q<4; ++q) dst4[q] = pk.u4[q];
}

// Layers 2-5: h = BN(z) via scale/shift; t = h @ w  (fp16 out)
__global__ __launch_bounds__(256) void k_transform(
    const float* __restrict__ z, const float* __restrict__ ss,
    const float* __restrict__ w, __half* __restrict__ t)
{
    __shared__ float wS[DIM*DIM];
    __shared__ float sS[2*DIM];
    for (int i = threadIdx.x; i < DIM*DIM; i += 256) wS[i] = w[i];
    if (threadIdx.x < 2*DIM) sS[threadIdx.x] = ss[threadIdx.x];
    __syncthreads();
    int node = blockIdx.x*256 + threadIdx.x;
    float h[DIM];
    const float4* z4 = (const float4*)(z + (long)node*DIM);
    #pragma unroll
    for (int q=0; q<DIM/4; ++q) {
        float4 v = z4[q];
        h[q*4+0]=v.x; h[q*4+1]=v.y; h[q*4+2]=v.z; h[q*4+3]=v.w;
    }
    #pragma unroll
    for (int d=0; d<DIM; ++d) h[d] = h[d]*sS[d] + sS[DIM+d];
    float acc[DIM];
    #pragma unroll
    for (int d=0; d<DIM; ++d) acc[d] = 0.f;
    #pragma unroll
    for (int j=0; j<DIM; ++j) {
        float hv = h[j];
        #pragma unroll
        for (int d=0; d<DIM; ++d) acc[d] += hv * wS[j*DIM+d];
    }
    union { __half2 h2[16]; uint4 u4[4]; } pk;
    #pragma unroll
    for (int q=0; q<16; ++q) pk.h2[q] = __floats2half2_rn(acc[2*q], acc[2*q+1]);
    uint4* dst4 = (uint4*)(t + (long)node*DIM);
    #pragma unroll
    for (int q=0; q<4; ++q) dst4[q] = pk.u4[q];
}

// Gather (CSR) + self + MLP + ReLU + BN-stats partials.
__global__ __launch_bounds__(256) void k_gather_mlp(
    const int* __restrict__ rowptr, const int* __restrict__ csr,
    const __half* __restrict__ t,
    const float* __restrict__ bi, const float* __restrict__ wo, const float* __restrict__ bo,
    float* __restrict__ z, float* __restrict__ part)
{
    __shared__ float wS[DIM*DIM];
    __shared__ float bS[2*DIM];
    __shared__ float stS[2*DIM];
    int tid = threadIdx.x;
    for (int i=tid; i<DIM*DIM; i+=256) wS[i]=wo[i];
    if (tid<DIM) bS[tid]=bi[tid];
    else if (tid<2*DIM) bS[tid]=bo[tid-DIM];
    if (tid<2*DIM) stS[tid]=0.f;
    __syncthreads();
    int g = tid >> 3;           // node 0..31 within block
    int l = tid & 7;            // lane in group; owns channels 4l..4l+3
    int node = blockIdx.x*32 + g;
    const uint2* t4 = (const uint2*)t;   // 8B = 4 halfs; 8 entries per row
    uint2 sv = t4[(long)node*8 + l];     // self term
    float2 p0 = __half22float2(*(const __half2*)&sv.x);
    float2 p1 = __half22float2(*(const __half2*)&sv.y);
    float a0=p0.x, a1=p0.y, a2=p1.x, a3=p1.y;
    float c0=0.f, c1=0.f, c2=0.f, c3=0.f;
    int s0 = rowptr[node], s1 = rowptr[node+1];
    int e = s0;
    for (; e+8 <= s1; e+=8) {
        int myIdx = csr[e + l];          // 8 consecutive, coalesced
        #pragma unroll
        for (int k=0; k<8; ++k) {
            int idx = __shfl(myIdx, k, 8);
            uint2 v = t4[(long)idx*8 + l];
            float2 q0 = __half22float2(*(const __half2*)&v.x);
            float2 q1 = __half22float2(*(const __half2*)&v.y);
            if (k & 1) { c0+=q0.x; c1+=q0.y; c2+=q1.x; c3+=q1.y; }
            else       { a0+=q0.x; a1+=q0.y; a2+=q1.x; a3+=q1.y; }
        }
    }
    if (e+4 <= s1) {
        int myIdx = csr[e + (l & 3)];
        #pragma unroll
        for (int k=0; k<4; ++k) {
            int idx = __shfl(myIdx, k, 8);
            uint2 v = t4[(long)idx*8 + l];
            float2 q0 = __half22float2(*(const __half2*)&v.x);
            float2 q1 = __half22float2(*(const __half2*)&v.y);
            if (k & 1) { c0+=q0.x; c1+=q0.y; c2+=q1.x; c3+=q1.y; }
            else       { a0+=q0.x; a1+=q0.y; a2+=q1.x; a3+=q1.y; }
        }
        e += 4;
    }
    for (; e<s1; ++e) {
        uint2 v = t4[(long)csr[e]*8 + l];
        float2 q0 = __half22float2(*(const __half2*)&v.x);
        float2 q1 = __half22float2(*(const __half2*)&v.y);
        a0+=q0.x; a1+=q0.y; a2+=q1.x; a3+=q1.y;
    }
    float ua[4];
    ua[0] = fmaxf(a0+c0 + bS[4*l+0], 0.f);
    ua[1] = fmaxf(a1+c1 + bS[4*l+1], 0.f);
    ua[2] = fmaxf(a2+c2 + bS[4*l+2], 0.f);
    ua[3] = fmaxf(a3+c3 + bS[4*l+3], 0.f);
    float zz[4];
    #pragma unroll
    for (int q=0; q<4; ++q) zz[q] = bS[DIM + 4*l + q];
    const float4* w4 = (const float4*)wS;
    #pragma unroll
    for (int j=0; j<DIM; ++j) {
        float uj = __shfl(ua[j & 3], j >> 2, 8);
        float4 wv = w4[j*8 + l];
        zz[0]+=uj*wv.x; zz[1]+=uj*wv.y; zz[2]+=uj*wv.z; zz[3]+=uj*wv.w;
    }
    #pragma unroll
    for (int q=0; q<4; ++q) zz[q] = fmaxf(zz[q], 0.f);
    ((float4*)z)[(long)node*8 + l] = make_float4(zz[0], zz[1], zz[2], zz[3]);
    // stats: reduce the 8 node-groups of each wave down to 8 lanes
    float sr[4], qr[4];
    #pragma unroll
    for (int q=0; q<4; ++q) { sr[q] = zz[q]; qr[q] = zz[q]*zz[q]; }
    #pragma unroll
    for (int q=0; q<4; ++q) {
        sr[q] += __shfl_down(sr[q], 32, 64); qr[q] += __shfl_down(qr[q], 32, 64);
        sr[q] += __shfl_down(sr[q], 16, 64); qr[q] += __shfl_down(qr[q], 16, 64);
        sr[q] += __shfl_down(sr[q],  8, 64); qr[q] += __shfl_down(qr[q],  8, 64);
    }
    if ((tid & 63) < 8) {
        #pragma unroll
        for (int q=0; q<4; ++q) {
            atomicAdd(&stS[4*l+q],       sr[q]);
            atomicAdd(&stS[DIM+4*l+q],   qr[q]);
        }
    }
    __syncthreads();
    if (tid < 2*DIM)
        atomicAdd(&part[((blockIdx.x & (NSLICE-1))<<6) + tid], stS[tid]);
}

// reduce partial stats -> scale/shift; re-zero partials for next layer
__global__ __launch_bounds__(256) void k_scaleshift(
    float* __restrict__ part,
    const float* __restrict__ gamma, const float* __restrict__ beta,
    int layer, float* __restrict__ ss)
{
    __shared__ float red[4][64];
    __shared__ float totS[64];
    int t = threadIdx.x;
    int ch = t & 63, q = t >> 6;
    float s = 0.f;
    for (int i = q*64; i < q*64 + 64; ++i) s += part[(i<<6) + ch];
    red[q][ch] = s;
    __syncthreads();
    if (t < 64) totS[t] = red[0][t]+red[1][t]+red[2][t]+red[3][t];
    __syncthreads();
    if (t < DIM) {
        float mean = totS[t] * (1.f/N_NODES);
        float var  = totS[DIM+t] * (1.f/N_NODES) - mean*mean;
        float sc = gamma[layer*DIM+t] * rsqrtf(var + 1e-5f);
        ss[t] = sc;
        ss[DIM+t] = beta[layer*DIM+t] - mean*sc;
    }
    for (int i = t; i < NSLICE*64; i += 256) part[i] = 0.f;
}

// Global add pool with BN applied: hg[batch[n]] += BN(z[n]).
// batch is sorted -> a wave's 8 nodes usually share one graph: wave-reduce
// then 1/8 the atomics.
__global__ __launch_bounds__(256) void k_pool(
    const float* __restrict__ z, const float* __restrict__ ss,
    const int* __restrict__ batch, float* __restrict__ hg)
{
    int tid = threadIdx.x;
    int node = blockIdx.x*32 + (tid>>3);
    int cq = tid & 7;                      // channels 4cq..4cq+3
    float4 v = ((const float4*)z)[(long)node*8 + cq];
    float4 sc = ((const float4*)ss)[cq];
    float4 sh = ((const float4*)ss)[8 + cq];
    v.x = v.x*sc.x + sh.x; v.y = v.y*sc.y + sh.y;
    v.z = v.z*sc.z + sh.z; v.w = v.w*sc.w + sh.w;
    int b = batch[node];
    int b0 = __shfl(b, 0, 64);
    int b7 = __shfl(b, 63, 64);
    if (b0 == b7) {
        #pragma unroll
        for (int off=8; off<64; off<<=1) {
            v.x += __shfl_xor(v.x, off, 64);
            v.y += __shfl_xor(v.y, off, 64);
            v.z += __shfl_xor(v.z, off, 64);
            v.w += __shfl_xor(v.w, off, 64);
        }
        if ((tid & 63) < 8) {
            float* dst = hg + (long)b0*DIM + cq*4;
            atomicAdd(dst+0, v.x); atomicAdd(dst+1, v.y);
            atomicAdd(dst+2, v.z); atomicAdd(dst+3, v.w);
        }
    } else {
        float* dst = hg + (long)b*DIM + cq*4;
        atomicAdd(dst+0, v.x); atomicAdd(dst+1, v.y);
        atomicAdd(dst+2, v.z); atomicAdd(dst+3, v.w);
    }
}

// xd = ReLU(hg @ w_fcxd + b) -> xc[:, 0:128]
__global__ __launch_bounds__(128) void k_xd(
    const float* __restrict__ hg, const float* __restrict__ w,
    const float* __restrict__ bias, float* __restrict__ xc)
{
    int b = blockIdx.x, n = threadIdx.x;
    __shared__ float hS[DIM];
    if (n < DIM) hS[n] = hg[b*DIM+n];
    __syncthreads();
    float acc = bias[n];
    #pragma unroll
    for (int r=0; r<DIM; ++r) acc += hS[r]*w[r*OUTD+n];
    xc[b*256 + n] = fmaxf(acc, 0.f);
}

// ---------------- protein branch ----------------

// conv_w (OIH fp32) -> cwT (fp16, layout [i][o*8+k], row = 256 halfs = 512B)
__global__ __launch_bounds__(256) void k_cw_transpose(
    const float* __restrict__ cw, __half* __restrict__ cwT)
{
    int g = blockIdx.x*256 + threadIdx.x;   // 256000 total
    int i = g >> 8;
    int j = g & 255;
    int o = j >> 3, k = j & 7;
    cwT[g] = __float2half(cw[o*(PLEN*KS) + i*KS + k]);
}

// Phase 1: LDS counting-sort of 1000 tokens by vocab.
// Phase 2: row-PAIR uint4 loads (lanes 0-31 even row, 32-63 odd row) + fp16
//          8-deep tree accumulate (v_pk_add_f16) flushed to fp32; cross-half
//          merge via shfl_xor(32). Buckets partitioned over the 4 waves.
// Phase 3: conv as G x emb with b128 LDS reads; emb staged in 2 chunks of 13
//          rows (stride 156, skew f(t)=t+4*(t>>4): 16B-aligned + bank-clean).
__global__ __launch_bounds__(256) void k_conv(
    const int* __restrict__ target, const float* __restrict__ emb,
    const __half* __restrict__ cwTh, const float* __restrict__ conv_b,
    float* __restrict__ c)
{
    __shared__ __align__(16) float Gs[VOCAB*256];   // 26,624B; reused as out-stage
    __shared__ __align__(16) float U[2080];         // 8,320B: sortedS ∪ emb chunk
    __shared__ int meta[3*VOCAB+2];                 // cnt / seg / cur
    __shared__ float cbS[NF];
    int* sortedS = (int*)U;
    int* cntS = meta;
    int* segS = meta + VOCAB;          // [VOCAB+1]
    int* curS = meta + 2*VOCAB + 1;
    int b = blockIdx.x, j = threadIdx.x;
    if (j < VOCAB) cntS[j] = 0;
    if (j < NF) cbS[j] = conv_b[j];
    __syncthreads();
    // ---- phase 1: counting sort ----
    int tloc[4];
    #pragma unroll
    for (int q=0; q<4; ++q) {
        int i = j + q*256;
        if (i < PLEN) {
            tloc[q] = target[b*PLEN+i];
            atomicAdd(&cntS[tloc[q]], 1);
        } else tloc[q] = -1;
    }
    __syncthreads();
    if (j == 0) {
        int run = 0;
        for (int v=0; v<VOCAB; ++v) { segS[v]=run; run += cntS[v]; }
        segS[VOCAB] = run;
    }
    __syncthreads();
    if (j < VOCAB) curS[j] = segS[j];
    __syncthreads();
    #pragma unroll
    for (int q=0; q<4; ++q) {
        int i = j + q*256;
        if (i < PLEN) {
            int pos = atomicAdd(&curS[tloc[q]], 1);
            sortedS[pos] = i;
        }
    }
    __syncthreads();
    // ---- phase 2: row-pair uint4 accumulate, buckets split over waves ----
    int w = j >> 6;
    int lane = j & 63;
    int half32 = lane >> 5;              // 0: even-index rows, 1: odd
    int c32 = lane & 31;                 // owns cols 8*c32..8*c32+7
    const uint4* cw4 = (const uint4*)cwTh;   // row = 32 uint4 (512B)
    __half2 hz = __float2half2_rn(0.f);
    for (int v=0; v<VOCAB; ++v) {
        int s = segS[v], e2 = segS[v+1];
        int wv = s / 250; if (wv > 3) wv = 3;
        if (wv != w) continue;
        float facc[8];
        #pragma unroll
        for (int q=0; q<8; ++q) facc[q] = 0.f;
        int p = s;
        for (; p+16 <= e2; p += 16) {    // 8 pairs; each lane sums 8 rows in fp16
            __half2 h0=hz, h1=hz, h2=hz, h3=hz;
            #pragma unroll
            for (int u=0; u<8; ++u) {
                int i0 = sortedS[p+2*u], i1 = sortedS[p+2*u+1];
                int row = half32 ? i1 : i0;
                uint4 q4 = cw4[row*32 + c32];
                const __half2* hh = (const __half2*)&q4;
                h0 = __hadd2(h0, hh[0]); h1 = __hadd2(h1, hh[1]);
                h2 = __hadd2(h2, hh[2]); h3 = __hadd2(h3, hh[3]);
            }
            float2 f0=__half22float2(h0), f1=__half22float2(h1),
                   f2=__half22float2(h2), f3=__half22float2(h3);
            facc[0]+=f0.x; facc[1]+=f0.y; facc[2]+=f1.x; facc[3]+=f1.y;
            facc[4]+=f2.x; facc[5]+=f2.y; facc[6]+=f3.x; facc[7]+=f3.y;
        }
        for (; p+2 <= e2; p += 2) {      // tail pairs in fp32
            int i0 = sortedS[p], i1 = sortedS[p+1];
            int row = half32 ? i1 : i0;
            uint4 q4 = cw4[row*32 + c32];
            const __half2* hh = (const __half2*)&q4;
            float2 f0=__half22float2(hh[0]), f1=__half22float2(hh[1]),
                   f2=__half22float2(hh[2]), f3=__half22float2(hh[3]);
            facc[0]+=f0.x; facc[1]+=f0.y; facc[2]+=f1.x; facc[3]+=f1.y;
            facc[4]+=f2.x; facc[5]+=f2.y; facc[6]+=f3.x; facc[7]+=f3.y;
        }
        if (p < e2 && half32 == 0) {     // leftover single row, lower half only
            uint4 q4 = cw4[sortedS[p]*32 + c32];
            const __half2* hh = (const __half2*)&q4;
            float2 f0=__half22float2(hh[0]), f1=__half22float2(hh[1]),
                   f2=__half22float2(hh[2]), f3=__half22float2(hh[3]);
            facc[0]+=f0.x; facc[1]+=f0.y; facc[2]+=f1.x; facc[3]+=f1.y;
            facc[4]+=f2.x; facc[5]+=f2.y; facc[6]+=f3.x; facc[7]+=f3.y;
        }
        #pragma unroll
        for (int q=0; q<8; ++q) facc[q] += __shfl_xor(facc[q], 32, 64);
        if (half32 == 0) {
            float4* gp = (float4*)(Gs + v*256 + c32*8);
            gp[0] = make_float4(facc[0], facc[1], facc[2], facc[3]);
            gp[1] = make_float4(facc[4], facc[5], facc[6], facc[7]);
        }
    }
    // ---- phase 3: conv, emb chunked through U ----
    int o = j >> 3, pg = j & 7;
    int t0 = pg*16;
    int tcnt = (t0+16 <= CLEN) ? 16 : (CLEN - t0);   // 16 or 9
    float out[16];
    #pragma unroll
    for (int q=0; q<16; ++q) out[q] = cbS[o];
    for (int ch=0; ch<2; ++ch) {
        __syncthreads();     // chunk 0: protect sortedS; chunk 1: protect prev emb
        for (int i=j; i<ECHUNK*EMBD; i+=256) {
            int v = i >> 7, tt = i & 127;
            U[v*EROW2 + tt + 4*(tt>>4)] = emb[(ch*ECHUNK + v)*EMBD + tt];
        }
        __syncthreads();
        for (int vv=0; vv<ECHUNK; ++vv) {
            const float4* gp = (const float4*)(Gs + (ch*ECHUNK+vv)*256 + o*8);
            float4 g0 = gp[0], g1 = gp[1];
            float g[8] = {g0.x,g0.y,g0.z,g0.w,g1.x,g1.y,g1.z,g1.w};
            const float* ev = &U[vv*EROW2 + 20*pg];
            float4 E0 = *(const float4*)(ev);
            float4 E1 = *(const float4*)(ev+4);
            float4 E2 = *(const float4*)(ev+8);
            float4 E3 = *(const float4*)(ev+12);
            float4 E4 = *(const float4*)(ev+20);
            float4 E5 = *(const float4*)(ev+24);
            float e[24] = {E0.x,E0.y,E0.z,E0.w, E1.x,E1.y,E1.z,E1.w,
                           E2.x,E2.y,E2.z,E2.w, E3.x,E3.y,E3.z,E3.w,
                           E4.x,E4.y,E4.z,E4.w, E5.x,E5.y,E5.z,E5.w};
            #pragma unroll
            for (int q=0; q<16; ++q) {
                float s = 0.f;
                #pragma unroll
                for (int k=0; k<KS; ++k) s += e[q+k]*g[k];
                out[q] += s;
            }
        }
    }
    __syncthreads();
    float* stage = Gs;
    for (int q=0; q<tcnt; ++q) stage[o*CLEN + t0 + q] = out[q];
    __syncthreads();
    for (int idx=j; idx<FCX; idx+=256)
        c[(long)b*FCX + idx] = stage[idx];
}

// xt: [1024 x 3872] @ [3872 x 128], grid (64 graph-tiles x 16 K-splits).
// NO atomics: each K-split stores partials to xtp[y][g][n] (plain float4),
// k_xt_red sums them. Staging is register-prefetched (load ch+1 during
// compute of ch) to hide L2 latency.
#define XT_GB  16
#define XT_NS  16
#define XT_KS  (FCX/XT_NS)   // 242
#define XT_BK  22
#define XT_NCH (XT_KS/XT_BK) // 11
__global__ __launch_bounds__(256) void k_xt(
    const float* __restrict__ c, const float* __restrict__ w,
    float* __restrict__ xtp)
{
    __shared__ float cS[XT_GB][XT_BK];    // 1.4 KB
    __shared__ float wS[XT_BK][128];      // 11.3 KB
    int b0 = blockIdx.x * XT_GB;
    int ks0 = blockIdx.y * XT_KS;
    int tid = threadIdx.x;
    int g2 = tid >> 5;          // graph pair 0..7 -> graphs 2g2, 2g2+1
    int co = tid & 31;          // cols co*4..co*4+3
    int cg0 = tid / XT_BK, ck0 = tid - cg0*XT_BK;          // cS slot 0
    int i1 = tid + 256;
    int cg1 = i1 / XT_BK, ck1 = i1 - cg1*XT_BK;            // cS slot 1 (tid<96)
    float wreg[11], creg0, creg1;
    // prologue: load chunk 0 into regs
    {
        int k0 = ks0;
        #pragma unroll
        for (int q=0; q<11; ++q) {
            int idx = tid + q*256;
            wreg[q] = w[(long)(k0 + (idx>>7))*OUTD + (idx & 127)];
        }
        creg0 = c[(long)(b0+cg0)*FCX + k0 + ck0];
        if (tid < 96) creg1 = c[(long)(b0+cg1)*FCX + k0 + ck1];
    }
    float acc[2][4];
    #pragma unroll
    for (int q=0; q<2; ++q)
      #pragma unroll
      for (int p=0; p<4; ++p) acc[q][p] = 0.f;
    for (int ch=0; ch<XT_NCH; ++ch) {
        // stage regs -> LDS
        #pragma unroll
        for (int q=0; q<11; ++q) {
            int idx = tid + q*256;
            wS[idx>>7][idx & 127] = wreg[q];
        }
        cS[cg0][ck0] = creg0;
        if (tid < 96) cS[cg1][ck1] = creg1;
        __syncthreads();
        // issue next chunk's loads (overlap with compute below)
        if (ch+1 < XT_NCH) {
            int k0 = ks0 + (ch+1)*XT_BK;
            #pragma unroll
            for (int q=0; q<11; ++q) {
                int idx = tid + q*256;
                wreg[q] = w[(long)(k0 + (idx>>7))*OUTD + (idx & 127)];
            }
            creg0 = c[(long)(b0+cg0)*FCX + k0 + ck0];
            if (tid < 96) creg1 = c[(long)(b0+cg1)*FCX + k0 + ck1];
        }
        #pragma unroll
        for (int k2=0; k2<XT_BK/2; ++k2) {
            float2 cv0 = *(const float2*)&cS[2*g2  ][2*k2];
            float2 cv1 = *(const float2*)&cS[2*g2+1][2*k2];
            float4 wv0 = *(const float4*)&wS[2*k2  ][co*4];
            float4 wv1 = *(const float4*)&wS[2*k2+1][co*4];
            acc[0][0]+=cv0.x*wv0.x; acc[0][1]+=cv0.x*wv0.y;
            acc[0][2]+=cv0.x*wv0.z; acc[0][3]+=cv0.x*wv0.w;
            acc[1][0]+=cv1.x*wv0.x; acc[1][1]+=cv1.x*wv0.y;
            acc[1][2]+=cv1.x*wv0.z; acc[1][3]+=cv1.x*wv0.w;
            acc[0][0]+=cv0.y*wv1.x; acc[0][1]+=cv0.y*wv1.y;
            acc[0][2]+=cv0.y*wv1.z; acc[0][3]+=cv0.y*wv1.w;
            acc[1][0]+=cv1.y*wv1.x; acc[1][1]+=cv1.y*wv1.y;
            acc[1][2]+=cv1.y*wv1.z; acc[1][3]+=cv1.y*wv1.w;
        }
        __syncthreads();
    }
    #pragma unroll
    for (int q=0; q<2; ++q) {
        int g = b0 + 2*g2 + q;
        float4* dst = (float4*)(xtp + ((long)blockIdx.y*NB + g)*128);
        dst[co] = make_float4(acc[q][0], acc[q][1], acc[q][2], acc[q][3]);
    }
}

// sum the 16 K-split partials + bias -> xc[:, 128:256)
__global__ __launch_bounds__(256) void k_xt_red(
    const float* __restrict__ xtp, const float* __restrict__ bias,
    float* __restrict__ xc)
{
    int p = blockIdx.x*256 + threadIdx.x;   // 32768 float4 slots
    int g = p >> 5, c4 = p & 31;
    const float4* src = (const float4*)xtp;
    float4 s = src[(long)g*32 + c4];
    #pragma unroll
    for (int y=1; y<XT_NS; ++y) {
        float4 v = src[((long)y*NB + g)*32 + c4];
        s.x += v.x; s.y += v.y; s.z += v.z; s.w += v.w;
    }
    float4 bv = ((const float4*)bias)[c4];
    s.x += bv.x; s.y += bv.y; s.z += bv.z; s.w += bv.w;
    ((float4*)(xc + g*256 + 128))[c4] = s;
}

// ---------------- joint head ----------------

__global__ __launch_bounds__(256) void k_fc1(
    const float* __restrict__ xc, const float* __restrict__ w,
    const float* __restrict__ bias, float* __restrict__ y)
{
    __shared__ float xS[4][256];
    int b0 = blockIdx.x*4, n = threadIdx.x;
    #pragma unroll
    for (int q=0; q<4; ++q) xS[q][n] = xc[(b0+q)*256 + n];
    __syncthreads();
    float acc[4][4];
    #pragma unroll
    for (int m=0; m<4; ++m) {
        float bv = bias[m*256+n];
        #pragma unroll
        for (int q=0; q<4; ++q) acc[q][m] = bv;
    }
    for (int r=0; r<256; ++r) {
        float x0=xS[0][r], x1=xS[1][r], x2=xS[2][r], x3=xS[3][r];
        #pragma unroll
        for (int m=0; m<4; ++m) {
            float wv = w[r*1024 + m*256 + n];
            acc[0][m]+=x0*wv; acc[1][m]+=x1*wv; acc[2][m]+=x2*wv; acc[3][m]+=x3*wv;
        }
    }
    #pragma unroll
    for (int q=0; q<4; ++q)
        #pragma unroll
        for (int m=0; m<4; ++m)
            y[(b0+q)*1024 + m*256 + n] = fmaxf(acc[q][m], 0.f);
}

__global__ __launch_bounds__(256) void k_fc2(
    const float* __restrict__ y, const float* __restrict__ w,
    const float* __restrict__ bias, float* __restrict__ y2)
{
    __shared__ float xS[4][1024];
    int b0 = blockIdx.x*4, n = threadIdx.x;
    #pragma unroll
    for (int q=0; q<4; ++q)
        for (int i=n; i<1024; i+=256) xS[q][i] = y[(b0+q)*1024 + i];
    __syncthreads();
    float acc[4];
    #pragma unroll
    for (int q=0; q<4; ++q) acc[q] = bias[n];
    for (int r=0; r<1024; ++r) {
        float wv = w[r*256 + n];
        #pragma unroll
        for (int q=0; q<4; ++q) acc[q] += xS[q][r]*wv;
    }
    #pragma unroll
    for (int q=0; q<4; ++q) y2[(b0+q)*256 + n] = fmaxf(acc[q], 0.f);
}

__global__ __launch_bounds__(256) void k_out(
    const float* __restrict__ y2, const float* __restrict__ w,
    const float* __restrict__ bias, float* __restrict__ out)
{
    int b = blockIdx.x, n = threadIdx.x;
    float v = y2[b*256 + n] * w[n];
    #pragma unroll
    for (int off=32; off; off>>=1) v += __shfl_down(v, off, 64);
    __shared__ float red[4];
    if ((n & 63) == 0) red[n >> 6] = v;
    __syncthreads();
    if (n == 0) out[b] = red[0]+red[1]+red[2]+red[3] + bias[0];
}

// ---------------- launch ----------------

extern "C" void kernel_launch(void* const* d_in, const int* in_sizes, int n_in,
                              void* d_out, int out_size, void* d_ws, size_t ws_size,
                              hipStream_t stream) {
    const float* x      = (const float*)d_in[0];
    const int*   ei     = (const int*)  d_in[1];
    const int*   batch  = (const int*)  d_in[2];
    const int*   target = (const int*)  d_in[3];
    const float* w1a    = (const float*)d_in[4];
    const float* b1a    = (const float*)d_in[5];
    const float* w1b    = (const float*)d_in[6];
    const float* b1b    = (const float*)d_in[7];
    const float* wa     = (const float*)d_in[8];
    const float* ba     = (const float*)d_in[9];
    const float* wb     = (const float*)d_in[10];
    const float* bb     = (const float*)d_in[11];
    const float* gamma  = (const float*)d_in[12];
    const float* beta   = (const float*)d_in[13];
    const float* w_fcxd = (const float*)d_in[14];
    const float* b_fcxd = (const float*)d_in[15];
    const float* emb    = (const float*)d_in[16];
    const float* conv_w = (const float*)d_in[17];
    const float* conv_b = (const float*)d_in[18];
    const float* w_fcxt = (const float*)d_in[19];
    const float* b_fcxt = (const float*)d_in[20];
    const float* w_fc1  = (const float*)d_in[21];
    const float* b_fc1  = (const float*)d_in[22];
    const float* w_fc2  = (const float*)d_in[23];
    const float* b_fc2  = (const float*)d_in[24];
    const float* w_out  = (const float*)d_in[25];
    const float* b_out  = (const float*)d_in[26];

    float* ws      = (float*)d_ws;
    __half* tH     = (__half*)ws;                          // N*32 halfs = 1,048,576 float-slots
    float* z       = ws + 1048576;                         // N*32 floats (= 8 MB)
    unsigned int* pairs = (unsigned int*)(z + (size_t)N_NODES*DIM);  // E uints
    int*   csr     = (int*)(pairs + N_EDGES);              // E ints
    int*   rowptr  = csr + N_EDGES;                        // N+1 (+pad)
    int*   bktCnt  = rowptr + (N_NODES + 8);               // 256
    int*   bktBase = bktCnt + 256;                         // 257 (+pad)
    int*   bktCur  = bktBase + 264;                        // 256
    float* ss      = (float*)(bktCur + 256);               // 64
    float* hg      = ss + 64;                              // 32768
    float* cwT     = hg + (size_t)NB*DIM;                  // 256000 float-slots (fp16 uses half)
    float* cbuf    = cwT + 256000;                         // 3964928
    float* xc      = cbuf + (size_t)NB*FCX;                // 262144
    float* y1      = xc + (size_t)NB*256;                  // 1048576
    float* y2      = y1 + (size_t)NB*1024;                 // 262144
    float* part    = y2 + (size_t)NB*256;                  // 256*64
    __half* cwTh   = (__half*)cwT;
    float* xtp     = z;   // xt partials [16][1024][128] = 2,097,152 floats:
                          // aliases z (first GIN write to z happens after xt_red)

    // ---- CSR build: bucket sort (coalesced) + fused rowptr/scatter ----
    hipMemsetAsync(bktCnt, 0, 256*sizeof(int), stream);
    k_bhist<<<N_EDGES/1024, 256, 0, stream>>>(ei, bktCnt);
    k_bscan<<<1, 256, 0, stream>>>(bktCnt, bktBase, bktCur);
    k_bucketA<<<NBKT, 256, 0, stream>>>(ei, bktCur, pairs);
    k_fillB<<<NBKT, 256, 0, stream>>>(bktBase, pairs, rowptr, csr);

    // ---- protein branch ----
    k_cw_transpose<<<1000, 256, 0, stream>>>(conv_w, cwTh);
    k_conv<<<NB, 256, 0, stream>>>(target, emb, cwTh, conv_b, cbuf);
    k_xt<<<dim3(NB/XT_GB, XT_NS), 256, 0, stream>>>(cbuf, w_fcxt, xtp);
    k_xt_red<<<(NB*DIM)/256, 256, 0, stream>>>(xtp, b_fcxt, xc);

    // ---- GIN layers ----
    hipMemsetAsync(part, 0, NSLICE*64*sizeof(float), stream);
    for (int l=0; l<5; ++l) {
        if (l == 0)
            k_l1_transform<<<N_NODES/256, 256, 0, stream>>>(x, w1a, tH);
        else
            k_transform<<<N_NODES/256, 256, 0, stream>>>(z, ss, wa + (size_t)(l-1)*DIM*DIM, tH);
        const float* bi = (l==0) ? b1a : ba + (size_t)(l-1)*DIM;
        const float* wo = (l==0) ? w1b : wb + (size_t)(l-1)*DIM*DIM;
        const float* bo = (l==0) ? b1b : bb + (size_t)(l-1)*DIM;
        k_gather_mlp<<<N_NODES/32, 256, 0, stream>>>(rowptr, csr, tH, bi, wo, bo, z, part);
        k_scaleshift<<<1, 256, 0, stream>>>(part, gamma, beta, l, ss);
    }

    // ---- pool + drug head ----
    hipMemsetAsync(hg, 0, (size_t)NB*DIM*sizeof(float), stream);
    k_pool<<<N_NODES/32, 256, 0, stream>>>(z, ss, batch, hg);
    k_xd<<<NB, 128, 0, stream>>>(hg, w_fcxd, b_fcxd, xc);

    // ---- joint head ----
    k_fc1<<<NB/4, 256, 0, stream>>>(xc, w_fc1, b_fc1, y1);
    k_fc2<<<NB/4, 256, 0, stream>>>(y1, w_fc2, b_fc2, y2);
    k_out<<<NB, 256, 0, stream>>>(y2, w_out, b_out, (float*)d_out);
}

// Round 6
// 686.532 us; speedup vs baseline: 1.1581x; 1.0763x over previous
//
#include <hip/hip_runtime.h>
#include <hip/hip_fp16.h>

#define N_NODES 65536
#define N_EDGES 2097152
#define NB      1024
#define FXD     78
#define DIM     32
#define EMBD    128
#define OUTD    128
#define VOCAB   26
#define PLEN    1000
#define KS      8
#define CLEN    121      // EMBD-KS+1
#define NF      32
#define FCX     (NF*CLEN)  // 3872
#define NBKT    256
#define EPB     8192     // edges per bucketA block (N_EDGES/256)
#define NSLICE  256      // stats partial slices
#define EROW2   156      // emb row stride (floats): f(t)=t+4*(t>>4), f(127)=155
#define ECHUNK  13       // emb rows staged per chunk (2 chunks x 13 = 26)

// ---------------- bucket sort (dst>>8) ----------------

__global__ __launch_bounds__(256) void k_bhist(
    const int* __restrict__ ei, int* __restrict__ bktCnt)
{
    __shared__ int h[NBKT];
    int tid = threadIdx.x;
    h[tid] = 0;
    __syncthreads();
    int base = blockIdx.x*1024;
    #pragma unroll
    for (int q=0; q<4; ++q) {
        int d = ei[N_EDGES + base + q*256 + tid];
        atomicAdd(&h[d>>8], 1);
    }
    __syncthreads();
    atomicAdd(&bktCnt[tid], h[tid]);
}

__global__ __launch_bounds__(256) void k_bscan(
    const int* __restrict__ bktCnt, int* __restrict__ bktBase, int* __restrict__ bktCur)
{
    __shared__ int s[NBKT];
    int t = threadIdx.x;
    int v = bktCnt[t];
    s[t] = v;
    __syncthreads();
    for (int off=1; off<256; off<<=1) {
        int tv = (t >= off) ? s[t-off] : 0;
        __syncthreads();
        s[t] += tv;
        __syncthreads();
    }
    int ex = s[t] - v;
    bktBase[t] = ex;
    bktCur[t] = ex;
    if (t == 255) bktBase[256] = s[255];   // == N_EDGES
}

// LDS-sort 8192 edges by bucket, write packed (dst<<16|src) in coalesced runs
__global__ __launch_bounds__(256) void k_bucketA(
    const int* __restrict__ ei, int* __restrict__ bktCur, unsigned int* __restrict__ pairs)
{
    __shared__ unsigned int raw[EPB];       // 32 KB
    __shared__ unsigned int srt[EPB];       // 32 KB
    __shared__ unsigned char bOf[EPB];      // 8 KB
    __shared__ int hist[NBKT], sc[NBKT], lcur[NBKT], gbase[NBKT];
    int tid = threadIdx.x;
    hist[tid] = 0;
    __syncthreads();
    int eb = blockIdx.x * EPB;
    for (int i=tid; i<EPB; i+=256) {
        int s = ei[eb+i];
        int d = ei[N_EDGES+eb+i];
        raw[i] = ((unsigned int)d<<16) | (unsigned int)s;
        atomicAdd(&hist[d>>8], 1);
    }
    __syncthreads();
    int v = hist[tid];
    sc[tid] = v;
    __syncthreads();
    for (int off=1; off<256; off<<=1) {
        int tv = (tid >= off) ? sc[tid-off] : 0;
        __syncthreads();
        sc[tid] += tv;
        __syncthreads();
    }
    int ex = sc[tid] - v;
    sc[tid] = ex;            // exclusive local base
    lcur[tid] = ex;
    gbase[tid] = atomicAdd(&bktCur[tid], v);
    __syncthreads();
    for (int i=tid; i<EPB; i+=256) {
        unsigned int p = raw[i];
        int k = p >> 24;
        int pos = atomicAdd(&lcur[k], 1);
        srt[pos] = p;
        bOf[pos] = (unsigned char)k;
    }
    __syncthreads();
    for (int i=tid; i<EPB; i+=256) {
        int k = bOf[i];
        pairs[gbase[k] + (i - sc[k])] = srt[i];
    }
}

// per bucket: build rowptr (LDS histogram + scan) and scatter srcs into the
// bucket's contiguous CSR segment.
__global__ __launch_bounds__(256) void k_fillB(
    const int* __restrict__ bktBase, const unsigned int* __restrict__ pairs,
    int* __restrict__ rowptr, int* __restrict__ csr)
{
    __shared__ int hist[256], sc[256], cur[256];
    int b = blockIdx.x, tid = threadIdx.x;
    int node0 = b*256;
    hist[tid] = 0;
    __syncthreads();
    int s = bktBase[b], e = bktBase[b+1];
    for (int i = s + tid; i < e; i += 256)
        atomicAdd(&hist[(pairs[i] >> 16) & 255], 1);
    __syncthreads();
    int v = hist[tid];
    sc[tid] = v;
    __syncthreads();
    for (int off=1; off<256; off<<=1) {
        int tv = (tid >= off) ? sc[tid-off] : 0;
        __syncthreads();
        sc[tid] += tv;
        __syncthreads();
    }
    int base = s + sc[tid] - v;     // exclusive
    rowptr[node0 + tid] = base;
    cur[tid] = base;
    if (b == NBKT-1 && tid == 255) rowptr[N_NODES] = N_EDGES;
    __syncthreads();
    for (int i = s + tid; i < e; i += 256) {
        unsigned int p = pairs[i];
        int pos = atomicAdd(&cur[(p >> 16) & 255], 1);
        csr[pos] = (int)(p & 0xFFFFu);
    }
}

// ---------------- GIN layer kernels ----------------

// Layer-1 transform: t = x @ w1a  (fp16 out)
__global__ __launch_bounds__(256) void k_l1_transform(
    const float* __restrict__ x, const float* __restrict__ w,
    __half* __restrict__ t)
{
    __shared__ float wS[FXD*DIM];
    for (int i = threadIdx.x; i < FXD*DIM; i += 256) wS[i] = w[i];
    __syncthreads();
    int node = blockIdx.x*256 + threadIdx.x;
    float acc[DIM];
    #pragma unroll
    for (int d=0; d<DIM; ++d) acc[d] = 0.f;
    const float* xr = x + (long)node*FXD;
    for (int j=0; j<FXD; ++j) {
        float xv = xr[j];
        #pragma unroll
        for (int d=0; d<DIM; ++d) acc[d] += xv * wS[j*DIM+d];
    }
    union { __half2 h2[16]; uint4 u4[4]; } pk;
    #pragma unroll
    for (int q=0; q<16; ++q) pk.h2[q] = __floats2half2_rn(acc[2*q], acc[2*q+1]);
    uint4* dst4 = (uint4*)(t + (long)node*DIM);
    #pragma unroll
    for (int q=0; q<4; ++q) dst4[q] = pk.u4[q];
}

// Layers 2-5: h = BN(z) via scale/shift; t = h @ w  (fp16 out)
__global__ __launch_bounds__(256) void k_transform(
    const float* __restrict__ z, const float* __restrict__ ss,
    const float* __restrict__ w, __half* __restrict__ t)
{
    __shared__ float wS[DIM*DIM];
    __shared__ float sS[2*DIM];
    for (int i = threadIdx.x; i < DIM*DIM; i += 256) wS[i] = w[i];
    if (threadIdx.x < 2*DIM) sS[threadIdx.x] = ss[threadIdx.x];
    __syncthreads();
    int node = blockIdx.x*256 + threadIdx.x;
    float h[DIM];
    const float4* z4 = (const float4*)(z + (long)node*DIM);
    #pragma unroll
    for (int q=0; q<DIM/4; ++q) {
        float4 v = z4[q];
        h[q*4+0]=v.x; h[q*4+1]=v.y; h[q*4+2]=v.z; h[q*4+3]=v.w;
    }
    #pragma unroll
    for (int d=0; d<DIM; ++d) h[d] = h[d]*sS[d] + sS[DIM+d];
    float acc[DIM];
    #pragma unroll
    for (int d=0; d<DIM; ++d) acc[d] = 0.f;
    #pragma unroll
    for (int j=0; j<DIM; ++j) {
        float hv = h[j];
        #pragma unroll
        for (int d=0; d<DIM; ++d) acc[d] += hv * wS[j*DIM+d];
    }
    union { __half2 h2[16]; uint4 u4[4]; } pk;
    #pragma unroll
    for (int q=0; q<16; ++q) pk.h2[q] = __floats2half2_rn(acc[2*q], acc[2*q+1]);
    uint4* dst4 = (uint4*)(t + (long)node*DIM);
    #pragma unroll
    for (int q=0; q<4; ++q) dst4[q] = pk.u4[q];
}

// Gather (CSR) + self + MLP + ReLU + BN-stats partials.
__global__ __launch_bounds__(256) void k_gather_mlp(
    const int* __restrict__ rowptr, const int* __restrict__ csr,
    const __half* __restrict__ t,
    const float* __restrict__ bi, const float* __restrict__ wo, const float* __restrict__ bo,
    float* __restrict__ z, float* __restrict__ part)
{
    __shared__ float wS[DIM*DIM];
    __shared__ float bS[2*DIM];
    __shared__ float stS[2*DIM];
    int tid = threadIdx.x;
    for (int i=tid; i<DIM*DIM; i+=256) wS[i]=wo[i];
    if (tid<DIM) bS[tid]=bi[tid];
    else if (tid<2*DIM) bS[tid]=bo[tid-DIM];
    if (tid<2*DIM) stS[tid]=0.f;
    __syncthreads();
    int g = tid >> 3;           // node 0..31 within block
    int l = tid & 7;            // lane in group; owns channels 4l..4l+3
    int node = blockIdx.x*32 + g;
    const uint2* t4 = (const uint2*)t;   // 8B = 4 halfs; 8 entries per row
    uint2 sv = t4[(long)node*8 + l];     // self term
    float2 p0 = __half22float2(*(const __half2*)&sv.x);
    float2 p1 = __half22float2(*(const __half2*)&sv.y);
    float a0=p0.x, a1=p0.y, a2=p1.x, a3=p1.y;
    float c0=0.f, c1=0.f, c2=0.f, c3=0.f;
    int s0 = rowptr[node], s1 = rowptr[node+1];
    int e = s0;
    for (; e+8 <= s1; e+=8) {
        int myIdx = csr[e + l];          // 8 consecutive, coalesced
        #pragma unroll
        for (int k=0; k<8; ++k) {
            int idx = __shfl(myIdx, k, 8);
            uint2 v = t4[(long)idx*8 + l];
            float2 q0 = __half22float2(*(const __half2*)&v.x);
            float2 q1 = __half22float2(*(const __half2*)&v.y);
            if (k & 1) { c0+=q0.x; c1+=q0.y; c2+=q1.x; c3+=q1.y; }
            else       { a0+=q0.x; a1+=q0.y; a2+=q1.x; a3+=q1.y; }
        }
    }
    if (e+4 <= s1) {
        int myIdx = csr[e + (l & 3)];
        #pragma unroll
        for (int k=0; k<4; ++k) {
            int idx = __shfl(myIdx, k, 8);
            uint2 v = t4[(long)idx*8 + l];
            float2 q0 = __half22float2(*(const __half2*)&v.x);
            float2 q1 = __half22float2(*(const __half2*)&v.y);
            if (k & 1) { c0+=q0.x; c1+=q0.y; c2+=q1.x; c3+=q1.y; }
            else       { a0+=q0.x; a1+=q0.y; a2+=q1.x; a3+=q1.y; }
        }
        e += 4;
    }
    for (; e<s1; ++e) {
        uint2 v = t4[(long)csr[e]*8 + l];
        float2 q0 = __half22float2(*(const __half2*)&v.x);
        float2 q1 = __half22float2(*(const __half2*)&v.y);
        a0+=q0.x; a1+=q0.y; a2+=q1.x; a3+=q1.y;
    }
    float ua[4];
    ua[0] = fmaxf(a0+c0 + bS[4*l+0], 0.f);
    ua[1] = fmaxf(a1+c1 + bS[4*l+1], 0.f);
    ua[2] = fmaxf(a2+c2 + bS[4*l+2], 0.f);
    ua[3] = fmaxf(a3+c3 + bS[4*l+3], 0.f);
    float zz[4];
    #pragma unroll
    for (int q=0; q<4; ++q) zz[q] = bS[DIM + 4*l + q];
    const float4* w4 = (const float4*)wS;
    #pragma unroll
    for (int j=0; j<DIM; ++j) {
        float uj = __shfl(ua[j & 3], j >> 2, 8);
        float4 wv = w4[j*8 + l];
        zz[0]+=uj*wv.x; zz[1]+=uj*wv.y; zz[2]+=uj*wv.z; zz[3]+=uj*wv.w;
    }
    #pragma unroll
    for (int q=0; q<4; ++q) zz[q] = fmaxf(zz[q], 0.f);
    ((float4*)z)[(long)node*8 + l] = make_float4(zz[0], zz[1], zz[2], zz[3]);
    // stats: reduce the 8 node-groups of each wave down to 8 lanes
    float sr[4], qr[4];
    #pragma unroll
    for (int q=0; q<4; ++q) { sr[q] = zz[q]; qr[q] = zz[q]*zz[q]; }
    #pragma unroll
    for (int q=0; q<4; ++q) {
        sr[q] += __shfl_down(sr[q], 32, 64); qr[q] += __shfl_down(qr[q], 32, 64);
        sr[q] += __shfl_down(sr[q], 16, 64); qr[q] += __shfl_down(qr[q], 16, 64);
        sr[q] += __shfl_down(sr[q],  8, 64); qr[q] += __shfl_down(qr[q],  8, 64);
    }
    if ((tid & 63) < 8) {
        #pragma unroll
        for (int q=0; q<4; ++q) {
            atomicAdd(&stS[4*l+q],       sr[q]);
            atomicAdd(&stS[DIM+4*l+q],   qr[q]);
        }
    }
    __syncthreads();
    if (tid < 2*DIM)
        atomicAdd(&part[((blockIdx.x & (NSLICE-1))<<6) + tid], stS[tid]);
}

// reduce partial stats -> scale/shift; re-zero partials for next layer
__global__ __launch_bounds__(256) void k_scaleshift(
    float* __restrict__ part,
    const float* __restrict__ gamma, const float* __restrict__ beta,
    int layer, float* __restrict__ ss)
{
    __shared__ float red[4][64];
    __shared__ float totS[64];
    int t = threadIdx.x;
    int ch = t & 63, q = t >> 6;
    float s = 0.f;
    for (int i = q*64; i < q*64 + 64; ++i) s += part[(i<<6) + ch];
    red[q][ch] = s;
    __syncthreads();
    if (t < 64) totS[t] = red[0][t]+red[1][t]+red[2][t]+red[3][t];
    __syncthreads();
    if (t < DIM) {
        float mean = totS[t] * (1.f/N_NODES);
        float var  = totS[DIM+t] * (1.f/N_NODES) - mean*mean;
        float sc = gamma[layer*DIM+t] * rsqrtf(var + 1e-5f);
        ss[t] = sc;
        ss[DIM+t] = beta[layer*DIM+t] - mean*sc;
    }
    for (int i = t; i < NSLICE*64; i += 256) part[i] = 0.f;
}

// Global add pool with BN applied: hg[batch[n]] += BN(z[n]).
// batch is sorted -> a wave's 8 nodes usually share one graph: wave-reduce
// then 1/8 the atomics.
__global__ __launch_bounds__(256) void k_pool(
    const float* __restrict__ z, const float* __restrict__ ss,
    const int* __restrict__ batch, float* __restrict__ hg)
{
    int tid = threadIdx.x;
    int node = blockIdx.x*32 + (tid>>3);
    int cq = tid & 7;                      // channels 4cq..4cq+3
    float4 v = ((const float4*)z)[(long)node*8 + cq];
    float4 sc = ((const float4*)ss)[cq];
    float4 sh = ((const float4*)ss)[8 + cq];
    v.x = v.x*sc.x + sh.x; v.y = v.y*sc.y + sh.y;
    v.z = v.z*sc.z + sh.z; v.w = v.w*sc.w + sh.w;
    int b = batch[node];
    int b0 = __shfl(b, 0, 64);
    int b7 = __shfl(b, 63, 64);
    if (b0 == b7) {
        #pragma unroll
        for (int off=8; off<64; off<<=1) {
            v.x += __shfl_xor(v.x, off, 64);
            v.y += __shfl_xor(v.y, off, 64);
            v.z += __shfl_xor(v.z, off, 64);
            v.w += __shfl_xor(v.w, off, 64);
        }
        if ((tid & 63) < 8) {
            float* dst = hg + (long)b0*DIM + cq*4;
            atomicAdd(dst+0, v.x); atomicAdd(dst+1, v.y);
            atomicAdd(dst+2, v.z); atomicAdd(dst+3, v.w);
        }
    } else {
        float* dst = hg + (long)b*DIM + cq*4;
        atomicAdd(dst+0, v.x); atomicAdd(dst+1, v.y);
        atomicAdd(dst+2, v.z); atomicAdd(dst+3, v.w);
    }
}

// xd = ReLU(hg @ w_fcxd + b) -> xc[:, 0:128]
__global__ __launch_bounds__(128) void k_xd(
    const float* __restrict__ hg, const float* __restrict__ w,
    const float* __restrict__ bias, float* __restrict__ xc)
{
    int b = blockIdx.x, n = threadIdx.x;
    __shared__ float hS[DIM];
    if (n < DIM) hS[n] = hg[b*DIM+n];
    __syncthreads();
    float acc = bias[n];
    #pragma unroll
    for (int r=0; r<DIM; ++r) acc += hS[r]*w[r*OUTD+n];
    xc[b*256 + n] = fmaxf(acc, 0.f);
}

// ---------------- protein branch ----------------

// conv_w (OIH fp32) -> cwT (fp16, layout [i][o*8+k], row = 256 halfs = 512B)
__global__ __launch_bounds__(256) void k_cw_transpose(
    const float* __restrict__ cw, __half* __restrict__ cwT)
{
    int g = blockIdx.x*256 + threadIdx.x;   // 256000 total
    int i = g >> 8;
    int j = g & 255;
    int o = j >> 3, k = j & 7;
    cwT[g] = __float2half(cw[o*(PLEN*KS) + i*KS + k]);
}

// Phase 1: LDS counting-sort of 1000 tokens by vocab.
// Phase 2: row-PAIR uint4 loads (lanes 0-31 even row, 32-63 odd row) + fp16
//          8-deep tree accumulate (v_pk_add_f16) flushed to fp32; cross-half
//          merge via shfl_xor(32). Buckets partitioned over the 4 waves.
// Phase 3: conv as G x emb with b128 LDS reads; emb staged in 2 chunks of 13
//          rows (stride 156, skew f(t)=t+4*(t>>4): 16B-aligned + bank-clean).
__global__ __launch_bounds__(256) void k_conv(
    const int* __restrict__ target, const float* __restrict__ emb,
    const __half* __restrict__ cwTh, const float* __restrict__ conv_b,
    float* __restrict__ c)
{
    __shared__ __align__(16) float Gs[VOCAB*256];   // 26,624B; reused as out-stage
    __shared__ __align__(16) float U[2080];         // 8,320B: sortedS ∪ emb chunk
    __shared__ int meta[3*VOCAB+2];                 // cnt / seg / cur
    __shared__ float cbS[NF];
    int* sortedS = (int*)U;
    int* cntS = meta;
    int* segS = meta + VOCAB;          // [VOCAB+1]
    int* curS = meta + 2*VOCAB + 1;
    int b = blockIdx.x, j = threadIdx.x;
    if (j < VOCAB) cntS[j] = 0;
    if (j < NF) cbS[j] = conv_b[j];
    __syncthreads();
    // ---- phase 1: counting sort ----
    int tloc[4];
    #pragma unroll
    for (int q=0; q<4; ++q) {
        int i = j + q*256;
        if (i < PLEN) {
            tloc[q] = target[b*PLEN+i];
            atomicAdd(&cntS[tloc[q]], 1);
        } else tloc[q] = -1;
    }
    __syncthreads();
    if (j == 0) {
        int run = 0;
        for (int v=0; v<VOCAB; ++v) { segS[v]=run; run += cntS[v]; }
        segS[VOCAB] = run;
    }
    __syncthreads();
    if (j < VOCAB) curS[j] = segS[j];
    __syncthreads();
    #pragma unroll
    for (int q=0; q<4; ++q) {
        int i = j + q*256;
        if (i < PLEN) {
            int pos = atomicAdd(&curS[tloc[q]], 1);
            sortedS[pos] = i;
        }
    }
    __syncthreads();
    // ---- phase 2: row-pair uint4 accumulate, buckets split over waves ----
    int w = j >> 6;
    int lane = j & 63;
    int half32 = lane >> 5;              // 0: even-index rows, 1: odd
    int c32 = lane & 31;                 // owns cols 8*c32..8*c32+7
    const uint4* cw4 = (const uint4*)cwTh;   // row = 32 uint4 (512B)
    __half2 hz = __float2half2_rn(0.f);
    for (int v=0; v<VOCAB; ++v) {
        int s = segS[v], e2 = segS[v+1];
        int wv = s / 250; if (wv > 3) wv = 3;
        if (wv != w) continue;
        float facc[8];
        #pragma unroll
        for (int q=0; q<8; ++q) facc[q] = 0.f;
        int p = s;
        for (; p+16 <= e2; p += 16) {    // 8 pairs; each lane sums 8 rows in fp16
            __half2 h0=hz, h1=hz, h2=hz, h3=hz;
            #pragma unroll
            for (int u=0; u<8; ++u) {
                int i0 = sortedS[p+2*u], i1 = sortedS[p+2*u+1];
                int row = half32 ? i1 : i0;
                uint4 q4 = cw4[row*32 + c32];
                const __half2* hh = (const __half2*)&q4;
                h0 = __hadd2(h0, hh[0]); h1 = __hadd2(h1, hh[1]);
                h2 = __hadd2(h2, hh[2]); h3 = __hadd2(h3, hh[3]);
            }
            float2 f0=__half22float2(h0), f1=__half22float2(h1),
                   f2=__half22float2(h2), f3=__half22float2(h3);
            facc[0]+=f0.x; facc[1]+=f0.y; facc[2]+=f1.x; facc[3]+=f1.y;
            facc[4]+=f2.x; facc[5]+=f2.y; facc[6]+=f3.x; facc[7]+=f3.y;
        }
        for (; p+2 <= e2; p += 2) {      // tail pairs in fp32
            int i0 = sortedS[p], i1 = sortedS[p+1];
            int row = half32 ? i1 : i0;
            uint4 q4 = cw4[row*32 + c32];
            const __half2* hh = (const __half2*)&q4;
            float2 f0=__half22float2(hh[0]), f1=__half22float2(hh[1]),
                   f2=__half22float2(hh[2]), f3=__half22float2(hh[3]);
            facc[0]+=f0.x; facc[1]+=f0.y; facc[2]+=f1.x; facc[3]+=f1.y;
            facc[4]+=f2.x; facc[5]+=f2.y; facc[6]+=f3.x; facc[7]+=f3.y;
        }
        if (p < e2 && half32 == 0) {     // leftover single row, lower half only
            uint4 q4 = cw4[sortedS[p]*32 + c32];
            const __half2* hh = (const __half2*)&q4;
            float2 f0=__half22float2(hh[0]), f1=__half22float2(hh[1]),
                   f2=__half22float2(hh[2]), f3=__half22float2(hh[3]);
            facc[0]+=f0.x; facc[1]+=f0.y; facc[2]+=f1.x; facc[3]+=f1.y;
            facc[4]+=f2.x; facc[5]+=f2.y; facc[6]+=f3.x; facc[7]+=f3.y;
        }
        #pragma unroll
        for (int q=0; q<8; ++q) facc[q] += __shfl_xor(facc[q], 32, 64);
        if (half32 == 0) {
            float4* gp = (float4*)(Gs + v*256 + c32*8);
            gp[0] = make_float4(facc[0], facc[1], facc[2], facc[3]);
            gp[1] = make_float4(facc[4], facc[5], facc[6], facc[7]);
        }
    }
    // ---- phase 3: conv, emb chunked through U ----
    int o = j >> 3, pg = j & 7;
    int t0 = pg*16;
    int tcnt = (t0+16 <= CLEN) ? 16 : (CLEN - t0);   // 16 or 9
    float out[16];
    #pragma unroll
    for (int q=0; q<16; ++q) out[q] = cbS[o];
    for (int ch=0; ch<2; ++ch) {
        __syncthreads();     // chunk 0: protect sortedS; chunk 1: protect prev emb
        for (int i=j; i<ECHUNK*EMBD; i+=256) {
            int v = i >> 7, tt = i & 127;
            U[v*EROW2 + tt + 4*(tt>>4)] = emb[(ch*ECHUNK + v)*EMBD + tt];
        }
        __syncthreads();
        for (int vv=0; vv<ECHUNK; ++vv) {
            const float4* gp = (const float4*)(Gs + (ch*ECHUNK+vv)*256 + o*8);
            float4 g0 = gp[0], g1 = gp[1];
            float g[8] = {g0.x,g0.y,g0.z,g0.w,g1.x,g1.y,g1.z,g1.w};
            const float* ev = &U[vv*EROW2 + 20*pg];
            float4 E0 = *(const float4*)(ev);
            float4 E1 = *(const float4*)(ev+4);
            float4 E2 = *(const float4*)(ev+8);
            float4 E3 = *(const float4*)(ev+12);
            float4 E4 = *(const float4*)(ev+20);
            float4 E5 = *(const float4*)(ev+24);
            float e[24] = {E0.x,E0.y,E0.z,E0.w, E1.x,E1.y,E1.z,E1.w,
                           E2.x,E2.y,E2.z,E2.w, E3.x,E3.y,E3.z,E3.w,
                           E4.x,E4.y,E4.z,E4.w, E5.x,E5.y,E5.z,E5.w};
            #pragma unroll
            for (int q=0; q<16; ++q) {
                float s = 0.f;
                #pragma unroll
                for (int k=0; k<KS; ++k) s += e[q+k]*g[k];
                out[q] += s;
            }
        }
    }
    __syncthreads();
    float* stage = Gs;
    for (int q=0; q<tcnt; ++q) stage[o*CLEN + t0 + q] = out[q];
    __syncthreads();
    for (int idx=j; idx<FCX; idx+=256)
        c[(long)b*FCX + idx] = stage[idx];
}

// xt: [1024 x 3872] @ [3872 x 128], grid (64 graph-tiles x 16 K-splits).
// NO atomics: each K-split stores partials to xtp[y][g][n] (plain float4),
// k_xt_red sums them. Staging is register-prefetched (load ch+1 during
// compute of ch) to hide L2 latency.
#define XT_GB  16
#define XT_NS  16
#define XT_KS  (FCX/XT_NS)   // 242
#define XT_BK  22
#define XT_NCH (XT_KS/XT_BK) // 11
__global__ __launch_bounds__(256) void k_xt(
    const float* __restrict__ c, const float* __restrict__ w,
    float* __restrict__ xtp)
{
    __shared__ float cS[XT_GB][XT_BK];    // 1.4 KB
    __shared__ float wS[XT_BK][128];      // 11.3 KB
    int b0 = blockIdx.x * XT_GB;
    int ks0 = blockIdx.y * XT_KS;
    int tid = threadIdx.x;
    int g2 = tid >> 5;          // graph pair 0..7 -> graphs 2g2, 2g2+1
    int co = tid & 31;          // cols co*4..co*4+3
    int cg0 = tid / XT_BK, ck0 = tid - cg0*XT_BK;          // cS slot 0
    int i1 = tid + 256;
    int cg1 = i1 / XT_BK, ck1 = i1 - cg1*XT_BK;            // cS slot 1 (tid<96)
    float wreg[11], creg0, creg1;
    // prologue: load chunk 0 into regs
    {
        int k0 = ks0;
        #pragma unroll
        for (int q=0; q<11; ++q) {
            int idx = tid + q*256;
            wreg[q] = w[(long)(k0 + (idx>>7))*OUTD + (idx & 127)];
        }
        creg0 = c[(long)(b0+cg0)*FCX + k0 + ck0];
        if (tid < 96) creg1 = c[(long)(b0+cg1)*FCX + k0 + ck1];
    }
    float acc[2][4];
    #pragma unroll
    for (int q=0; q<2; ++q)
      #pragma unroll
      for (int p=0; p<4; ++p) acc[q][p] = 0.f;
    for (int ch=0; ch<XT_NCH; ++ch) {
        // stage regs -> LDS
        #pragma unroll
        for (int q=0; q<11; ++q) {
            int idx = tid + q*256;
            wS[idx>>7][idx & 127] = wreg[q];
        }
        cS[cg0][ck0] = creg0;
        if (tid < 96) cS[cg1][ck1] = creg1;
        __syncthreads();
        // issue next chunk's loads (overlap with compute below)
        if (ch+1 < XT_NCH) {
            int k0 = ks0 + (ch+1)*XT_BK;
            #pragma unroll
            for (int q=0; q<11; ++q) {
                int idx = tid + q*256;
                wreg[q] = w[(long)(k0 + (idx>>7))*OUTD + (idx & 127)];
            }
            creg0 = c[(long)(b0+cg0)*FCX + k0 + ck0];
            if (tid < 96) creg1 = c[(long)(b0+cg1)*FCX + k0 + ck1];
        }
        #pragma unroll
        for (int k2=0; k2<XT_BK/2; ++k2) {
            float2 cv0 = *(const float2*)&cS[2*g2  ][2*k2];
            float2 cv1 = *(const float2*)&cS[2*g2+1][2*k2];
            float4 wv0 = *(const float4*)&wS[2*k2  ][co*4];
            float4 wv1 = *(const float4*)&wS[2*k2+1][co*4];
            acc[0][0]+=cv0.x*wv0.x; acc[0][1]+=cv0.x*wv0.y;
            acc[0][2]+=cv0.x*wv0.z; acc[0][3]+=cv0.x*wv0.w;
            acc[1][0]+=cv1.x*wv0.x; acc[1][1]+=cv1.x*wv0.y;
            acc[1][2]+=cv1.x*wv0.z; acc[1][3]+=cv1.x*wv0.w;
            acc[0][0]+=cv0.y*wv1.x; acc[0][1]+=cv0.y*wv1.y;
            acc[0][2]+=cv0.y*wv1.z; acc[0][3]+=cv0.y*wv1.w;
            acc[1][0]+=cv1.y*wv1.x; acc[1][1]+=cv1.y*wv1.y;
            acc[1][2]+=cv1.y*wv1.z; acc[1][3]+=cv1.y*wv1.w;
        }
        __syncthreads();
    }
    #pragma unroll
    for (int q=0; q<2; ++q) {
        int g = b0 + 2*g2 + q;
        float4* dst = (float4*)(xtp + ((long)blockIdx.y*NB + g)*128);
        dst[co] = make_float4(acc[q][0], acc[q][1], acc[q][2], acc[q][3]);
    }
}

// sum the 16 K-split partials + bias -> xc[:, 128:256)
__global__ __launch_bounds__(256) void k_xt_red(
    const float* __restrict__ xtp, const float* __restrict__ bias,
    float* __restrict__ xc)
{
    int p = blockIdx.x*256 + threadIdx.x;   // 32768 float4 slots
    int g = p >> 5, c4 = p & 31;
    const float4* src = (const float4*)xtp;
    float4 s = src[(long)g*32 + c4];
    #pragma unroll
    for (int y=1; y<XT_NS; ++y) {
        float4 v = src[((long)y*NB + g)*32 + c4];
        s.x += v.x; s.y += v.y; s.z += v.z; s.w += v.w;
    }
    float4 bv = ((const float4*)bias)[c4];
    s.x += bv.x; s.y += bv.y; s.z += bv.z; s.w += bv.w;
    ((float4*)(xc + g*256 + 128))[c4] = s;
}

// ---------------- joint head ----------------
// fc1/fc2: K-split partial-sum GEMMs (no atomics), mirrors the k_xt fix.
// Old form: 256 blocks (1/CU), each streaming the FULL 1 MB weight ->
// latency-bound at 67 us (VALUBusy 13%, occupancy 10%).

#define FC1_NS 4
#define FC1_KR 64    // 256/FC1_NS rows per split
__global__ __launch_bounds__(256) void k_fc1(
    const float* __restrict__ xc, const float* __restrict__ w,
    float* __restrict__ y1p)
{
    __shared__ float xS[4][FC1_KR];
    int b0 = blockIdx.x*4;
    int r0 = blockIdx.y*FC1_KR;
    int n = threadIdx.x;
    xS[n>>6][n&63] = xc[(b0 + (n>>6))*256 + r0 + (n&63)];
    __syncthreads();
    float acc[4][4];   // [graph][m]
    #pragma unroll
    for (int q=0;q<4;++q)
      #pragma unroll
      for (int m=0;m<4;++m) acc[q][m]=0.f;
    for (int r=0; r<FC1_KR; ++r) {
        float x0=xS[0][r], x1=xS[1][r], x2=xS[2][r], x3=xS[3][r];
        #pragma unroll
        for (int m=0; m<4; ++m) {
            float wv = w[(long)(r0+r)*1024 + m*256 + n];
            acc[0][m]+=x0*wv; acc[1][m]+=x1*wv;
            acc[2][m]+=x2*wv; acc[3][m]+=x3*wv;
        }
    }
    long base = ((long)blockIdx.y*NB + b0)*1024;
    #pragma unroll
    for (int q=0; q<4; ++q)
        #pragma unroll
        for (int m=0; m<4; ++m)
            y1p[base + (long)q*1024 + m*256 + n] = acc[q][m];
}

__global__ __launch_bounds__(256) void k_fc1_red(
    const float* __restrict__ y1p, const float* __restrict__ bias,
    float* __restrict__ y)
{
    int p = blockIdx.x*256 + threadIdx.x;   // 262144 float4 slots
    int g = p >> 8, c4 = p & 255;
    const float4* src = (const float4*)y1p;
    float4 s = src[(long)g*256 + c4];
    #pragma unroll
    for (int yq=1; yq<FC1_NS; ++yq) {
        float4 v = src[((long)yq*NB + g)*256 + c4];
        s.x+=v.x; s.y+=v.y; s.z+=v.z; s.w+=v.w;
    }
    float4 bv = ((const float4*)bias)[c4];
    s.x = fmaxf(s.x+bv.x, 0.f); s.y = fmaxf(s.y+bv.y, 0.f);
    s.z = fmaxf(s.z+bv.z, 0.f); s.w = fmaxf(s.w+bv.w, 0.f);
    ((float4*)y)[(long)g*256 + c4] = s;
}

#define FC2_NS 8
#define FC2_KR 128   // 1024/FC2_NS rows per split
__global__ __launch_bounds__(256) void k_fc2(
    const float* __restrict__ y, const float* __restrict__ w,
    float* __restrict__ y2p)
{
    __shared__ float xS[4][FC2_KR];
    int b0 = blockIdx.x*4;
    int r0 = blockIdx.y*FC2_KR;
    int n = threadIdx.x;
    {
        int e1 = n + 256;
        xS[n>>7][n&127]   = y[(b0 + (n>>7))*1024  + r0 + (n&127)];
        xS[e1>>7][e1&127] = y[(b0 + (e1>>7))*1024 + r0 + (e1&127)];
    }
    __syncthreads();
    float acc[4] = {0.f, 0.f, 0.f, 0.f};
    for (int r=0; r<FC2_KR; ++r) {
        float wv = w[(long)(r0+r)*256 + n];
        acc[0]+=xS[0][r]*wv; acc[1]+=xS[1][r]*wv;
        acc[2]+=xS[2][r]*wv; acc[3]+=xS[3][r]*wv;
    }
    long base = ((long)blockIdx.y*NB + b0)*256;
    #pragma unroll
    for (int q=0; q<4; ++q) y2p[base + q*256 + n] = acc[q];
}

__global__ __launch_bounds__(256) void k_fc2_red(
    const float* __restrict__ y2p, const float* __restrict__ bias,
    float* __restrict__ y2)
{
    int p = blockIdx.x*256 + threadIdx.x;   // 65536 float4 slots
    int g = p >> 6, c4 = p & 63;
    const float4* src = (const float4*)y2p;
    float4 s = src[(long)g*64 + c4];
    #pragma unroll
    for (int yq=1; yq<FC2_NS; ++yq) {
        float4 v = src[((long)yq*NB + g)*64 + c4];
        s.x+=v.x; s.y+=v.y; s.z+=v.z; s.w+=v.w;
    }
    float4 bv = ((const float4*)bias)[c4];
    s.x = fmaxf(s.x+bv.x, 0.f); s.y = fmaxf(s.y+bv.y, 0.f);
    s.z = fmaxf(s.z+bv.z, 0.f); s.w = fmaxf(s.w+bv.w, 0.f);
    ((float4*)y2)[(long)g*64 + c4] = s;
}

__global__ __launch_bounds__(256) void k_out(
    const float* __restrict__ y2, const float* __restrict__ w,
    const float* __restrict__ bias, float* __restrict__ out)
{
    int b = blockIdx.x, n = threadIdx.x;
    float v = y2[b*256 + n] * w[n];
    #pragma unroll
    for (int off=32; off; off>>=1) v += __shfl_down(v, off, 64);
    __shared__ float red[4];
    if ((n & 63) == 0) red[n >> 6] = v;
    __syncthreads();
    if (n == 0) out[b] = red[0]+red[1]+red[2]+red[3] + bias[0];
}

// ---------------- launch ----------------

extern "C" void kernel_launch(void* const* d_in, const int* in_sizes, int n_in,
                              void* d_out, int out_size, void* d_ws, size_t ws_size,
                              hipStream_t stream) {
    const float* x      = (const float*)d_in[0];
    const int*   ei     = (const int*)  d_in[1];
    const int*   batch  = (const int*)  d_in[2];
    const int*   target = (const int*)  d_in[3];
    const float* w1a    = (const float*)d_in[4];
    const float* b1a    = (const float*)d_in[5];
    const float* w1b    = (const float*)d_in[6];
    const float* b1b    = (const float*)d_in[7];
    const float* wa     = (const float*)d_in[8];
    const float* ba     = (const float*)d_in[9];
    const float* wb     = (const float*)d_in[10];
    const float* bb     = (const float*)d_in[11];
    const float* gamma  = (const float*)d_in[12];
    const float* beta   = (const float*)d_in[13];
    const float* w_fcxd = (const float*)d_in[14];
    const float* b_fcxd = (const float*)d_in[15];
    const float* emb    = (const float*)d_in[16];
    const float* conv_w = (const float*)d_in[17];
    const float* conv_b = (const float*)d_in[18];
    const float* w_fcxt = (const float*)d_in[19];
    const float* b_fcxt = (const float*)d_in[20];
    const float* w_fc1  = (const float*)d_in[21];
    const float* b_fc1  = (const float*)d_in[22];
    const float* w_fc2  = (const float*)d_in[23];
    const float* b_fc2  = (const float*)d_in[24];
    const float* w_out  = (const float*)d_in[25];
    const float* b_out  = (const float*)d_in[26];

    float* ws      = (float*)d_ws;
    __half* tH     = (__half*)ws;                          // N*32 halfs = 1,048,576 float-slots
    float* z       = ws + 1048576;                         // N*32 floats (= 8 MB)
    unsigned int* pairs = (unsigned int*)(z + (size_t)N_NODES*DIM);  // E uints
    int*   csr     = (int*)(pairs + N_EDGES);              // E ints
    int*   rowptr  = csr + N_EDGES;                        // N+1 (+pad)
    int*   bktCnt  = rowptr + (N_NODES + 8);               // 256
    int*   bktBase = bktCnt + 256;                         // 257 (+pad)
    int*   bktCur  = bktBase + 264;                        // 256
    float* ss      = (float*)(bktCur + 256);               // 64
    float* hg      = ss + 64;                              // 32768
    float* cwT     = hg + (size_t)NB*DIM;                  // 256000 float-slots (fp16 uses half)
    float* cbuf    = cwT + 256000;                         // 3964928
    float* xc      = cbuf + (size_t)NB*FCX;                // 262144
    float* y1      = xc + (size_t)NB*256;                  // 1048576
    float* y2      = y1 + (size_t)NB*1024;                 // 262144
    float* part    = y2 + (size_t)NB*256;                  // 256*64
    __half* cwTh   = (__half*)cwT;
    float* xtp     = z;   // xt partials [16][1024][128] = 2,097,152 floats:
                          // aliases z (first GIN write to z happens after xt_red)
    float* y1p     = ws;             // fc1 partials [4][1024][1024] = 4M floats
                                     // aliases tH+z (dead after GIN+pool)
    float* y2p     = ws + 4194304;   // fc2 partials [8][1024][256] = 2M floats
                                     // aliases pairs (dead after GIN loop)

    // ---- CSR build: bucket sort (coalesced) + fused rowptr/scatter ----
    hipMemsetAsync(bktCnt, 0, 256*sizeof(int), stream);
    k_bhist<<<N_EDGES/1024, 256, 0, stream>>>(ei, bktCnt);
    k_bscan<<<1, 256, 0, stream>>>(bktCnt, bktBase, bktCur);
    k_bucketA<<<NBKT, 256, 0, stream>>>(ei, bktCur, pairs);
    k_fillB<<<NBKT, 256, 0, stream>>>(bktBase, pairs, rowptr, csr);

    // ---- protein branch ----
    k_cw_transpose<<<1000, 256, 0, stream>>>(conv_w, cwTh);
    k_conv<<<NB, 256, 0, stream>>>(target, emb, cwTh, conv_b, cbuf);
    k_xt<<<dim3(NB/XT_GB, XT_NS), 256, 0, stream>>>(cbuf, w_fcxt, xtp);
    k_xt_red<<<(NB*DIM)/256, 256, 0, stream>>>(xtp, b_fcxt, xc);

    // ---- GIN layers ----
    hipMemsetAsync(part, 0, NSLICE*64*sizeof(float), stream);
    for (int l=0; l<5; ++l) {
        if (l == 0)
            k_l1_transform<<<N_NODES/256, 256, 0, stream>>>(x, w1a, tH);
        else
            k_transform<<<N_NODES/256, 256, 0, stream>>>(z, ss, wa + (size_t)(l-1)*DIM*DIM, tH);
        const float* bi = (l==0) ? b1a : ba + (size_t)(l-1)*DIM;
        const float* wo = (l==0) ? w1b : wb + (size_t)(l-1)*DIM*DIM;
        const float* bo = (l==0) ? b1b : bb + (size_t)(l-1)*DIM;
        k_gather_mlp<<<N_NODES/32, 256, 0, stream>>>(rowptr, csr, tH, bi, wo, bo, z, part);
        k_scaleshift<<<1, 256, 0, stream>>>(part, gamma, beta, l, ss);
    }

    // ---- pool + drug head ----
    hipMemsetAsync(hg, 0, (size_t)NB*DIM*sizeof(float), stream);
    k_pool<<<N_NODES/32, 256, 0, stream>>>(z, ss, batch, hg);
    k_xd<<<NB, 128, 0, stream>>>(hg, w_fcxd, b_fcxd, xc);

    // ---- joint head (K-split partials + reduce; tH/z/pairs/csr are dead) ----
    k_fc1<<<dim3(NB/4, FC1_NS), 256, 0, stream>>>(xc, w_fc1, y1p);
    k_fc1_red<<<1024, 256, 0, stream>>>(y1p, b_fc1, y1);
    k_fc2<<<dim3(NB/4, FC2_NS), 256, 0, stream>>>(y1, w_fc2, y2p);
    k_fc2_red<<<256, 256, 0, stream>>>(y2p, b_fc2, y2);
    k_out<<<NB, 256, 0, stream>>>(y2, w_out, b_out, (float*)d_out);
}

// Round 7
// 670.341 us; speedup vs baseline: 1.1861x; 1.0242x over previous
//
#include <hip/hip_runtime.h>
#include <hip/hip_fp16.h>

#define N_NODES 65536
#define N_EDGES 2097152
#define NB      1024
#define FXD     78
#define DIM     32
#define EMBD    128
#define OUTD    128
#define VOCAB   26
#define PLEN    1000
#define KS      8
#define CLEN    121      // EMBD-KS+1
#define NF      32
#define FCX     (NF*CLEN)  // 3872
#define NBKT    256
#define EPB     8192     // edges per bucketA block (N_EDGES/256)
#define NSLICE  256      // stats partial slices
#define EROW2   156      // emb row stride (floats): f(t)=t+4*(t>>4), f(127)=155
#define ECHUNK  13       // emb rows staged per chunk (2 chunks x 13 = 26)

// ---------------- bucket sort (dst>>8) ----------------

__global__ __launch_bounds__(256) void k_bhist(
    const int* __restrict__ ei, int* __restrict__ bktCnt)
{
    __shared__ int h[NBKT];
    int tid = threadIdx.x;
    h[tid] = 0;
    __syncthreads();
    int base = blockIdx.x*1024;
    #pragma unroll
    for (int q=0; q<4; ++q) {
        int d = ei[N_EDGES + base + q*256 + tid];
        atomicAdd(&h[d>>8], 1);
    }
    __syncthreads();
    atomicAdd(&bktCnt[tid], h[tid]);
}

__global__ __launch_bounds__(256) void k_bscan(
    const int* __restrict__ bktCnt, int* __restrict__ bktBase, int* __restrict__ bktCur)
{
    __shared__ int s[NBKT];
    int t = threadIdx.x;
    int v = bktCnt[t];
    s[t] = v;
    __syncthreads();
    for (int off=1; off<256; off<<=1) {
        int tv = (t >= off) ? s[t-off] : 0;
        __syncthreads();
        s[t] += tv;
        __syncthreads();
    }
    int ex = s[t] - v;
    bktBase[t] = ex;
    bktCur[t] = ex;
    if (t == 255) bktBase[256] = s[255];   // == N_EDGES
}

// LDS-sort 8192 edges by bucket, write packed (dst<<16|src) in coalesced runs
__global__ __launch_bounds__(256) void k_bucketA(
    const int* __restrict__ ei, int* __restrict__ bktCur, unsigned int* __restrict__ pairs)
{
    __shared__ unsigned int raw[EPB];       // 32 KB
    __shared__ unsigned int srt[EPB];       // 32 KB
    __shared__ unsigned char bOf[EPB];      // 8 KB
    __shared__ int hist[NBKT], sc[NBKT], lcur[NBKT], gbase[NBKT];
    int tid = threadIdx.x;
    hist[tid] = 0;
    __syncthreads();
    int eb = blockIdx.x * EPB;
    for (int i=tid; i<EPB; i+=256) {
        int s = ei[eb+i];
        int d = ei[N_EDGES+eb+i];
        raw[i] = ((unsigned int)d<<16) | (unsigned int)s;
        atomicAdd(&hist[d>>8], 1);
    }
    __syncthreads();
    int v = hist[tid];
    sc[tid] = v;
    __syncthreads();
    for (int off=1; off<256; off<<=1) {
        int tv = (tid >= off) ? sc[tid-off] : 0;
        __syncthreads();
        sc[tid] += tv;
        __syncthreads();
    }
    int ex = sc[tid] - v;
    sc[tid] = ex;            // exclusive local base
    lcur[tid] = ex;
    gbase[tid] = atomicAdd(&bktCur[tid], v);
    __syncthreads();
    for (int i=tid; i<EPB; i+=256) {
        unsigned int p = raw[i];
        int k = p >> 24;
        int pos = atomicAdd(&lcur[k], 1);
        srt[pos] = p;
        bOf[pos] = (unsigned char)k;
    }
    __syncthreads();
    for (int i=tid; i<EPB; i+=256) {
        int k = bOf[i];
        pairs[gbase[k] + (i - sc[k])] = srt[i];
    }
}

// per bucket: build rowptr (LDS histogram + scan) and scatter srcs into the
// bucket's contiguous CSR segment.
__global__ __launch_bounds__(256) void k_fillB(
    const int* __restrict__ bktBase, const unsigned int* __restrict__ pairs,
    int* __restrict__ rowptr, int* __restrict__ csr)
{
    __shared__ int hist[256], sc[256], cur[256];
    int b = blockIdx.x, tid = threadIdx.x;
    int node0 = b*256;
    hist[tid] = 0;
    __syncthreads();
    int s = bktBase[b], e = bktBase[b+1];
    for (int i = s + tid; i < e; i += 256)
        atomicAdd(&hist[(pairs[i] >> 16) & 255], 1);
    __syncthreads();
    int v = hist[tid];
    sc[tid] = v;
    __syncthreads();
    for (int off=1; off<256; off<<=1) {
        int tv = (tid >= off) ? sc[tid-off] : 0;
        __syncthreads();
        sc[tid] += tv;
        __syncthreads();
    }
    int base = s + sc[tid] - v;     // exclusive
    rowptr[node0 + tid] = base;
    cur[tid] = base;
    if (b == NBKT-1 && tid == 255) rowptr[N_NODES] = N_EDGES;
    __syncthreads();
    for (int i = s + tid; i < e; i += 256) {
        unsigned int p = pairs[i];
        int pos = atomicAdd(&cur[(p >> 16) & 255], 1);
        csr[pos] = (int)(p & 0xFFFFu);
    }
}

// ---------------- GIN layer kernels ----------------

// Layer-1 transform: t = x @ w1a  (fp16 out)
__global__ __launch_bounds__(256) void k_l1_transform(
    const float* __restrict__ x, const float* __restrict__ w,
    __half* __restrict__ t)
{
    __shared__ float wS[FXD*DIM];
    for (int i = threadIdx.x; i < FXD*DIM; i += 256) wS[i] = w[i];
    __syncthreads();
    int node = blockIdx.x*256 + threadIdx.x;
    float acc[DIM];
    #pragma unroll
    for (int d=0; d<DIM; ++d) acc[d] = 0.f;
    const float* xr = x + (long)node*FXD;
    for (int j=0; j<FXD; ++j) {
        float xv = xr[j];
        #pragma unroll
        for (int d=0; d<DIM; ++d) acc[d] += xv * wS[j*DIM+d];
    }
    union { __half2 h2[16]; uint4 u4[4]; } pk;
    #pragma unroll
    for (int q=0; q<16; ++q) pk.h2[q] = __floats2half2_rn(acc[2*q], acc[2*q+1]);
    uint4* dst4 = (uint4*)(t + (long)node*DIM);
    #pragma unroll
    for (int q=0; q<4; ++q) dst4[q] = pk.u4[q];
}

// Layers 2-5: computes BN scale/shift IN-BLOCK from the stats partials of
// the previous layer (replaces 4 one-block k_scaleshift serialization
// points), then t = BN(z) @ w  (fp16 out).
__global__ __launch_bounds__(256) void k_transform(
    const float* __restrict__ z, const float* __restrict__ part,
    const float* __restrict__ gamma, const float* __restrict__ beta, int layer,
    const float* __restrict__ w, __half* __restrict__ t)
{
    __shared__ float wS[DIM*DIM];
    __shared__ float red[4][64];
    __shared__ float sS[2*DIM];
    int tid = threadIdx.x;
    for (int i=tid; i<DIM*DIM; i+=256) wS[i] = w[i];
    {
        int ch = tid & 63, qq = tid >> 6;
        float s = 0.f;
        for (int i = qq*64; i < qq*64 + 64; ++i) s += part[(i<<6) + ch];
        red[qq][ch] = s;
    }
    __syncthreads();
    if (tid < DIM) {
        float tots = red[0][tid]+red[1][tid]+red[2][tid]+red[3][tid];
        float totq = red[0][DIM+tid]+red[1][DIM+tid]+red[2][DIM+tid]+red[3][DIM+tid];
        float mean = tots * (1.f/N_NODES);
        float var  = totq * (1.f/N_NODES) - mean*mean;
        float sc = gamma[layer*DIM+tid] * rsqrtf(var + 1e-5f);
        sS[tid] = sc;
        sS[DIM+tid] = beta[layer*DIM+tid] - mean*sc;
    }
    __syncthreads();
    int node = blockIdx.x*256 + tid;
    float h[DIM];
    const float4* z4 = (const float4*)(z + (long)node*DIM);
    #pragma unroll
    for (int q=0; q<DIM/4; ++q) {
        float4 v = z4[q];
        h[q*4+0]=v.x; h[q*4+1]=v.y; h[q*4+2]=v.z; h[q*4+3]=v.w;
    }
    #pragma unroll
    for (int d=0; d<DIM; ++d) h[d] = h[d]*sS[d] + sS[DIM+d];
    float acc[DIM];
    #pragma unroll
    for (int d=0; d<DIM; ++d) acc[d] = 0.f;
    #pragma unroll
    for (int j=0; j<DIM; ++j) {
        float hv = h[j];
        #pragma unroll
        for (int d=0; d<DIM; ++d) acc[d] += hv * wS[j*DIM+d];
    }
    union { __half2 h2[16]; uint4 u4[4]; } pk;
    #pragma unroll
    for (int q=0; q<16; ++q) pk.h2[q] = __floats2half2_rn(acc[2*q], acc[2*q+1]);
    uint4* dst4 = (uint4*)(t + (long)node*DIM);
    #pragma unroll
    for (int q=0; q<4; ++q) dst4[q] = pk.u4[q];
}

// Gather (CSR) + self + MLP + ReLU + BN-stats partials.
__global__ __launch_bounds__(256) void k_gather_mlp(
    const int* __restrict__ rowptr, const int* __restrict__ csr,
    const __half* __restrict__ t,
    const float* __restrict__ bi, const float* __restrict__ wo, const float* __restrict__ bo,
    float* __restrict__ z, float* __restrict__ part)
{
    __shared__ float wS[DIM*DIM];
    __shared__ float bS[2*DIM];
    __shared__ float stS[2*DIM];
    int tid = threadIdx.x;
    for (int i=tid; i<DIM*DIM; i+=256) wS[i]=wo[i];
    if (tid<DIM) bS[tid]=bi[tid];
    else if (tid<2*DIM) bS[tid]=bo[tid-DIM];
    if (tid<2*DIM) stS[tid]=0.f;
    __syncthreads();
    int g = tid >> 3;           // node 0..31 within block
    int l = tid & 7;            // lane in group; owns channels 4l..4l+3
    int node = blockIdx.x*32 + g;
    const uint2* t4 = (const uint2*)t;   // 8B = 4 halfs; 8 entries per row
    uint2 sv = t4[(long)node*8 + l];     // self term
    float2 p0 = __half22float2(*(const __half2*)&sv.x);
    float2 p1 = __half22float2(*(const __half2*)&sv.y);
    float a0=p0.x, a1=p0.y, a2=p1.x, a3=p1.y;
    float c0=0.f, c1=0.f, c2=0.f, c3=0.f;
    int s0 = rowptr[node], s1 = rowptr[node+1];
    int e = s0;
    for (; e+8 <= s1; e+=8) {
        int myIdx = csr[e + l];          // 8 consecutive, coalesced
        #pragma unroll
        for (int k=0; k<8; ++k) {
            int idx = __shfl(myIdx, k, 8);
            uint2 v = t4[(long)idx*8 + l];
            float2 q0 = __half22float2(*(const __half2*)&v.x);
            float2 q1 = __half22float2(*(const __half2*)&v.y);
            if (k & 1) { c0+=q0.x; c1+=q0.y; c2+=q1.x; c3+=q1.y; }
            else       { a0+=q0.x; a1+=q0.y; a2+=q1.x; a3+=q1.y; }
        }
    }
    if (e+4 <= s1) {
        int myIdx = csr[e + (l & 3)];
        #pragma unroll
        for (int k=0; k<4; ++k) {
            int idx = __shfl(myIdx, k, 8);
            uint2 v = t4[(long)idx*8 + l];
            float2 q0 = __half22float2(*(const __half2*)&v.x);
            float2 q1 = __half22float2(*(const __half2*)&v.y);
            if (k & 1) { c0+=q0.x; c1+=q0.y; c2+=q1.x; c3+=q1.y; }
            else       { a0+=q0.x; a1+=q0.y; a2+=q1.x; a3+=q1.y; }
        }
        e += 4;
    }
    for (; e<s1; ++e) {
        uint2 v = t4[(long)csr[e]*8 + l];
        float2 q0 = __half22float2(*(const __half2*)&v.x);
        float2 q1 = __half22float2(*(const __half2*)&v.y);
        a0+=q0.x; a1+=q0.y; a2+=q1.x; a3+=q1.y;
    }
    float ua[4];
    ua[0] = fmaxf(a0+c0 + bS[4*l+0], 0.f);
    ua[1] = fmaxf(a1+c1 + bS[4*l+1], 0.f);
    ua[2] = fmaxf(a2+c2 + bS[4*l+2], 0.f);
    ua[3] = fmaxf(a3+c3 + bS[4*l+3], 0.f);
    float zz[4];
    #pragma unroll
    for (int q=0; q<4; ++q) zz[q] = bS[DIM + 4*l + q];
    const float4* w4 = (const float4*)wS;
    #pragma unroll
    for (int j=0; j<DIM; ++j) {
        float uj = __shfl(ua[j & 3], j >> 2, 8);
        float4 wv = w4[j*8 + l];
        zz[0]+=uj*wv.x; zz[1]+=uj*wv.y; zz[2]+=uj*wv.z; zz[3]+=uj*wv.w;
    }
    #pragma unroll
    for (int q=0; q<4; ++q) zz[q] = fmaxf(zz[q], 0.f);
    ((float4*)z)[(long)node*8 + l] = make_float4(zz[0], zz[1], zz[2], zz[3]);
    // stats: reduce the 8 node-groups of each wave down to 8 lanes
    float sr[4], qr[4];
    #pragma unroll
    for (int q=0; q<4; ++q) { sr[q] = zz[q]; qr[q] = zz[q]*zz[q]; }
    #pragma unroll
    for (int q=0; q<4; ++q) {
        sr[q] += __shfl_down(sr[q], 32, 64); qr[q] += __shfl_down(qr[q], 32, 64);
        sr[q] += __shfl_down(sr[q], 16, 64); qr[q] += __shfl_down(qr[q], 16, 64);
        sr[q] += __shfl_down(sr[q],  8, 64); qr[q] += __shfl_down(qr[q],  8, 64);
    }
    if ((tid & 63) < 8) {
        #pragma unroll
        for (int q=0; q<4; ++q) {
            atomicAdd(&stS[4*l+q],       sr[q]);
            atomicAdd(&stS[DIM+4*l+q],   qr[q]);
        }
    }
    __syncthreads();
    if (tid < 2*DIM)
        atomicAdd(&part[((blockIdx.x & (NSLICE-1))<<6) + tid], stS[tid]);
}

// reduce partial stats -> scale/shift (still used for layer 4 -> k_pool)
__global__ __launch_bounds__(256) void k_scaleshift(
    const float* __restrict__ part,
    const float* __restrict__ gamma, const float* __restrict__ beta,
    int layer, float* __restrict__ ss)
{
    __shared__ float red[4][64];
    __shared__ float totS[64];
    int t = threadIdx.x;
    int ch = t & 63, q = t >> 6;
    float s = 0.f;
    for (int i = q*64; i < q*64 + 64; ++i) s += part[(i<<6) + ch];
    red[q][ch] = s;
    __syncthreads();
    if (t < 64) totS[t] = red[0][t]+red[1][t]+red[2][t]+red[3][t];
    __syncthreads();
    if (t < DIM) {
        float mean = totS[t] * (1.f/N_NODES);
        float var  = totS[DIM+t] * (1.f/N_NODES) - mean*mean;
        float sc = gamma[layer*DIM+t] * rsqrtf(var + 1e-5f);
        ss[t] = sc;
        ss[DIM+t] = beta[layer*DIM+t] - mean*sc;
    }
}

// Global add pool with BN applied: hg[batch[n]] += BN(z[n]).
__global__ __launch_bounds__(256) void k_pool(
    const float* __restrict__ z, const float* __restrict__ ss,
    const int* __restrict__ batch, float* __restrict__ hg)
{
    int tid = threadIdx.x;
    int node = blockIdx.x*32 + (tid>>3);
    int cq = tid & 7;                      // channels 4cq..4cq+3
    float4 v = ((const float4*)z)[(long)node*8 + cq];
    float4 sc = ((const float4*)ss)[cq];
    float4 sh = ((const float4*)ss)[8 + cq];
    v.x = v.x*sc.x + sh.x; v.y = v.y*sc.y + sh.y;
    v.z = v.z*sc.z + sh.z; v.w = v.w*sc.w + sh.w;
    int b = batch[node];
    int b0 = __shfl(b, 0, 64);
    int b7 = __shfl(b, 63, 64);
    if (b0 == b7) {
        #pragma unroll
        for (int off=8; off<64; off<<=1) {
            v.x += __shfl_xor(v.x, off, 64);
            v.y += __shfl_xor(v.y, off, 64);
            v.z += __shfl_xor(v.z, off, 64);
            v.w += __shfl_xor(v.w, off, 64);
        }
        if ((tid & 63) < 8) {
            float* dst = hg + (long)b0*DIM + cq*4;
            atomicAdd(dst+0, v.x); atomicAdd(dst+1, v.y);
            atomicAdd(dst+2, v.z); atomicAdd(dst+3, v.w);
        }
    } else {
        float* dst = hg + (long)b*DIM + cq*4;
        atomicAdd(dst+0, v.x); atomicAdd(dst+1, v.y);
        atomicAdd(dst+2, v.z); atomicAdd(dst+3, v.w);
    }
}

// xd = ReLU(hg @ w_fcxd + b) -> xc[:, 0:128]
__global__ __launch_bounds__(128) void k_xd(
    const float* __restrict__ hg, const float* __restrict__ w,
    const float* __restrict__ bias, float* __restrict__ xc)
{
    int b = blockIdx.x, n = threadIdx.x;
    __shared__ float hS[DIM];
    if (n < DIM) hS[n] = hg[b*DIM+n];
    __syncthreads();
    float acc = bias[n];
    #pragma unroll
    for (int r=0; r<DIM; ++r) acc += hS[r]*w[r*OUTD+n];
    xc[b*256 + n] = fmaxf(acc, 0.f);
}

// ---------------- protein branch ----------------

// conv_w (OIH fp32) -> cwT (fp16, layout [i][o*8+k], row = 256 halfs = 512B)
__global__ __launch_bounds__(256) void k_cw_transpose(
    const float* __restrict__ cw, __half* __restrict__ cwT)
{
    int g = blockIdx.x*256 + threadIdx.x;   // 256000 total
    int i = g >> 8;
    int j = g & 255;
    int o = j >> 3, k = j & 7;
    cwT[g] = __float2half(cw[o*(PLEN*KS) + i*KS + k]);
}

// convA: counting-sort + bucket-accumulate HALF the vocab (13 buckets) per
// block; G written fp16 to global. grid 2048 (2 blocks/graph), LDS 4.4 KB
// -> 8 blocks/CU, 32 waves/CU: hides phase-2's L2 latency (the old fused
// k_conv had grid 1024 = 4/CU with zero scheduling slack).
__global__ __launch_bounds__(256) void k_convA(
    const int* __restrict__ target, const __half* __restrict__ cwTh,
    __half* __restrict__ G)
{
    __shared__ int sortedS[PLEN];
    __shared__ int meta[3*VOCAB+2];
    int* cntS = meta;
    int* segS = meta + VOCAB;          // [VOCAB+1]
    int* curS = meta + 2*VOCAB + 1;
    int bb = blockIdx.x, j = threadIdx.x;
    int b = bb >> 1, sub = bb & 1;
    if (j < VOCAB) cntS[j] = 0;
    __syncthreads();
    // ---- phase 1: counting sort (full; both halves need positions) ----
    int tloc[4];
    #pragma unroll
    for (int q=0; q<4; ++q) {
        int i = j + q*256;
        if (i < PLEN) {
            tloc[q] = target[b*PLEN+i];
            atomicAdd(&cntS[tloc[q]], 1);
        } else tloc[q] = -1;
    }
    __syncthreads();
    if (j == 0) {
        int run = 0;
        for (int v=0; v<VOCAB; ++v) { segS[v]=run; run += cntS[v]; }
        segS[VOCAB] = run;
    }
    __syncthreads();
    if (j < VOCAB) curS[j] = segS[j];
    __syncthreads();
    #pragma unroll
    for (int q=0; q<4; ++q) {
        int i = j + q*256;
        if (i < PLEN) {
            int pos = atomicAdd(&curS[tloc[q]], 1);
            sortedS[pos] = i;
        }
    }
    __syncthreads();
    // ---- phase 2: row-pair uint4 accumulate over this block's 13 buckets ----
    int w = j >> 6;
    int lane = j & 63;
    int half32 = lane >> 5;              // 0: even-index rows, 1: odd
    int c32 = lane & 31;                 // owns cols 8*c32..8*c32+7
    const uint4* cw4 = (const uint4*)cwTh;   // row = 32 uint4 (512B)
    __half2 hz = __float2half2_rn(0.f);
    int v0 = 13*sub, v1 = v0 + 13;
    int segbase = segS[v0];
    int tot = segS[v1] - segbase;
    for (int v=v0; v<v1; ++v) {
        int s = segS[v], e2 = segS[v+1];
        int wv = (tot > 0) ? ((s - segbase)*4)/tot : 0;
        if (wv > 3) wv = 3;
        if (wv != w) continue;
        float facc[8];
        #pragma unroll
        for (int q=0; q<8; ++q) facc[q] = 0.f;
        int p = s;
        for (; p+16 <= e2; p += 16) {    // 8 pairs; lane sums 8 rows in fp16
            __half2 h0=hz, h1=hz, h2=hz, h3=hz;
            #pragma unroll
            for (int u=0; u<8; ++u) {
                int i0 = sortedS[p+2*u], i1 = sortedS[p+2*u+1];
                int row = half32 ? i1 : i0;
                uint4 q4 = cw4[row*32 + c32];
                const __half2* hh = (const __half2*)&q4;
                h0 = __hadd2(h0, hh[0]); h1 = __hadd2(h1, hh[1]);
                h2 = __hadd2(h2, hh[2]); h3 = __hadd2(h3, hh[3]);
            }
            float2 f0=__half22float2(h0), f1=__half22float2(h1),
                   f2=__half22float2(h2), f3=__half22float2(h3);
            facc[0]+=f0.x; facc[1]+=f0.y; facc[2]+=f1.x; facc[3]+=f1.y;
            facc[4]+=f2.x; facc[5]+=f2.y; facc[6]+=f3.x; facc[7]+=f3.y;
        }
        for (; p+2 <= e2; p += 2) {      // tail pairs in fp32
            int i0 = sortedS[p], i1 = sortedS[p+1];
            int row = half32 ? i1 : i0;
            uint4 q4 = cw4[row*32 + c32];
            const __half2* hh = (const __half2*)&q4;
            float2 f0=__half22float2(hh[0]), f1=__half22float2(hh[1]),
                   f2=__half22float2(hh[2]), f3=__half22float2(hh[3]);
            facc[0]+=f0.x; facc[1]+=f0.y; facc[2]+=f1.x; facc[3]+=f1.y;
            facc[4]+=f2.x; facc[5]+=f2.y; facc[6]+=f3.x; facc[7]+=f3.y;
        }
        if (p < e2 && half32 == 0) {     // leftover single row, lower half only
            uint4 q4 = cw4[sortedS[p]*32 + c32];
            const __half2* hh = (const __half2*)&q4;
            float2 f0=__half22float2(hh[0]), f1=__half22float2(hh[1]),
                   f2=__half22float2(hh[2]), f3=__half22float2(hh[3]);
            facc[0]+=f0.x; facc[1]+=f0.y; facc[2]+=f1.x; facc[3]+=f1.y;
            facc[4]+=f2.x; facc[5]+=f2.y; facc[6]+=f3.x; facc[7]+=f3.y;
        }
        #pragma unroll
        for (int q=0; q<8; ++q) facc[q] += __shfl_xor(facc[q], 32, 64);
        if (half32 == 0) {
            __half2 o0 = __floats2half2_rn(facc[0], facc[1]);
            __half2 o1 = __floats2half2_rn(facc[2], facc[3]);
            __half2 o2 = __floats2half2_rn(facc[4], facc[5]);
            __half2 o3 = __floats2half2_rn(facc[6], facc[7]);
            uint4 pk;
            pk.x = *(unsigned int*)&o0; pk.y = *(unsigned int*)&o1;
            pk.z = *(unsigned int*)&o2; pk.w = *(unsigned int*)&o3;
            ((uint4*)(G + ((long)b*VOCAB + v)*256))[c32] = pk;
        }
    }
}

// convB: load graph's fp16 G (13.3 KB) into LDS, conv against emb chunks,
// write c. LDS union: [GsH 13312B][U 8320B]; stage (15488B) overlays after.
__global__ __launch_bounds__(256) void k_convB(
    const float* __restrict__ emb, const __half* __restrict__ G,
    const float* __restrict__ conv_b, float* __restrict__ c)
{
    __shared__ __align__(16) char buf[21632];
    __shared__ float cbS[NF];
    __half* GsH = (__half*)buf;               // 13312 B
    float*  U   = (float*)(buf + 13312);      // 8320 B (2080 floats)
    float*  stage = (float*)buf;              // overlays after final sync
    int b = blockIdx.x, j = threadIdx.x;
    if (j < NF) cbS[j] = conv_b[j];
    {
        const uint4* gsrc = (const uint4*)(G + (long)b*VOCAB*256);
        uint4* gdst = (uint4*)GsH;
        for (int i=j; i<832; i+=256) gdst[i] = gsrc[i];   // 832*16B = 13312B
    }
    int o = j >> 3, pg = j & 7;
    int t0 = pg*16;
    int tcnt = (t0+16 <= CLEN) ? 16 : (CLEN - t0);   // 16 or 9
    float out[16];
    __syncthreads();   // GsH + cbS ready
    #pragma unroll
    for (int q=0; q<16; ++q) out[q] = cbS[o];
    for (int ch=0; ch<2; ++ch) {
        __syncthreads();     // protect previous chunk's U reads
        for (int i=j; i<ECHUNK*EMBD; i+=256) {
            int v = i >> 7, tt = i & 127;
            U[v*EROW2 + tt + 4*(tt>>4)] = emb[(ch*ECHUNK + v)*EMBD + tt];
        }
        __syncthreads();
        for (int vv=0; vv<ECHUNK; ++vv) {
            uint4 gv = *(const uint4*)(GsH + (ch*ECHUNK+vv)*256 + o*8);
            const __half2* gh = (const __half2*)&gv;
            float2 ga = __half22float2(gh[0]), gb = __half22float2(gh[1]);
            float2 gc = __half22float2(gh[2]), gd = __half22float2(gh[3]);
            float g[8] = {ga.x,ga.y,gb.x,gb.y,gc.x,gc.y,gd.x,gd.y};
            const float* ev = &U[vv*EROW2 + 20*pg];
            float4 E0 = *(const float4*)(ev);
            float4 E1 = *(const float4*)(ev+4);
            float4 E2 = *(const float4*)(ev+8);
            float4 E3 = *(const float4*)(ev+12);
            float4 E4 = *(const float4*)(ev+20);
            float4 E5 = *(const float4*)(ev+24);
            float e[24] = {E0.x,E0.y,E0.z,E0.w, E1.x,E1.y,E1.z,E1.w,
                           E2.x,E2.y,E2.z,E2.w, E3.x,E3.y,E3.z,E3.w,
                           E4.x,E4.y,E4.z,E4.w, E5.x,E5.y,E5.z,E5.w};
            #pragma unroll
            for (int q=0; q<16; ++q) {
                float s = 0.f;
                #pragma unroll
                for (int k=0; k<KS; ++k) s += e[q+k]*g[k];
                out[q] += s;
            }
        }
    }
    __syncthreads();
    for (int q=0; q<tcnt; ++q) stage[o*CLEN + t0 + q] = out[q];
    __syncthreads();
    for (int idx=j; idx<FCX; idx+=256)
        c[(long)b*FCX + idx] = stage[idx];
}

// xt: [1024 x 3872] @ [3872 x 128], grid (64 graph-tiles x 16 K-splits).
#define XT_GB  16
#define XT_NS  16
#define XT_KS  (FCX/XT_NS)   // 242
#define XT_BK  22
#define XT_NCH (XT_KS/XT_BK) // 11
__global__ __launch_bounds__(256) void k_xt(
    const float* __restrict__ c, const float* __restrict__ w,
    float* __restrict__ xtp)
{
    __shared__ float cS[XT_GB][XT_BK];    // 1.4 KB
    __shared__ float wS[XT_BK][128];      // 11.3 KB
    int b0 = blockIdx.x * XT_GB;
    int ks0 = blockIdx.y * XT_KS;
    int tid = threadIdx.x;
    int g2 = tid >> 5;          // graph pair 0..7 -> graphs 2g2, 2g2+1
    int co = tid & 31;          // cols co*4..co*4+3
    int cg0 = tid / XT_BK, ck0 = tid - cg0*XT_BK;          // cS slot 0
    int i1 = tid + 256;
    int cg1 = i1 / XT_BK, ck1 = i1 - cg1*XT_BK;            // cS slot 1 (tid<96)
    float wreg[11], creg0, creg1;
    {
        int k0 = ks0;
        #pragma unroll
        for (int q=0; q<11; ++q) {
            int idx = tid + q*256;
            wreg[q] = w[(long)(k0 + (idx>>7))*OUTD + (idx & 127)];
        }
        creg0 = c[(long)(b0+cg0)*FCX + k0 + ck0];
        if (tid < 96) creg1 = c[(long)(b0+cg1)*FCX + k0 + ck1];
    }
    float acc[2][4];
    #pragma unroll
    for (int q=0; q<2; ++q)
      #pragma unroll
      for (int p=0; p<4; ++p) acc[q][p] = 0.f;
    for (int ch=0; ch<XT_NCH; ++ch) {
        #pragma unroll
        for (int q=0; q<11; ++q) {
            int idx = tid + q*256;
            wS[idx>>7][idx & 127] = wreg[q];
        }
        cS[cg0][ck0] = creg0;
        if (tid < 96) cS[cg1][ck1] = creg1;
        __syncthreads();
        if (ch+1 < XT_NCH) {
            int k0 = ks0 + (ch+1)*XT_BK;
            #pragma unroll
            for (int q=0; q<11; ++q) {
                int idx = tid + q*256;
                wreg[q] = w[(long)(k0 + (idx>>7))*OUTD + (idx & 127)];
            }
            creg0 = c[(long)(b0+cg0)*FCX + k0 + ck0];
            if (tid < 96) creg1 = c[(long)(b0+cg1)*FCX + k0 + ck1];
        }
        #pragma unroll
        for (int k2=0; k2<XT_BK/2; ++k2) {
            float2 cv0 = *(const float2*)&cS[2*g2  ][2*k2];
            float2 cv1 = *(const float2*)&cS[2*g2+1][2*k2];
            float4 wv0 = *(const float4*)&wS[2*k2  ][co*4];
            float4 wv1 = *(const float4*)&wS[2*k2+1][co*4];
            acc[0][0]+=cv0.x*wv0.x; acc[0][1]+=cv0.x*wv0.y;
            acc[0][2]+=cv0.x*wv0.z; acc[0][3]+=cv0.x*wv0.w;
            acc[1][0]+=cv1.x*wv0.x; acc[1][1]+=cv1.x*wv0.y;
            acc[1][2]+=cv1.x*wv0.z; acc[1][3]+=cv1.x*wv0.w;
            acc[0][0]+=cv0.y*wv1.x; acc[0][1]+=cv0.y*wv1.y;
            acc[0][2]+=cv0.y*wv1.z; acc[0][3]+=cv0.y*wv1.w;
            acc[1][0]+=cv1.y*wv1.x; acc[1][1]+=cv1.y*wv1.y;
            acc[1][2]+=cv1.y*wv1.z; acc[1][3]+=cv1.y*wv1.w;
        }
        __syncthreads();
    }
    #pragma unroll
    for (int q=0; q<2; ++q) {
        int g = b0 + 2*g2 + q;
        float4* dst = (float4*)(xtp + ((long)blockIdx.y*NB + g)*128);
        dst[co] = make_float4(acc[q][0], acc[q][1], acc[q][2], acc[q][3]);
    }
}

// sum the 16 K-split partials + bias -> xc[:, 128:256)
__global__ __launch_bounds__(256) void k_xt_red(
    const float* __restrict__ xtp, const float* __restrict__ bias,
    float* __restrict__ xc)
{
    int p = blockIdx.x*256 + threadIdx.x;   // 32768 float4 slots
    int g = p >> 5, c4 = p & 31;
    const float4* src = (const float4*)xtp;
    float4 s = src[(long)g*32 + c4];
    #pragma unroll
    for (int y=1; y<XT_NS; ++y) {
        float4 v = src[((long)y*NB + g)*32 + c4];
        s.x += v.x; s.y += v.y; s.z += v.z; s.w += v.w;
    }
    float4 bv = ((const float4*)bias)[c4];
    s.x += bv.x; s.y += bv.y; s.z += bv.z; s.w += bv.w;
    ((float4*)(xc + g*256 + 128))[c4] = s;
}

// ---------------- joint head ----------------
// fc1/fc2: K-split partial-sum GEMMs (no atomics), same recipe as k_xt.

#define FC1_NS 4
#define FC1_KR 64    // 256/FC1_NS rows per split
__global__ __launch_bounds__(256) void k_fc1(
    const float* __restrict__ xc, const float* __restrict__ w,
    float* __restrict__ y1p)
{
    __shared__ float xS[4][FC1_KR];
    int b0 = blockIdx.x*4;
    int r0 = blockIdx.y*FC1_KR;
    int n = threadIdx.x;
    xS[n>>6][n&63] = xc[(b0 + (n>>6))*256 + r0 + (n&63)];
    __syncthreads();
    float acc[4][4];   // [graph][m]
    #pragma unroll
    for (int q=0;q<4;++q)
      #pragma unroll
      for (int m=0;m<4;++m) acc[q][m]=0.f;
    for (int r=0; r<FC1_KR; ++r) {
        float x0=xS[0][r], x1=xS[1][r], x2=xS[2][r], x3=xS[3][r];
        #pragma unroll
        for (int m=0; m<4; ++m) {
            float wv = w[(long)(r0+r)*1024 + m*256 + n];
            acc[0][m]+=x0*wv; acc[1][m]+=x1*wv;
            acc[2][m]+=x2*wv; acc[3][m]+=x3*wv;
        }
    }
    long base = ((long)blockIdx.y*NB + b0)*1024;
    #pragma unroll
    for (int q=0; q<4; ++q)
        #pragma unroll
        for (int m=0; m<4; ++m)
            y1p[base + (long)q*1024 + m*256 + n] = acc[q][m];
}

__global__ __launch_bounds__(256) void k_fc1_red(
    const float* __restrict__ y1p, const float* __restrict__ bias,
    float* __restrict__ y)
{
    int p = blockIdx.x*256 + threadIdx.x;   // 262144 float4 slots
    int g = p >> 8, c4 = p & 255;
    const float4* src = (const float4*)y1p;
    float4 s = src[(long)g*256 + c4];
    #pragma unroll
    for (int yq=1; yq<FC1_NS; ++yq) {
        float4 v = src[((long)yq*NB + g)*256 + c4];
        s.x+=v.x; s.y+=v.y; s.z+=v.z; s.w+=v.w;
    }
    float4 bv = ((const float4*)bias)[c4];
    s.x = fmaxf(s.x+bv.x, 0.f); s.y = fmaxf(s.y+bv.y, 0.f);
    s.z = fmaxf(s.z+bv.z, 0.f); s.w = fmaxf(s.w+bv.w, 0.f);
    ((float4*)y)[(long)g*256 + c4] = s;
}

#define FC2_NS 8
#define FC2_KR 128   // 1024/FC2_NS rows per split
__global__ __launch_bounds__(256) void k_fc2(
    const float* __restrict__ y, const float* __restrict__ w,
    float* __restrict__ y2p)
{
    __shared__ float xS[4][FC2_KR];
    int b0 = blockIdx.x*4;
    int r0 = blockIdx.y*FC2_KR;
    int n = threadIdx.x;
    {
        int e1 = n + 256;
        xS[n>>7][n&127]   = y[(b0 + (n>>7))*1024  + r0 + (n&127)];
        xS[e1>>7][e1&127] = y[(b0 + (e1>>7))*1024 + r0 + (e1&127)];
    }
    __syncthreads();
    float acc[4] = {0.f, 0.f, 0.f, 0.f};
    for (int r=0; r<FC2_KR; ++r) {
        float wv = w[(long)(r0+r)*256 + n];
        acc[0]+=xS[0][r]*wv; acc[1]+=xS[1][r]*wv;
        acc[2]+=xS[2][r]*wv; acc[3]+=xS[3][r]*wv;
    }
    long base = ((long)blockIdx.y*NB + b0)*256;
    #pragma unroll
    for (int q=0; q<4; ++q) y2p[base + q*256 + n] = acc[q];
}

__global__ __launch_bounds__(256) void k_fc2_red(
    const float* __restrict__ y2p, const float* __restrict__ bias,
    float* __restrict__ y2)
{
    int p = blockIdx.x*256 + threadIdx.x;   // 65536 float4 slots
    int g = p >> 6, c4 = p & 63;
    const float4* src = (const float4*)y2p;
    float4 s = src[(long)g*64 + c4];
    #pragma unroll
    for (int yq=1; yq<FC2_NS; ++yq) {
        float4 v = src[((long)yq*NB + g)*64 + c4];
        s.x+=v.x; s.y+=v.y; s.z+=v.z; s.w+=v.w;
    }
    float4 bv = ((const float4*)bias)[c4];
    s.x = fmaxf(s.x+bv.x, 0.f); s.y = fmaxf(s.y+bv.y, 0.f);
    s.z = fmaxf(s.z+bv.z, 0.f); s.w = fmaxf(s.w+bv.w, 0.f);
    ((float4*)y2)[(long)g*64 + c4] = s;
}

__global__ __launch_bounds__(256) void k_out(
    const float* __restrict__ y2, const float* __restrict__ w,
    const float* __restrict__ bias, float* __restrict__ out)
{
    int b = blockIdx.x, n = threadIdx.x;
    float v = y2[b*256 + n] * w[n];
    #pragma unroll
    for (int off=32; off; off>>=1) v += __shfl_down(v, off, 64);
    __shared__ float red[4];
    if ((n & 63) == 0) red[n >> 6] = v;
    __syncthreads();
    if (n == 0) out[b] = red[0]+red[1]+red[2]+red[3] + bias[0];
}

// ---------------- launch ----------------

extern "C" void kernel_launch(void* const* d_in, const int* in_sizes, int n_in,
                              void* d_out, int out_size, void* d_ws, size_t ws_size,
                              hipStream_t stream) {
    const float* x      = (const float*)d_in[0];
    const int*   ei     = (const int*)  d_in[1];
    const int*   batch  = (const int*)  d_in[2];
    const int*   target = (const int*)  d_in[3];
    const float* w1a    = (const float*)d_in[4];
    const float* b1a    = (const float*)d_in[5];
    const float* w1b    = (const float*)d_in[6];
    const float* b1b    = (const float*)d_in[7];
    const float* wa     = (const float*)d_in[8];
    const float* ba     = (const float*)d_in[9];
    const float* wb     = (const float*)d_in[10];
    const float* bb     = (const float*)d_in[11];
    const float* gamma  = (const float*)d_in[12];
    const float* beta   = (const float*)d_in[13];
    const float* w_fcxd = (const float*)d_in[14];
    const float* b_fcxd = (const float*)d_in[15];
    const float* emb    = (const float*)d_in[16];
    const float* conv_w = (const float*)d_in[17];
    const float* conv_b = (const float*)d_in[18];
    const float* w_fcxt = (const float*)d_in[19];
    const float* b_fcxt = (const float*)d_in[20];
    const float* w_fc1  = (const float*)d_in[21];
    const float* b_fc1  = (const float*)d_in[22];
    const float* w_fc2  = (const float*)d_in[23];
    const float* b_fc2  = (const float*)d_in[24];
    const float* w_out  = (const float*)d_in[25];
    const float* b_out  = (const float*)d_in[26];

    float* ws      = (float*)d_ws;
    __half* tH     = (__half*)ws;                          // N*32 halfs = 1,048,576 float-slots
    float* z       = ws + 1048576;                         // N*32 floats (= 8 MB)
    unsigned int* pairs = (unsigned int*)(z + (size_t)N_NODES*DIM);  // E uints
    int*   csr     = (int*)(pairs + N_EDGES);              // E ints
    int*   rowptr  = csr + N_EDGES;                        // N+1 (+pad)
    int*   bktCnt  = rowptr + (N_NODES + 8);               // 256
    int*   bktBase = bktCnt + 256;                         // 257 (+pad)
    int*   bktCur  = bktBase + 264;                        // 256
    float* ss      = (float*)(bktCur + 256);               // 64
    float* hg      = ss + 64;                              // 32768
    float* cwT     = hg + (size_t)NB*DIM;                  // 256000 float-slots (fp16 uses half)
    float* cbuf    = cwT + 256000;                         // 3964928
    float* xc      = cbuf + (size_t)NB*FCX;                // 262144
    float* y1      = xc + (size_t)NB*256;                  // 1048576
    float* y2      = y1 + (size_t)NB*1024;                 // 262144
    float* part    = y2 + (size_t)NB*256;                  // 5 * 16384 floats
    __half* cwTh   = (__half*)cwT;
    float* xtp     = z;   // xt partials [16][1024][128]: aliases z (dead then)
    __half* Gbuf   = (__half*)z;   // fp16 G [1024][26][256] = 3.4M float-slots:
                                   // aliases z+pairs-head (pairs dead post-fillB;
                                   // ends before csr; k_xt's xtp write comes after convB)
    float* y1p     = ws;             // fc1 partials [4][1024][1024] (dead tH/z region)
    float* y2p     = ws + 4194304;   // fc2 partials [8][1024][256] (dead pairs/csr-head)

    // ---- CSR build: bucket sort (coalesced) + fused rowptr/scatter ----
    hipMemsetAsync(bktCnt, 0, 256*sizeof(int), stream);
    k_bhist<<<N_EDGES/1024, 256, 0, stream>>>(ei, bktCnt);
    k_bscan<<<1, 256, 0, stream>>>(bktCnt, bktBase, bktCur);
    k_bucketA<<<NBKT, 256, 0, stream>>>(ei, bktCur, pairs);
    k_fillB<<<NBKT, 256, 0, stream>>>(bktBase, pairs, rowptr, csr);

    // ---- protein branch ----
    k_cw_transpose<<<1000, 256, 0, stream>>>(conv_w, cwTh);
    k_convA<<<2*NB, 256, 0, stream>>>(target, cwTh, Gbuf);
    k_convB<<<NB, 256, 0, stream>>>(emb, Gbuf, conv_b, cbuf);
    k_xt<<<dim3(NB/XT_GB, XT_NS), 256, 0, stream>>>(cbuf, w_fcxt, xtp);
    k_xt_red<<<(NB*DIM)/256, 256, 0, stream>>>(xtp, b_fcxt, xc);

    // ---- GIN layers (per-layer part buffers; BN fused into transform) ----
    hipMemsetAsync(part, 0, 5*NSLICE*64*sizeof(float), stream);
    for (int l=0; l<5; ++l) {
        if (l == 0)
            k_l1_transform<<<N_NODES/256, 256, 0, stream>>>(x, w1a, tH);
        else
            k_transform<<<N_NODES/256, 256, 0, stream>>>(
                z, part + (size_t)(l-1)*NSLICE*64, gamma, beta, l-1,
                wa + (size_t)(l-1)*DIM*DIM, tH);
        const float* bi = (l==0) ? b1a : ba + (size_t)(l-1)*DIM;
        const float* wo = (l==0) ? w1b : wb + (size_t)(l-1)*DIM*DIM;
        const float* bo = (l==0) ? b1b : bb + (size_t)(l-1)*DIM;
        k_gather_mlp<<<N_NODES/32, 256, 0, stream>>>(
            rowptr, csr, tH, bi, wo, bo, z, part + (size_t)l*NSLICE*64);
    }
    k_scaleshift<<<1, 256, 0, stream>>>(part + (size_t)4*NSLICE*64, gamma, beta, 4, ss);

    // ---- pool + drug head ----
    hipMemsetAsync(hg, 0, (size_t)NB*DIM*sizeof(float), stream);
    k_pool<<<N_NODES/32, 256, 0, stream>>>(z, ss, batch, hg);
    k_xd<<<NB, 128, 0, stream>>>(hg, w_fcxd, b_fcxd, xc);

    // ---- joint head (K-split partials + reduce) ----
    k_fc1<<<dim3(NB/4, FC1_NS), 256, 0, stream>>>(xc, w_fc1, y1p);
    k_fc1_red<<<1024, 256, 0, stream>>>(y1p, b_fc1, y1);
    k_fc2<<<dim3(NB/4, FC2_NS), 256, 0, stream>>>(y1, w_fc2, y2p);
    k_fc2_red<<<256, 256, 0, stream>>>(y2p, b_fc2, y2);
    k_out<<<NB, 256, 0, stream>>>(y2, w_out, b_out, (float*)d_out);
}

// Round 8
// 634.120 us; speedup vs baseline: 1.2538x; 1.0571x over previous
//
#include <hip/hip_runtime.h>
#include <hip/hip_fp16.h>

#define N_NODES 65536
#define N_EDGES 2097152
#define NB      1024
#define FXD     78
#define DIM     32
#define EMBD    128
#define OUTD    128
#define VOCAB   26
#define PLEN    1000
#define KS      8
#define CLEN    121      // EMBD-KS+1
#define NF      32
#define FCX     (NF*CLEN)  // 3872
#define NBKT    256
#define EPB     8192     // edges per bucketA block (N_EDGES/256)
#define NSLICE  256      // stats partial slices
#define EROW2   156      // emb row stride (floats): f(t)=t+4*(t>>4), f(127)=155
#define ECHUNK  13       // emb rows staged per chunk (2 chunks x 13 = 26)

// ---------------- bucket sort (dst>>8) ----------------

// 256 blocks x 8192 edges (was 2048 x 1024): 8x fewer global atomics into
// the 1KB bktCnt region. The old 524K device-scope atomics to 16 cache
// lines serialized at L2 -> 57 us with VALUBusy 0.3%.
__global__ __launch_bounds__(256) void k_bhist(
    const int* __restrict__ ei, int* __restrict__ bktCnt)
{
    __shared__ int h[NBKT];
    int tid = threadIdx.x;
    h[tid] = 0;
    __syncthreads();
    long base = (long)blockIdx.x * EPB;
    #pragma unroll 4
    for (int q=0; q<EPB/256; ++q) {
        int d = ei[N_EDGES + base + q*256 + tid];
        atomicAdd(&h[d>>8], 1);
    }
    __syncthreads();
    atomicAdd(&bktCnt[tid], h[tid]);
}

__global__ __launch_bounds__(256) void k_bscan(
    const int* __restrict__ bktCnt, int* __restrict__ bktBase, int* __restrict__ bktCur)
{
    __shared__ int s[NBKT];
    int t = threadIdx.x;
    int v = bktCnt[t];
    s[t] = v;
    __syncthreads();
    for (int off=1; off<256; off<<=1) {
        int tv = (t >= off) ? s[t-off] : 0;
        __syncthreads();
        s[t] += tv;
        __syncthreads();
    }
    int ex = s[t] - v;
    bktBase[t] = ex;
    bktCur[t] = ex;
    if (t == 255) bktBase[256] = s[255];   // == N_EDGES
}

// LDS-sort 8192 edges by bucket, write packed (dst<<16|src) in coalesced runs
__global__ __launch_bounds__(256) void k_bucketA(
    const int* __restrict__ ei, int* __restrict__ bktCur, unsigned int* __restrict__ pairs)
{
    __shared__ unsigned int raw[EPB];       // 32 KB
    __shared__ unsigned int srt[EPB];       // 32 KB
    __shared__ unsigned char bOf[EPB];      // 8 KB
    __shared__ int hist[NBKT], sc[NBKT], lcur[NBKT], gbase[NBKT];
    int tid = threadIdx.x;
    hist[tid] = 0;
    __syncthreads();
    int eb = blockIdx.x * EPB;
    for (int i=tid; i<EPB; i+=256) {
        int s = ei[eb+i];
        int d = ei[N_EDGES+eb+i];
        raw[i] = ((unsigned int)d<<16) | (unsigned int)s;
        atomicAdd(&hist[d>>8], 1);
    }
    __syncthreads();
    int v = hist[tid];
    sc[tid] = v;
    __syncthreads();
    for (int off=1; off<256; off<<=1) {
        int tv = (tid >= off) ? sc[tid-off] : 0;
        __syncthreads();
        sc[tid] += tv;
        __syncthreads();
    }
    int ex = sc[tid] - v;
    sc[tid] = ex;            // exclusive local base
    lcur[tid] = ex;
    gbase[tid] = atomicAdd(&bktCur[tid], v);
    __syncthreads();
    for (int i=tid; i<EPB; i+=256) {
        unsigned int p = raw[i];
        int k = p >> 24;
        int pos = atomicAdd(&lcur[k], 1);
        srt[pos] = p;
        bOf[pos] = (unsigned char)k;
    }
    __syncthreads();
    for (int i=tid; i<EPB; i+=256) {
        int k = bOf[i];
        pairs[gbase[k] + (i - sc[k])] = srt[i];
    }
}

// per bucket: build rowptr (LDS histogram + scan) and scatter srcs into the
// bucket's contiguous CSR segment.
__global__ __launch_bounds__(256) void k_fillB(
    const int* __restrict__ bktBase, const unsigned int* __restrict__ pairs,
    int* __restrict__ rowptr, int* __restrict__ csr)
{
    __shared__ int hist[256], sc[256], cur[256];
    int b = blockIdx.x, tid = threadIdx.x;
    int node0 = b*256;
    hist[tid] = 0;
    __syncthreads();
    int s = bktBase[b], e = bktBase[b+1];
    for (int i = s + tid; i < e; i += 256)
        atomicAdd(&hist[(pairs[i] >> 16) & 255], 1);
    __syncthreads();
    int v = hist[tid];
    sc[tid] = v;
    __syncthreads();
    for (int off=1; off<256; off<<=1) {
        int tv = (tid >= off) ? sc[tid-off] : 0;
        __syncthreads();
        sc[tid] += tv;
        __syncthreads();
    }
    int base = s + sc[tid] - v;     // exclusive
    rowptr[node0 + tid] = base;
    cur[tid] = base;
    if (b == NBKT-1 && tid == 255) rowptr[N_NODES] = N_EDGES;
    __syncthreads();
    for (int i = s + tid; i < e; i += 256) {
        unsigned int p = pairs[i];
        int pos = atomicAdd(&cur[(p >> 16) & 255], 1);
        csr[pos] = (int)(p & 0xFFFFu);
    }
}

// ---------------- GIN layer kernels ----------------

// Layer-1 transform: t = x @ w1a  (fp16 out)
__global__ __launch_bounds__(256) void k_l1_transform(
    const float* __restrict__ x, const float* __restrict__ w,
    __half* __restrict__ t)
{
    __shared__ float wS[FXD*DIM];
    for (int i = threadIdx.x; i < FXD*DIM; i += 256) wS[i] = w[i];
    __syncthreads();
    int node = blockIdx.x*256 + threadIdx.x;
    float acc[DIM];
    #pragma unroll
    for (int d=0; d<DIM; ++d) acc[d] = 0.f;
    const float* xr = x + (long)node*FXD;
    for (int j=0; j<FXD; ++j) {
        float xv = xr[j];
        #pragma unroll
        for (int d=0; d<DIM; ++d) acc[d] += xv * wS[j*DIM+d];
    }
    union { __half2 h2[16]; uint4 u4[4]; } pk;
    #pragma unroll
    for (int q=0; q<16; ++q) pk.h2[q] = __floats2half2_rn(acc[2*q], acc[2*q+1]);
    uint4* dst4 = (uint4*)(t + (long)node*DIM);
    #pragma unroll
    for (int q=0; q<4; ++q) dst4[q] = pk.u4[q];
}

// Layers 2-5: computes BN scale/shift IN-BLOCK from the stats partials of
// the previous layer, then t = BN(z) @ w  (fp16 out).
__global__ __launch_bounds__(256) void k_transform(
    const float* __restrict__ z, const float* __restrict__ part,
    const float* __restrict__ gamma, const float* __restrict__ beta, int layer,
    const float* __restrict__ w, __half* __restrict__ t)
{
    __shared__ float wS[DIM*DIM];
    __shared__ float red[4][64];
    __shared__ float sS[2*DIM];
    int tid = threadIdx.x;
    for (int i=tid; i<DIM*DIM; i+=256) wS[i] = w[i];
    {
        int ch = tid & 63, qq = tid >> 6;
        float s = 0.f;
        for (int i = qq*64; i < qq*64 + 64; ++i) s += part[(i<<6) + ch];
        red[qq][ch] = s;
    }
    __syncthreads();
    if (tid < DIM) {
        float tots = red[0][tid]+red[1][tid]+red[2][tid]+red[3][tid];
        float totq = red[0][DIM+tid]+red[1][DIM+tid]+red[2][DIM+tid]+red[3][DIM+tid];
        float mean = tots * (1.f/N_NODES);
        float var  = totq * (1.f/N_NODES) - mean*mean;
        float sc = gamma[layer*DIM+tid] * rsqrtf(var + 1e-5f);
        sS[tid] = sc;
        sS[DIM+tid] = beta[layer*DIM+tid] - mean*sc;
    }
    __syncthreads();
    int node = blockIdx.x*256 + tid;
    float h[DIM];
    const float4* z4 = (const float4*)(z + (long)node*DIM);
    #pragma unroll
    for (int q=0; q<DIM/4; ++q) {
        float4 v = z4[q];
        h[q*4+0]=v.x; h[q*4+1]=v.y; h[q*4+2]=v.z; h[q*4+3]=v.w;
    }
    #pragma unroll
    for (int d=0; d<DIM; ++d) h[d] = h[d]*sS[d] + sS[DIM+d];
    float acc[DIM];
    #pragma unroll
    for (int d=0; d<DIM; ++d) acc[d] = 0.f;
    #pragma unroll
    for (int j=0; j<DIM; ++j) {
        float hv = h[j];
        #pragma unroll
        for (int d=0; d<DIM; ++d) acc[d] += hv * wS[j*DIM+d];
    }
    union { __half2 h2[16]; uint4 u4[4]; } pk;
    #pragma unroll
    for (int q=0; q<16; ++q) pk.h2[q] = __floats2half2_rn(acc[2*q], acc[2*q+1]);
    uint4* dst4 = (uint4*)(t + (long)node*DIM);
    #pragma unroll
    for (int q=0; q<4; ++q) dst4[q] = pk.u4[q];
}

// Gather (CSR) + self + MLP + ReLU + BN-stats partials.
__global__ __launch_bounds__(256) void k_gather_mlp(
    const int* __restrict__ rowptr, const int* __restrict__ csr,
    const __half* __restrict__ t,
    const float* __restrict__ bi, const float* __restrict__ wo, const float* __restrict__ bo,
    float* __restrict__ z, float* __restrict__ part)
{
    __shared__ float wS[DIM*DIM];
    __shared__ float bS[2*DIM];
    __shared__ float stS[2*DIM];
    int tid = threadIdx.x;
    for (int i=tid; i<DIM*DIM; i+=256) wS[i]=wo[i];
    if (tid<DIM) bS[tid]=bi[tid];
    else if (tid<2*DIM) bS[tid]=bo[tid-DIM];
    if (tid<2*DIM) stS[tid]=0.f;
    __syncthreads();
    int g = tid >> 3;           // node 0..31 within block
    int l = tid & 7;            // lane in group; owns channels 4l..4l+3
    int node = blockIdx.x*32 + g;
    const uint2* t4 = (const uint2*)t;   // 8B = 4 halfs; 8 entries per row
    uint2 sv = t4[(long)node*8 + l];     // self term
    float2 p0 = __half22float2(*(const __half2*)&sv.x);
    float2 p1 = __half22float2(*(const __half2*)&sv.y);
    float a0=p0.x, a1=p0.y, a2=p1.x, a3=p1.y;
    float c0=0.f, c1=0.f, c2=0.f, c3=0.f;
    int s0 = rowptr[node], s1 = rowptr[node+1];
    int e = s0;
    for (; e+8 <= s1; e+=8) {
        int myIdx = csr[e + l];          // 8 consecutive, coalesced
        #pragma unroll
        for (int k=0; k<8; ++k) {
            int idx = __shfl(myIdx, k, 8);
            uint2 v = t4[(long)idx*8 + l];
            float2 q0 = __half22float2(*(const __half2*)&v.x);
            float2 q1 = __half22float2(*(const __half2*)&v.y);
            if (k & 1) { c0+=q0.x; c1+=q0.y; c2+=q1.x; c3+=q1.y; }
            else       { a0+=q0.x; a1+=q0.y; a2+=q1.x; a3+=q1.y; }
        }
    }
    if (e+4 <= s1) {
        int myIdx = csr[e + (l & 3)];
        #pragma unroll
        for (int k=0; k<4; ++k) {
            int idx = __shfl(myIdx, k, 8);
            uint2 v = t4[(long)idx*8 + l];
            float2 q0 = __half22float2(*(const __half2*)&v.x);
            float2 q1 = __half22float2(*(const __half2*)&v.y);
            if (k & 1) { c0+=q0.x; c1+=q0.y; c2+=q1.x; c3+=q1.y; }
            else       { a0+=q0.x; a1+=q0.y; a2+=q1.x; a3+=q1.y; }
        }
        e += 4;
    }
    for (; e<s1; ++e) {
        uint2 v = t4[(long)csr[e]*8 + l];
        float2 q0 = __half22float2(*(const __half2*)&v.x);
        float2 q1 = __half22float2(*(const __half2*)&v.y);
        a0+=q0.x; a1+=q0.y; a2+=q1.x; a3+=q1.y;
    }
    float ua[4];
    ua[0] = fmaxf(a0+c0 + bS[4*l+0], 0.f);
    ua[1] = fmaxf(a1+c1 + bS[4*l+1], 0.f);
    ua[2] = fmaxf(a2+c2 + bS[4*l+2], 0.f);
    ua[3] = fmaxf(a3+c3 + bS[4*l+3], 0.f);
    float zz[4];
    #pragma unroll
    for (int q=0; q<4; ++q) zz[q] = bS[DIM + 4*l + q];
    const float4* w4 = (const float4*)wS;
    #pragma unroll
    for (int j=0; j<DIM; ++j) {
        float uj = __shfl(ua[j & 3], j >> 2, 8);
        float4 wv = w4[j*8 + l];
        zz[0]+=uj*wv.x; zz[1]+=uj*wv.y; zz[2]+=uj*wv.z; zz[3]+=uj*wv.w;
    }
    #pragma unroll
    for (int q=0; q<4; ++q) zz[q] = fmaxf(zz[q], 0.f);
    ((float4*)z)[(long)node*8 + l] = make_float4(zz[0], zz[1], zz[2], zz[3]);
    // stats: reduce the 8 node-groups of each wave down to 8 lanes
    float sr[4], qr[4];
    #pragma unroll
    for (int q=0; q<4; ++q) { sr[q] = zz[q]; qr[q] = zz[q]*zz[q]; }
    #pragma unroll
    for (int q=0; q<4; ++q) {
        sr[q] += __shfl_down(sr[q], 32, 64); qr[q] += __shfl_down(qr[q], 32, 64);
        sr[q] += __shfl_down(sr[q], 16, 64); qr[q] += __shfl_down(qr[q], 16, 64);
        sr[q] += __shfl_down(sr[q],  8, 64); qr[q] += __shfl_down(qr[q],  8, 64);
    }
    if ((tid & 63) < 8) {
        #pragma unroll
        for (int q=0; q<4; ++q) {
            atomicAdd(&stS[4*l+q],       sr[q]);
            atomicAdd(&stS[DIM+4*l+q],   qr[q]);
        }
    }
    __syncthreads();
    if (tid < 2*DIM)
        atomicAdd(&part[((blockIdx.x & (NSLICE-1))<<6) + tid], stS[tid]);
}

// reduce partial stats -> scale/shift (still used for layer 4 -> k_pool)
__global__ __launch_bounds__(256) void k_scaleshift(
    const float* __restrict__ part,
    const float* __restrict__ gamma, const float* __restrict__ beta,
    int layer, float* __restrict__ ss)
{
    __shared__ float red[4][64];
    __shared__ float totS[64];
    int t = threadIdx.x;
    int ch = t & 63, q = t >> 6;
    float s = 0.f;
    for (int i = q*64; i < q*64 + 64; ++i) s += part[(i<<6) + ch];
    red[q][ch] = s;
    __syncthreads();
    if (t < 64) totS[t] = red[0][t]+red[1][t]+red[2][t]+red[3][t];
    __syncthreads();
    if (t < DIM) {
        float mean = totS[t] * (1.f/N_NODES);
        float var  = totS[DIM+t] * (1.f/N_NODES) - mean*mean;
        float sc = gamma[layer*DIM+t] * rsqrtf(var + 1e-5f);
        ss[t] = sc;
        ss[DIM+t] = beta[layer*DIM+t] - mean*sc;
    }
}

// Global add pool with BN applied: hg[batch[n]] += BN(z[n]).
__global__ __launch_bounds__(256) void k_pool(
    const float* __restrict__ z, const float* __restrict__ ss,
    const int* __restrict__ batch, float* __restrict__ hg)
{
    int tid = threadIdx.x;
    int node = blockIdx.x*32 + (tid>>3);
    int cq = tid & 7;                      // channels 4cq..4cq+3
    float4 v = ((const float4*)z)[(long)node*8 + cq];
    float4 sc = ((const float4*)ss)[cq];
    float4 sh = ((const float4*)ss)[8 + cq];
    v.x = v.x*sc.x + sh.x; v.y = v.y*sc.y + sh.y;
    v.z = v.z*sc.z + sh.z; v.w = v.w*sc.w + sh.w;
    int b = batch[node];
    int b0 = __shfl(b, 0, 64);
    int b7 = __shfl(b, 63, 64);
    if (b0 == b7) {
        #pragma unroll
        for (int off=8; off<64; off<<=1) {
            v.x += __shfl_xor(v.x, off, 64);
            v.y += __shfl_xor(v.y, off, 64);
            v.z += __shfl_xor(v.z, off, 64);
            v.w += __shfl_xor(v.w, off, 64);
        }
        if ((tid & 63) < 8) {
            float* dst = hg + (long)b0*DIM + cq*4;
            atomicAdd(dst+0, v.x); atomicAdd(dst+1, v.y);
            atomicAdd(dst+2, v.z); atomicAdd(dst+3, v.w);
        }
    } else {
        float* dst = hg + (long)b*DIM + cq*4;
        atomicAdd(dst+0, v.x); atomicAdd(dst+1, v.y);
        atomicAdd(dst+2, v.z); atomicAdd(dst+3, v.w);
    }
}

// xd = ReLU(hg @ w_fcxd + b) -> xc[:, 0:128]
__global__ __launch_bounds__(128) void k_xd(
    const float* __restrict__ hg, const float* __restrict__ w,
    const float* __restrict__ bias, float* __restrict__ xc)
{
    int b = blockIdx.x, n = threadIdx.x;
    __shared__ float hS[DIM];
    if (n < DIM) hS[n] = hg[b*DIM+n];
    __syncthreads();
    float acc = bias[n];
    #pragma unroll
    for (int r=0; r<DIM; ++r) acc += hS[r]*w[r*OUTD+n];
    xc[b*256 + n] = fmaxf(acc, 0.f);
}

// ---------------- protein branch ----------------

// conv_w (OIH fp32) -> cwT (fp16, layout [i][o*8+k], row = 256 halfs = 512B)
__global__ __launch_bounds__(256) void k_cw_transpose(
    const float* __restrict__ cw, __half* __restrict__ cwT)
{
    int g = blockIdx.x*256 + threadIdx.x;   // 256000 total
    int i = g >> 8;
    int j = g & 255;
    int o = j >> 3, k = j & 7;
    cwT[g] = __float2half(cw[o*(PLEN*KS) + i*KS + k]);
}

// convA: counting-sort + bucket-accumulate HALF the vocab (13 buckets) per
// block; G written fp16 to global. grid 2048 (2 blocks/graph), LDS 4.4 KB
// -> high occupancy hides phase-2's L2 latency.
__global__ __launch_bounds__(256) void k_convA(
    const int* __restrict__ target, const __half* __restrict__ cwTh,
    __half* __restrict__ G)
{
    __shared__ int sortedS[PLEN];
    __shared__ int meta[3*VOCAB+2];
    int* cntS = meta;
    int* segS = meta + VOCAB;          // [VOCAB+1]
    int* curS = meta + 2*VOCAB + 1;
    int bb = blockIdx.x, j = threadIdx.x;
    int b = bb >> 1, sub = bb & 1;
    if (j < VOCAB) cntS[j] = 0;
    __syncthreads();
    // ---- phase 1: counting sort (full; both halves need positions) ----
    int tloc[4];
    #pragma unroll
    for (int q=0; q<4; ++q) {
        int i = j + q*256;
        if (i < PLEN) {
            tloc[q] = target[b*PLEN+i];
            atomicAdd(&cntS[tloc[q]], 1);
        } else tloc[q] = -1;
    }
    __syncthreads();
    if (j == 0) {
        int run = 0;
        for (int v=0; v<VOCAB; ++v) { segS[v]=run; run += cntS[v]; }
        segS[VOCAB] = run;
    }
    __syncthreads();
    if (j < VOCAB) curS[j] = segS[j];
    __syncthreads();
    #pragma unroll
    for (int q=0; q<4; ++q) {
        int i = j + q*256;
        if (i < PLEN) {
            int pos = atomicAdd(&curS[tloc[q]], 1);
            sortedS[pos] = i;
        }
    }
    __syncthreads();
    // ---- phase 2: row-pair uint4 accumulate over this block's 13 buckets ----
    int w = j >> 6;
    int lane = j & 63;
    int half32 = lane >> 5;              // 0: even-index rows, 1: odd
    int c32 = lane & 31;                 // owns cols 8*c32..8*c32+7
    const uint4* cw4 = (const uint4*)cwTh;   // row = 32 uint4 (512B)
    __half2 hz = __float2half2_rn(0.f);
    int v0 = 13*sub, v1 = v0 + 13;
    int segbase = segS[v0];
    int tot = segS[v1] - segbase;
    for (int v=v0; v<v1; ++v) {
        int s = segS[v], e2 = segS[v+1];
        int wv = (tot > 0) ? ((s - segbase)*4)/tot : 0;
        if (wv > 3) wv = 3;
        if (wv != w) continue;
        float facc[8];
        #pragma unroll
        for (int q=0; q<8; ++q) facc[q] = 0.f;
        int p = s;
        for (; p+16 <= e2; p += 16) {    // 8 pairs; lane sums 8 rows in fp16
            __half2 h0=hz, h1=hz, h2=hz, h3=hz;
            #pragma unroll
            for (int u=0; u<8; ++u) {
                int i0 = sortedS[p+2*u], i1 = sortedS[p+2*u+1];
                int row = half32 ? i1 : i0;
                uint4 q4 = cw4[row*32 + c32];
                const __half2* hh = (const __half2*)&q4;
                h0 = __hadd2(h0, hh[0]); h1 = __hadd2(h1, hh[1]);
                h2 = __hadd2(h2, hh[2]); h3 = __hadd2(h3, hh[3]);
            }
            float2 f0=__half22float2(h0), f1=__half22float2(h1),
                   f2=__half22float2(h2), f3=__half22float2(h3);
            facc[0]+=f0.x; facc[1]+=f0.y; facc[2]+=f1.x; facc[3]+=f1.y;
            facc[4]+=f2.x; facc[5]+=f2.y; facc[6]+=f3.x; facc[7]+=f3.y;
        }
        for (; p+2 <= e2; p += 2) {      // tail pairs in fp32
            int i0 = sortedS[p], i1 = sortedS[p+1];
            int row = half32 ? i1 : i0;
            uint4 q4 = cw4[row*32 + c32];
            const __half2* hh = (const __half2*)&q4;
            float2 f0=__half22float2(hh[0]), f1=__half22float2(hh[1]),
                   f2=__half22float2(hh[2]), f3=__half22float2(hh[3]);
            facc[0]+=f0.x; facc[1]+=f0.y; facc[2]+=f1.x; facc[3]+=f1.y;
            facc[4]+=f2.x; facc[5]+=f2.y; facc[6]+=f3.x; facc[7]+=f3.y;
        }
        if (p < e2 && half32 == 0) {     // leftover single row, lower half only
            uint4 q4 = cw4[sortedS[p]*32 + c32];
            const __half2* hh = (const __half2*)&q4;
            float2 f0=__half22float2(hh[0]), f1=__half22float2(hh[1]),
                   f2=__half22float2(hh[2]), f3=__half22float2(hh[3]);
            facc[0]+=f0.x; facc[1]+=f0.y; facc[2]+=f1.x; facc[3]+=f1.y;
            facc[4]+=f2.x; facc[5]+=f2.y; facc[6]+=f3.x; facc[7]+=f3.y;
        }
        #pragma unroll
        for (int q=0; q<8; ++q) facc[q] += __shfl_xor(facc[q], 32, 64);
        if (half32 == 0) {
            __half2 o0 = __floats2half2_rn(facc[0], facc[1]);
            __half2 o1 = __floats2half2_rn(facc[2], facc[3]);
            __half2 o2 = __floats2half2_rn(facc[4], facc[5]);
            __half2 o3 = __floats2half2_rn(facc[6], facc[7]);
            uint4 pk;
            pk.x = *(unsigned int*)&o0; pk.y = *(unsigned int*)&o1;
            pk.z = *(unsigned int*)&o2; pk.w = *(unsigned int*)&o3;
            ((uint4*)(G + ((long)b*VOCAB + v)*256))[c32] = pk;
        }
    }
}

// convB: load graph's fp16 G (13.3 KB) into LDS, conv against emb chunks,
// write c. LDS union: [GsH 13312B][U 8320B]; stage (15488B) overlays after.
__global__ __launch_bounds__(256) void k_convB(
    const float* __restrict__ emb, const __half* __restrict__ G,
    const float* __restrict__ conv_b, float* __restrict__ c)
{
    __shared__ __align__(16) char buf[21632];
    __shared__ float cbS[NF];
    __half* GsH = (__half*)buf;               // 13312 B
    float*  U   = (float*)(buf + 13312);      // 8320 B (2080 floats)
    float*  stage = (float*)buf;              // overlays after final sync
    int b = blockIdx.x, j = threadIdx.x;
    if (j < NF) cbS[j] = conv_b[j];
    {
        const uint4* gsrc = (const uint4*)(G + (long)b*VOCAB*256);
        uint4* gdst = (uint4*)GsH;
        for (int i=j; i<832; i+=256) gdst[i] = gsrc[i];   // 832*16B = 13312B
    }
    int o = j >> 3, pg = j & 7;
    int t0 = pg*16;
    int tcnt = (t0+16 <= CLEN) ? 16 : (CLEN - t0);   // 16 or 9
    float out[16];
    __syncthreads();   // GsH + cbS ready
    #pragma unroll
    for (int q=0; q<16; ++q) out[q] = cbS[o];
    for (int ch=0; ch<2; ++ch) {
        __syncthreads();     // protect previous chunk's U reads
        for (int i=j; i<ECHUNK*EMBD; i+=256) {
            int v = i >> 7, tt = i & 127;
            U[v*EROW2 + tt + 4*(tt>>4)] = emb[(ch*ECHUNK + v)*EMBD + tt];
        }
        __syncthreads();
        for (int vv=0; vv<ECHUNK; ++vv) {
            uint4 gv = *(const uint4*)(GsH + (ch*ECHUNK+vv)*256 + o*8);
            const __half2* gh = (const __half2*)&gv;
            float2 ga = __half22float2(gh[0]), gb = __half22float2(gh[1]);
            float2 gc = __half22float2(gh[2]), gd = __half22float2(gh[3]);
            float g[8] = {ga.x,ga.y,gb.x,gb.y,gc.x,gc.y,gd.x,gd.y};
            const float* ev = &U[vv*EROW2 + 20*pg];
            float4 E0 = *(const float4*)(ev);
            float4 E1 = *(const float4*)(ev+4);
            float4 E2 = *(const float4*)(ev+8);
            float4 E3 = *(const float4*)(ev+12);
            float4 E4 = *(const float4*)(ev+20);
            float4 E5 = *(const float4*)(ev+24);
            float e[24] = {E0.x,E0.y,E0.z,E0.w, E1.x,E1.y,E1.z,E1.w,
                           E2.x,E2.y,E2.z,E2.w, E3.x,E3.y,E3.z,E3.w,
                           E4.x,E4.y,E4.z,E4.w, E5.x,E5.y,E5.z,E5.w};
            #pragma unroll
            for (int q=0; q<16; ++q) {
                float s = 0.f;
                #pragma unroll
                for (int k=0; k<KS; ++k) s += e[q+k]*g[k];
                out[q] += s;
            }
        }
    }
    __syncthreads();
    for (int q=0; q<tcnt; ++q) stage[o*CLEN + t0 + q] = out[q];
    __syncthreads();
    for (int idx=j; idx<FCX; idx+=256)
        c[(long)b*FCX + idx] = stage[idx];
}

// xt: [1024 x 3872] @ [3872 x 128], grid (64 graph-tiles x 16 K-splits).
#define XT_GB  16
#define XT_NS  16
#define XT_KS  (FCX/XT_NS)   // 242
#define XT_BK  22
#define XT_NCH (XT_KS/XT_BK) // 11
__global__ __launch_bounds__(256) void k_xt(
    const float* __restrict__ c, const float* __restrict__ w,
    float* __restrict__ xtp)
{
    __shared__ float cS[XT_GB][XT_BK];    // 1.4 KB
    __shared__ float wS[XT_BK][128];      // 11.3 KB
    int b0 = blockIdx.x * XT_GB;
    int ks0 = blockIdx.y * XT_KS;
    int tid = threadIdx.x;
    int g2 = tid >> 5;          // graph pair 0..7 -> graphs 2g2, 2g2+1
    int co = tid & 31;          // cols co*4..co*4+3
    int cg0 = tid / XT_BK, ck0 = tid - cg0*XT_BK;          // cS slot 0
    int i1 = tid + 256;
    int cg1 = i1 / XT_BK, ck1 = i1 - cg1*XT_BK;            // cS slot 1 (tid<96)
    float wreg[11], creg0, creg1;
    {
        int k0 = ks0;
        #pragma unroll
        for (int q=0; q<11; ++q) {
            int idx = tid + q*256;
            wreg[q] = w[(long)(k0 + (idx>>7))*OUTD + (idx & 127)];
        }
        creg0 = c[(long)(b0+cg0)*FCX + k0 + ck0];
        if (tid < 96) creg1 = c[(long)(b0+cg1)*FCX + k0 + ck1];
    }
    float acc[2][4];
    #pragma unroll
    for (int q=0; q<2; ++q)
      #pragma unroll
      for (int p=0; p<4; ++p) acc[q][p] = 0.f;
    for (int ch=0; ch<XT_NCH; ++ch) {
        #pragma unroll
        for (int q=0; q<11; ++q) {
            int idx = tid + q*256;
            wS[idx>>7][idx & 127] = wreg[q];
        }
        cS[cg0][ck0] = creg0;
        if (tid < 96) cS[cg1][ck1] = creg1;
        __syncthreads();
        if (ch+1 < XT_NCH) {
            int k0 = ks0 + (ch+1)*XT_BK;
            #pragma unroll
            for (int q=0; q<11; ++q) {
                int idx = tid + q*256;
                wreg[q] = w[(long)(k0 + (idx>>7))*OUTD + (idx & 127)];
            }
            creg0 = c[(long)(b0+cg0)*FCX + k0 + ck0];
            if (tid < 96) creg1 = c[(long)(b0+cg1)*FCX + k0 + ck1];
        }
        #pragma unroll
        for (int k2=0; k2<XT_BK/2; ++k2) {
            float2 cv0 = *(const float2*)&cS[2*g2  ][2*k2];
            float2 cv1 = *(const float2*)&cS[2*g2+1][2*k2];
            float4 wv0 = *(const float4*)&wS[2*k2  ][co*4];
            float4 wv1 = *(const float4*)&wS[2*k2+1][co*4];
            acc[0][0]+=cv0.x*wv0.x; acc[0][1]+=cv0.x*wv0.y;
            acc[0][2]+=cv0.x*wv0.z; acc[0][3]+=cv0.x*wv0.w;
            acc[1][0]+=cv1.x*wv0.x; acc[1][1]+=cv1.x*wv0.y;
            acc[1][2]+=cv1.x*wv0.z; acc[1][3]+=cv1.x*wv0.w;
            acc[0][0]+=cv0.y*wv1.x; acc[0][1]+=cv0.y*wv1.y;
            acc[0][2]+=cv0.y*wv1.z; acc[0][3]+=cv0.y*wv1.w;
            acc[1][0]+=cv1.y*wv1.x; acc[1][1]+=cv1.y*wv1.y;
            acc[1][2]+=cv1.y*wv1.z; acc[1][3]+=cv1.y*wv1.w;
        }
        __syncthreads();
    }
    #pragma unroll
    for (int q=0; q<2; ++q) {
        int g = b0 + 2*g2 + q;
        float4* dst = (float4*)(xtp + ((long)blockIdx.y*NB + g)*128);
        dst[co] = make_float4(acc[q][0], acc[q][1], acc[q][2], acc[q][3]);
    }
}

// sum the 16 K-split partials + bias -> xc[:, 128:256)
__global__ __launch_bounds__(256) void k_xt_red(
    const float* __restrict__ xtp, const float* __restrict__ bias,
    float* __restrict__ xc)
{
    int p = blockIdx.x*256 + threadIdx.x;   // 32768 float4 slots
    int g = p >> 5, c4 = p & 31;
    const float4* src = (const float4*)xtp;
    float4 s = src[(long)g*32 + c4];
    #pragma unroll
    for (int y=1; y<XT_NS; ++y) {
        float4 v = src[((long)y*NB + g)*32 + c4];
        s.x += v.x; s.y += v.y; s.z += v.z; s.w += v.w;
    }
    float4 bv = ((const float4*)bias)[c4];
    s.x += bv.x; s.y += bv.y; s.z += bv.z; s.w += bv.w;
    ((float4*)(xc + g*256 + 128))[c4] = s;
}

// ---------------- joint head ----------------
// fc1/fc2: K-split partial-sum GEMMs (no atomics), same recipe as k_xt.

#define FC1_NS 4
#define FC1_KR 64    // 256/FC1_NS rows per split
__global__ __launch_bounds__(256) void k_fc1(
    const float* __restrict__ xc, const float* __restrict__ w,
    float* __restrict__ y1p)
{
    __shared__ float xS[4][FC1_KR];
    int b0 = blockIdx.x*4;
    int r0 = blockIdx.y*FC1_KR;
    int n = threadIdx.x;
    xS[n>>6][n&63] = xc[(b0 + (n>>6))*256 + r0 + (n&63)];
    __syncthreads();
    float acc[4][4];   // [graph][m]
    #pragma unroll
    for (int q=0;q<4;++q)
      #pragma unroll
      for (int m=0;m<4;++m) acc[q][m]=0.f;
    for (int r=0; r<FC1_KR; ++r) {
        float x0=xS[0][r], x1=xS[1][r], x2=xS[2][r], x3=xS[3][r];
        #pragma unroll
        for (int m=0; m<4; ++m) {
            float wv = w[(long)(r0+r)*1024 + m*256 + n];
            acc[0][m]+=x0*wv; acc[1][m]+=x1*wv;
            acc[2][m]+=x2*wv; acc[3][m]+=x3*wv;
        }
    }
    long base = ((long)blockIdx.y*NB + b0)*1024;
    #pragma unroll
    for (int q=0; q<4; ++q)
        #pragma unroll
        for (int m=0; m<4; ++m)
            y1p[base + (long)q*1024 + m*256 + n] = acc[q][m];
}

__global__ __launch_bounds__(256) void k_fc1_red(
    const float* __restrict__ y1p, const float* __restrict__ bias,
    float* __restrict__ y)
{
    int p = blockIdx.x*256 + threadIdx.x;   // 262144 float4 slots
    int g = p >> 8, c4 = p & 255;
    const float4* src = (const float4*)y1p;
    float4 s = src[(long)g*256 + c4];
    #pragma unroll
    for (int yq=1; yq<FC1_NS; ++yq) {
        float4 v = src[((long)yq*NB + g)*256 + c4];
        s.x+=v.x; s.y+=v.y; s.z+=v.z; s.w+=v.w;
    }
    float4 bv = ((const float4*)bias)[c4];
    s.x = fmaxf(s.x+bv.x, 0.f); s.y = fmaxf(s.y+bv.y, 0.f);
    s.z = fmaxf(s.z+bv.z, 0.f); s.w = fmaxf(s.w+bv.w, 0.f);
    ((float4*)y)[(long)g*256 + c4] = s;
}

#define FC2_NS 8
#define FC2_KR 128   // 1024/FC2_NS rows per split
__global__ __launch_bounds__(256) void k_fc2(
    const float* __restrict__ y, const float* __restrict__ w,
    float* __restrict__ y2p)
{
    __shared__ float xS[4][FC2_KR];
    int b0 = blockIdx.x*4;
    int r0 = blockIdx.y*FC2_KR;
    int n = threadIdx.x;
    {
        int e1 = n + 256;
        xS[n>>7][n&127]   = y[(b0 + (n>>7))*1024  + r0 + (n&127)];
        xS[e1>>7][e1&127] = y[(b0 + (e1>>7))*1024 + r0 + (e1&127)];
    }
    __syncthreads();
    float acc[4] = {0.f, 0.f, 0.f, 0.f};
    for (int r=0; r<FC2_KR; ++r) {
        float wv = w[(long)(r0+r)*256 + n];
        acc[0]+=xS[0][r]*wv; acc[1]+=xS[1][r]*wv;
        acc[2]+=xS[2][r]*wv; acc[3]+=xS[3][r]*wv;
    }
    long base = ((long)blockIdx.y*NB + b0)*256;
    #pragma unroll
    for (int q=0; q<4; ++q) y2p[base + q*256 + n] = acc[q];
}

__global__ __launch_bounds__(256) void k_fc2_red(
    const float* __restrict__ y2p, const float* __restrict__ bias,
    float* __restrict__ y2)
{
    int p = blockIdx.x*256 + threadIdx.x;   // 65536 float4 slots
    int g = p >> 6, c4 = p & 63;
    const float4* src = (const float4*)y2p;
    float4 s = src[(long)g*64 + c4];
    #pragma unroll
    for (int yq=1; yq<FC2_NS; ++yq) {
        float4 v = src[((long)yq*NB + g)*64 + c4];
        s.x+=v.x; s.y+=v.y; s.z+=v.z; s.w+=v.w;
    }
    float4 bv = ((const float4*)bias)[c4];
    s.x = fmaxf(s.x+bv.x, 0.f); s.y = fmaxf(s.y+bv.y, 0.f);
    s.z = fmaxf(s.z+bv.z, 0.f); s.w = fmaxf(s.w+bv.w, 0.f);
    ((float4*)y2)[(long)g*64 + c4] = s;
}

__global__ __launch_bounds__(256) void k_out(
    const float* __restrict__ y2, const float* __restrict__ w,
    const float* __restrict__ bias, float* __restrict__ out)
{
    int b = blockIdx.x, n = threadIdx.x;
    float v = y2[b*256 + n] * w[n];
    #pragma unroll
    for (int off=32; off; off>>=1) v += __shfl_down(v, off, 64);
    __shared__ float red[4];
    if ((n & 63) == 0) red[n >> 6] = v;
    __syncthreads();
    if (n == 0) out[b] = red[0]+red[1]+red[2]+red[3] + bias[0];
}

// ---------------- launch ----------------

extern "C" void kernel_launch(void* const* d_in, const int* in_sizes, int n_in,
                              void* d_out, int out_size, void* d_ws, size_t ws_size,
                              hipStream_t stream) {
    const float* x      = (const float*)d_in[0];
    const int*   ei     = (const int*)  d_in[1];
    const int*   batch  = (const int*)  d_in[2];
    const int*   target = (const int*)  d_in[3];
    const float* w1a    = (const float*)d_in[4];
    const float* b1a    = (const float*)d_in[5];
    const float* w1b    = (const float*)d_in[6];
    const float* b1b    = (const float*)d_in[7];
    const float* wa     = (const float*)d_in[8];
    const float* ba     = (const float*)d_in[9];
    const float* wb     = (const float*)d_in[10];
    const float* bb     = (const float*)d_in[11];
    const float* gamma  = (const float*)d_in[12];
    const float* beta   = (const float*)d_in[13];
    const float* w_fcxd = (const float*)d_in[14];
    const float* b_fcxd = (const float*)d_in[15];
    const float* emb    = (const float*)d_in[16];
    const float* conv_w = (const float*)d_in[17];
    const float* conv_b = (const float*)d_in[18];
    const float* w_fcxt = (const float*)d_in[19];
    const float* b_fcxt = (const float*)d_in[20];
    const float* w_fc1  = (const float*)d_in[21];
    const float* b_fc1  = (const float*)d_in[22];
    const float* w_fc2  = (const float*)d_in[23];
    const float* b_fc2  = (const float*)d_in[24];
    const float* w_out  = (const float*)d_in[25];
    const float* b_out  = (const float*)d_in[26];

    float* ws      = (float*)d_ws;
    __half* tH     = (__half*)ws;                          // N*32 halfs = 1,048,576 float-slots
    float* z       = ws + 1048576;                         // N*32 floats (= 8 MB)
    unsigned int* pairs = (unsigned int*)(z + (size_t)N_NODES*DIM);  // E uints
    int*   csr     = (int*)(pairs + N_EDGES);              // E ints
    int*   rowptr  = csr + N_EDGES;                        // N+1 (+pad)
    int*   bktCnt  = rowptr + (N_NODES + 8);               // 256
    int*   bktBase = bktCnt + 256;                         // 257 (+pad)
    int*   bktCur  = bktBase + 264;                        // 256
    float* ss      = (float*)(bktCur + 256);               // 64
    float* hg      = ss + 64;                              // 32768
    float* cwT     = hg + (size_t)NB*DIM;                  // 256000 float-slots (fp16 uses half)
    float* cbuf    = cwT + 256000;                         // 3964928
    float* xc      = cbuf + (size_t)NB*FCX;                // 262144
    float* y1      = xc + (size_t)NB*256;                  // 1048576
    float* y2      = y1 + (size_t)NB*1024;                 // 262144
    float* part    = y2 + (size_t)NB*256;                  // 5 * 16384 floats
    __half* cwTh   = (__half*)cwT;
    float* xtp     = z;   // xt partials [16][1024][128]: aliases z (dead then)
    __half* Gbuf   = (__half*)z;   // fp16 G [1024][26][256]: aliases z+pairs-head
    float* y1p     = ws;             // fc1 partials [4][1024][1024] (dead tH/z region)
    float* y2p     = ws + 4194304;   // fc2 partials [8][1024][256] (dead pairs/csr-head)

    // ---- CSR build: bucket sort (coalesced) + fused rowptr/scatter ----
    hipMemsetAsync(bktCnt, 0, 256*sizeof(int), stream);
    k_bhist<<<NBKT, 256, 0, stream>>>(ei, bktCnt);
    k_bscan<<<1, 256, 0, stream>>>(bktCnt, bktBase, bktCur);
    k_bucketA<<<NBKT, 256, 0, stream>>>(ei, bktCur, pairs);
    k_fillB<<<NBKT, 256, 0, stream>>>(bktBase, pairs, rowptr, csr);

    // ---- protein branch ----
    k_cw_transpose<<<1000, 256, 0, stream>>>(conv_w, cwTh);
    k_convA<<<2*NB, 256, 0, stream>>>(target, cwTh, Gbuf);
    k_convB<<<NB, 256, 0, stream>>>(emb, Gbuf, conv_b, cbuf);
    k_xt<<<dim3(NB/XT_GB, XT_NS), 256, 0, stream>>>(cbuf, w_fcxt, xtp);
    k_xt_red<<<(NB*DIM)/256, 256, 0, stream>>>(xtp, b_fcxt, xc);

    // ---- GIN layers (per-layer part buffers; BN fused into transform) ----
    hipMemsetAsync(part, 0, 5*NSLICE*64*sizeof(float), stream);
    for (int l=0; l<5; ++l) {
        if (l == 0)
            k_l1_transform<<<N_NODES/256, 256, 0, stream>>>(x, w1a, tH);
        else
            k_transform<<<N_NODES/256, 256, 0, stream>>>(
                z, part + (size_t)(l-1)*NSLICE*64, gamma, beta, l-1,
                wa + (size_t)(l-1)*DIM*DIM, tH);
        const float* bi = (l==0) ? b1a : ba + (size_t)(l-1)*DIM;
        const float* wo = (l==0) ? w1b : wb + (size_t)(l-1)*DIM*DIM;
        const float* bo = (l==0) ? b1b : bb + (size_t)(l-1)*DIM;
        k_gather_mlp<<<N_NODES/32, 256, 0, stream>>>(
            rowptr, csr, tH, bi, wo, bo, z, part + (size_t)l*NSLICE*64);
    }
    k_scaleshift<<<1, 256, 0, stream>>>(part + (size_t)4*NSLICE*64, gamma, beta, 4, ss);

    // ---- pool + drug head ----
    hipMemsetAsync(hg, 0, (size_t)NB*DIM*sizeof(float), stream);
    k_pool<<<N_NODES/32, 256, 0, stream>>>(z, ss, batch, hg);
    k_xd<<<NB, 128, 0, stream>>>(hg, w_fcxd, b_fcxd, xc);

    // ---- joint head (K-split partials + reduce) ----
    k_fc1<<<dim3(NB/4, FC1_NS), 256, 0, stream>>>(xc, w_fc1, y1p);
    k_fc1_red<<<1024, 256, 0, stream>>>(y1p, b_fc1, y1);
    k_fc2<<<dim3(NB/4, FC2_NS), 256, 0, stream>>>(y1, w_fc2, y2p);
    k_fc2_red<<<256, 256, 0, stream>>>(y2p, b_fc2, y2);
    k_out<<<NB, 256, 0, stream>>>(y2, w_out, b_out, (float*)d_out);
}

// Round 9
// 622.506 us; speedup vs baseline: 1.2772x; 1.0187x over previous
//
#include <hip/hip_runtime.h>
#include <hip/hip_fp16.h>

#define N_NODES 65536
#define N_EDGES 2097152
#define NB      1024
#define FXD     78
#define DIM     32
#define EMBD    128
#define OUTD    128
#define VOCAB   26
#define PLEN    1000
#define KS      8
#define CLEN    121      // EMBD-KS+1
#define NF      32
#define FCX     (NF*CLEN)  // 3872
#define NBKT    256
#define EPB     8192     // edges per block (N_EDGES/256)
#define NSLICE  256      // stats partial slices

// ---------------- bucket sort (dst>>8) ----------------

// 256 blocks x 8192 edges: few global atomics into the 1KB bktCnt region.
__global__ __launch_bounds__(256) void k_bhist(
    const int* __restrict__ ei, int* __restrict__ bktCnt)
{
    __shared__ int h[NBKT];
    int tid = threadIdx.x;
    h[tid] = 0;
    __syncthreads();
    long base = (long)blockIdx.x * EPB;
    #pragma unroll 4
    for (int q=0; q<EPB/256; ++q) {
        int d = ei[N_EDGES + base + q*256 + tid];
        atomicAdd(&h[d>>8], 1);
    }
    __syncthreads();
    atomicAdd(&bktCnt[tid], h[tid]);
}

__global__ __launch_bounds__(256) void k_bscan(
    const int* __restrict__ bktCnt, int* __restrict__ bktBase, int* __restrict__ bktCur)
{
    __shared__ int s[NBKT];
    int t = threadIdx.x;
    int v = bktCnt[t];
    s[t] = v;
    __syncthreads();
    for (int off=1; off<256; off<<=1) {
        int tv = (t >= off) ? s[t-off] : 0;
        __syncthreads();
        s[t] += tv;
        __syncthreads();
    }
    int ex = s[t] - v;
    bktBase[t] = ex;
    bktCur[t] = ex;
    if (t == 255) bktBase[256] = s[255];   // == N_EDGES
}

// LDS-sort 8192 edges by bucket, write packed (dst<<16|src) in coalesced runs
__global__ __launch_bounds__(256) void k_bucketA(
    const int* __restrict__ ei, int* __restrict__ bktCur, unsigned int* __restrict__ pairs)
{
    __shared__ unsigned int raw[EPB];       // 32 KB
    __shared__ unsigned int srt[EPB];       // 32 KB
    __shared__ unsigned char bOf[EPB];      // 8 KB
    __shared__ int hist[NBKT], sc[NBKT], lcur[NBKT], gbase[NBKT];
    int tid = threadIdx.x;
    hist[tid] = 0;
    __syncthreads();
    int eb = blockIdx.x * EPB;
    for (int i=tid; i<EPB; i+=256) {
        int s = ei[eb+i];
        int d = ei[N_EDGES+eb+i];
        raw[i] = ((unsigned int)d<<16) | (unsigned int)s;
        atomicAdd(&hist[d>>8], 1);
    }
    __syncthreads();
    int v = hist[tid];
    sc[tid] = v;
    __syncthreads();
    for (int off=1; off<256; off<<=1) {
        int tv = (tid >= off) ? sc[tid-off] : 0;
        __syncthreads();
        sc[tid] += tv;
        __syncthreads();
    }
    int ex = sc[tid] - v;
    sc[tid] = ex;            // exclusive local base
    lcur[tid] = ex;
    gbase[tid] = atomicAdd(&bktCur[tid], v);
    __syncthreads();
    for (int i=tid; i<EPB; i+=256) {
        unsigned int p = raw[i];
        int k = p >> 24;
        int pos = atomicAdd(&lcur[k], 1);
        srt[pos] = p;
        bOf[pos] = (unsigned char)k;
    }
    __syncthreads();
    for (int i=tid; i<EPB; i+=256) {
        int k = bOf[i];
        pairs[gbase[k] + (i - sc[k])] = srt[i];
    }
}

// per bucket: build rowptr (LDS histogram + scan) and scatter srcs into the
// bucket's contiguous CSR segment.
__global__ __launch_bounds__(256) void k_fillB(
    const int* __restrict__ bktBase, const unsigned int* __restrict__ pairs,
    int* __restrict__ rowptr, int* __restrict__ csr)
{
    __shared__ int hist[256], sc[256], cur[256];
    int b = blockIdx.x, tid = threadIdx.x;
    int node0 = b*256;
    hist[tid] = 0;
    __syncthreads();
    int s = bktBase[b], e = bktBase[b+1];
    for (int i = s + tid; i < e; i += 256)
        atomicAdd(&hist[(pairs[i] >> 16) & 255], 1);
    __syncthreads();
    int v = hist[tid];
    sc[tid] = v;
    __syncthreads();
    for (int off=1; off<256; off<<=1) {
        int tv = (tid >= off) ? sc[tid-off] : 0;
        __syncthreads();
        sc[tid] += tv;
        __syncthreads();
    }
    int base = s + sc[tid] - v;     // exclusive
    rowptr[node0 + tid] = base;
    cur[tid] = base;
    if (b == NBKT-1 && tid == 255) rowptr[N_NODES] = N_EDGES;
    __syncthreads();
    for (int i = s + tid; i < e; i += 256) {
        unsigned int p = pairs[i];
        int pos = atomicAdd(&cur[(p >> 16) & 255], 1);
        csr[pos] = (int)(p & 0xFFFFu);
    }
}

// ---------------- GIN layer kernels ----------------

// Layer-1 transform: t = x @ w1a  (fp16 out)
__global__ __launch_bounds__(256) void k_l1_transform(
    const float* __restrict__ x, const float* __restrict__ w,
    __half* __restrict__ t)
{
    __shared__ float wS[FXD*DIM];
    for (int i = threadIdx.x; i < FXD*DIM; i += 256) wS[i] = w[i];
    __syncthreads();
    int node = blockIdx.x*256 + threadIdx.x;
    float acc[DIM];
    #pragma unroll
    for (int d=0; d<DIM; ++d) acc[d] = 0.f;
    const float* xr = x + (long)node*FXD;
    for (int j=0; j<FXD; ++j) {
        float xv = xr[j];
        #pragma unroll
        for (int d=0; d<DIM; ++d) acc[d] += xv * wS[j*DIM+d];
    }
    union { __half2 h2[16]; uint4 u4[4]; } pk;
    #pragma unroll
    for (int q=0; q<16; ++q) pk.h2[q] = __floats2half2_rn(acc[2*q], acc[2*q+1]);
    uint4* dst4 = (uint4*)(t + (long)node*DIM);
    #pragma unroll
    for (int q=0; q<4; ++q) dst4[q] = pk.u4[q];
}

// Layers 2-5: computes BN scale/shift IN-BLOCK from the stats partials of
// the previous layer, then t = BN(z) @ w  (fp16 out).
__global__ __launch_bounds__(256) void k_transform(
    const float* __restrict__ z, const float* __restrict__ part,
    const float* __restrict__ gamma, const float* __restrict__ beta, int layer,
    const float* __restrict__ w, __half* __restrict__ t)
{
    __shared__ float wS[DIM*DIM];
    __shared__ float red[4][64];
    __shared__ float sS[2*DIM];
    int tid = threadIdx.x;
    for (int i=tid; i<DIM*DIM; i+=256) wS[i] = w[i];
    {
        int ch = tid & 63, qq = tid >> 6;
        float s = 0.f;
        for (int i = qq*64; i < qq*64 + 64; ++i) s += part[(i<<6) + ch];
        red[qq][ch] = s;
    }
    __syncthreads();
    if (tid < DIM) {
        float tots = red[0][tid]+red[1][tid]+red[2][tid]+red[3][tid];
        float totq = red[0][DIM+tid]+red[1][DIM+tid]+red[2][DIM+tid]+red[3][DIM+tid];
        float mean = tots * (1.f/N_NODES);
        float var  = totq * (1.f/N_NODES) - mean*mean;
        float sc = gamma[layer*DIM+tid] * rsqrtf(var + 1e-5f);
        sS[tid] = sc;
        sS[DIM+tid] = beta[layer*DIM+tid] - mean*sc;
    }
    __syncthreads();
    int node = blockIdx.x*256 + tid;
    float h[DIM];
    const float4* z4 = (const float4*)(z + (long)node*DIM);
    #pragma unroll
    for (int q=0; q<DIM/4; ++q) {
        float4 v = z4[q];
        h[q*4+0]=v.x; h[q*4+1]=v.y; h[q*4+2]=v.z; h[q*4+3]=v.w;
    }
    #pragma unroll
    for (int d=0; d<DIM; ++d) h[d] = h[d]*sS[d] + sS[DIM+d];
    float acc[DIM];
    #pragma unroll
    for (int d=0; d<DIM; ++d) acc[d] = 0.f;
    #pragma unroll
    for (int j=0; j<DIM; ++j) {
        float hv = h[j];
        #pragma unroll
        for (int d=0; d<DIM; ++d) acc[d] += hv * wS[j*DIM+d];
    }
    union { __half2 h2[16]; uint4 u4[4]; } pk;
    #pragma unroll
    for (int q=0; q<16; ++q) pk.h2[q] = __floats2half2_rn(acc[2*q], acc[2*q+1]);
    uint4* dst4 = (uint4*)(t + (long)node*DIM);
    #pragma unroll
    for (int q=0; q<4; ++q) dst4[q] = pk.u4[q];
}

// Gather (CSR) + self + MLP + ReLU + BN-stats partials.
__global__ __launch_bounds__(256) void k_gather_mlp(
    const int* __restrict__ rowptr, const int* __restrict__ csr,
    const __half* __restrict__ t,
    const float* __restrict__ bi, const float* __restrict__ wo, const float* __restrict__ bo,
    float* __restrict__ z, float* __restrict__ part)
{
    __shared__ float wS[DIM*DIM];
    __shared__ float bS[2*DIM];
    __shared__ float stS[2*DIM];
    int tid = threadIdx.x;
    for (int i=tid; i<DIM*DIM; i+=256) wS[i]=wo[i];
    if (tid<DIM) bS[tid]=bi[tid];
    else if (tid<2*DIM) bS[tid]=bo[tid-DIM];
    if (tid<2*DIM) stS[tid]=0.f;
    __syncthreads();
    int g = tid >> 3;           // node 0..31 within block
    int l = tid & 7;            // lane in group; owns channels 4l..4l+3
    int node = blockIdx.x*32 + g;
    const uint2* t4 = (const uint2*)t;   // 8B = 4 halfs; 8 entries per row
    uint2 sv = t4[(long)node*8 + l];     // self term
    float2 p0 = __half22float2(*(const __half2*)&sv.x);
    float2 p1 = __half22float2(*(const __half2*)&sv.y);
    float a0=p0.x, a1=p0.y, a2=p1.x, a3=p1.y;
    float c0=0.f, c1=0.f, c2=0.f, c3=0.f;
    int s0 = rowptr[node], s1 = rowptr[node+1];
    int e = s0;
    for (; e+8 <= s1; e+=8) {
        int myIdx = csr[e + l];          // 8 consecutive, coalesced
        #pragma unroll
        for (int k=0; k<8; ++k) {
            int idx = __shfl(myIdx, k, 8);
            uint2 v = t4[(long)idx*8 + l];
            float2 q0 = __half22float2(*(const __half2*)&v.x);
            float2 q1 = __half22float2(*(const __half2*)&v.y);
            if (k & 1) { c0+=q0.x; c1+=q0.y; c2+=q1.x; c3+=q1.y; }
            else       { a0+=q0.x; a1+=q0.y; a2+=q1.x; a3+=q1.y; }
        }
    }
    if (e+4 <= s1) {
        int myIdx = csr[e + (l & 3)];
        #pragma unroll
        for (int k=0; k<4; ++k) {
            int idx = __shfl(myIdx, k, 8);
            uint2 v = t4[(long)idx*8 + l];
            float2 q0 = __half22float2(*(const __half2*)&v.x);
            float2 q1 = __half22float2(*(const __half2*)&v.y);
            if (k & 1) { c0+=q0.x; c1+=q0.y; c2+=q1.x; c3+=q1.y; }
            else       { a0+=q0.x; a1+=q0.y; a2+=q1.x; a3+=q1.y; }
        }
        e += 4;
    }
    for (; e<s1; ++e) {
        uint2 v = t4[(long)csr[e]*8 + l];
        float2 q0 = __half22float2(*(const __half2*)&v.x);
        float2 q1 = __half22float2(*(const __half2*)&v.y);
        a0+=q0.x; a1+=q0.y; a2+=q1.x; a3+=q1.y;
    }
    float ua[4];
    ua[0] = fmaxf(a0+c0 + bS[4*l+0], 0.f);
    ua[1] = fmaxf(a1+c1 + bS[4*l+1], 0.f);
    ua[2] = fmaxf(a2+c2 + bS[4*l+2], 0.f);
    ua[3] = fmaxf(a3+c3 + bS[4*l+3], 0.f);
    float zz[4];
    #pragma unroll
    for (int q=0; q<4; ++q) zz[q] = bS[DIM + 4*l + q];
    const float4* w4 = (const float4*)wS;
    #pragma unroll
    for (int j=0; j<DIM; ++j) {
        float uj = __shfl(ua[j & 3], j >> 2, 8);
        float4 wv = w4[j*8 + l];
        zz[0]+=uj*wv.x; zz[1]+=uj*wv.y; zz[2]+=uj*wv.z; zz[3]+=uj*wv.w;
    }
    #pragma unroll
    for (int q=0; q<4; ++q) zz[q] = fmaxf(zz[q], 0.f);
    ((float4*)z)[(long)node*8 + l] = make_float4(zz[0], zz[1], zz[2], zz[3]);
    // stats: reduce the 8 node-groups of each wave down to 8 lanes
    float sr[4], qr[4];
    #pragma unroll
    for (int q=0; q<4; ++q) { sr[q] = zz[q]; qr[q] = zz[q]*zz[q]; }
    #pragma unroll
    for (int q=0; q<4; ++q) {
        sr[q] += __shfl_down(sr[q], 32, 64); qr[q] += __shfl_down(qr[q], 32, 64);
        sr[q] += __shfl_down(sr[q], 16, 64); qr[q] += __shfl_down(qr[q], 16, 64);
        sr[q] += __shfl_down(sr[q],  8, 64); qr[q] += __shfl_down(qr[q],  8, 64);
    }
    if ((tid & 63) < 8) {
        #pragma unroll
        for (int q=0; q<4; ++q) {
            atomicAdd(&stS[4*l+q],       sr[q]);
            atomicAdd(&stS[DIM+4*l+q],   qr[q]);
        }
    }
    __syncthreads();
    if (tid < 2*DIM)
        atomicAdd(&part[((blockIdx.x & (NSLICE-1))<<6) + tid], stS[tid]);
}

// reduce partial stats -> scale/shift (still used for layer 4 -> k_pool)
__global__ __launch_bounds__(256) void k_scaleshift(
    const float* __restrict__ part,
    const float* __restrict__ gamma, const float* __restrict__ beta,
    int layer, float* __restrict__ ss)
{
    __shared__ float red[4][64];
    __shared__ float totS[64];
    int t = threadIdx.x;
    int ch = t & 63, q = t >> 6;
    float s = 0.f;
    for (int i = q*64; i < q*64 + 64; ++i) s += part[(i<<6) + ch];
    red[q][ch] = s;
    __syncthreads();
    if (t < 64) totS[t] = red[0][t]+red[1][t]+red[2][t]+red[3][t];
    __syncthreads();
    if (t < DIM) {
        float mean = totS[t] * (1.f/N_NODES);
        float var  = totS[DIM+t] * (1.f/N_NODES) - mean*mean;
        float sc = gamma[layer*DIM+t] * rsqrtf(var + 1e-5f);
        ss[t] = sc;
        ss[DIM+t] = beta[layer*DIM+t] - mean*sc;
    }
}

// Global add pool with BN applied: hg[batch[n]] += BN(z[n]).
__global__ __launch_bounds__(256) void k_pool(
    const float* __restrict__ z, const float* __restrict__ ss,
    const int* __restrict__ batch, float* __restrict__ hg)
{
    int tid = threadIdx.x;
    int node = blockIdx.x*32 + (tid>>3);
    int cq = tid & 7;                      // channels 4cq..4cq+3
    float4 v = ((const float4*)z)[(long)node*8 + cq];
    float4 sc = ((const float4*)ss)[cq];
    float4 sh = ((const float4*)ss)[8 + cq];
    v.x = v.x*sc.x + sh.x; v.y = v.y*sc.y + sh.y;
    v.z = v.z*sc.z + sh.z; v.w = v.w*sc.w + sh.w;
    int b = batch[node];
    int b0 = __shfl(b, 0, 64);
    int b7 = __shfl(b, 63, 64);
    if (b0 == b7) {
        #pragma unroll
        for (int off=8; off<64; off<<=1) {
            v.x += __shfl_xor(v.x, off, 64);
            v.y += __shfl_xor(v.y, off, 64);
            v.z += __shfl_xor(v.z, off, 64);
            v.w += __shfl_xor(v.w, off, 64);
        }
        if ((tid & 63) < 8) {
            float* dst = hg + (long)b0*DIM + cq*4;
            atomicAdd(dst+0, v.x); atomicAdd(dst+1, v.y);
            atomicAdd(dst+2, v.z); atomicAdd(dst+3, v.w);
        }
    } else {
        float* dst = hg + (long)b*DIM + cq*4;
        atomicAdd(dst+0, v.x); atomicAdd(dst+1, v.y);
        atomicAdd(dst+2, v.z); atomicAdd(dst+3, v.w);
    }
}

// xd = ReLU(hg @ w_fcxd + b) -> xc[:, 0:128]
__global__ __launch_bounds__(128) void k_xd(
    const float* __restrict__ hg, const float* __restrict__ w,
    const float* __restrict__ bias, float* __restrict__ xc)
{
    int b = blockIdx.x, n = threadIdx.x;
    __shared__ float hS[DIM];
    if (n < DIM) hS[n] = hg[b*DIM+n];
    __syncthreads();
    float acc = bias[n];
    #pragma unroll
    for (int r=0; r<DIM; ++r) acc += hS[r]*w[r*OUTD+n];
    xc[b*256 + n] = fmaxf(acc, 0.f);
}

// ---------------- protein branch ----------------

// conv_w (OIH fp32) -> cwT (fp16, layout [i][o*8+k], row = 256 halfs = 512B)
__global__ __launch_bounds__(256) void k_cw_transpose(
    const float* __restrict__ cw, __half* __restrict__ cwT)
{
    int g = blockIdx.x*256 + threadIdx.x;   // 256000 total
    int i = g >> 8;
    int j = g & 255;
    int o = j >> 3, k = j & 7;
    cwT[g] = __float2half(cw[o*(PLEN*KS) + i*KS + k]);
}

// convA: counting-sort + bucket-accumulate HALF the vocab (13 buckets) per
// block; G written fp16 to global. grid 2048 (2 blocks/graph), LDS 4.4 KB.
__global__ __launch_bounds__(256) void k_convA(
    const int* __restrict__ target, const __half* __restrict__ cwTh,
    __half* __restrict__ G)
{
    __shared__ int sortedS[PLEN];
    __shared__ int meta[3*VOCAB+2];
    int* cntS = meta;
    int* segS = meta + VOCAB;          // [VOCAB+1]
    int* curS = meta + 2*VOCAB + 1;
    int bb = blockIdx.x, j = threadIdx.x;
    int b = bb >> 1, sub = bb & 1;
    if (j < VOCAB) cntS[j] = 0;
    __syncthreads();
    // ---- phase 1: counting sort (full; both halves need positions) ----
    int tloc[4];
    #pragma unroll
    for (int q=0; q<4; ++q) {
        int i = j + q*256;
        if (i < PLEN) {
            tloc[q] = target[b*PLEN+i];
            atomicAdd(&cntS[tloc[q]], 1);
        } else tloc[q] = -1;
    }
    __syncthreads();
    if (j == 0) {
        int run = 0;
        for (int v=0; v<VOCAB; ++v) { segS[v]=run; run += cntS[v]; }
        segS[VOCAB] = run;
    }
    __syncthreads();
    if (j < VOCAB) curS[j] = segS[j];
    __syncthreads();
    #pragma unroll
    for (int q=0; q<4; ++q) {
        int i = j + q*256;
        if (i < PLEN) {
            int pos = atomicAdd(&curS[tloc[q]], 1);
            sortedS[pos] = i;
        }
    }
    __syncthreads();
    // ---- phase 2: row-pair uint4 accumulate over this block's 13 buckets ----
    int w = j >> 6;
    int lane = j & 63;
    int half32 = lane >> 5;              // 0: even-index rows, 1: odd
    int c32 = lane & 31;                 // owns cols 8*c32..8*c32+7
    const uint4* cw4 = (const uint4*)cwTh;   // row = 32 uint4 (512B)
    __half2 hz = __float2half2_rn(0.f);
    int v0 = 13*sub, v1 = v0 + 13;
    int segbase = segS[v0];
    int tot = segS[v1] - segbase;
    for (int v=v0; v<v1; ++v) {
        int s = segS[v], e2 = segS[v+1];
        int wv = (tot > 0) ? ((s - segbase)*4)/tot : 0;
        if (wv > 3) wv = 3;
        if (wv != w) continue;
        float facc[8];
        #pragma unroll
        for (int q=0; q<8; ++q) facc[q] = 0.f;
        int p = s;
        for (; p+16 <= e2; p += 16) {    // 8 pairs; lane sums 8 rows in fp16
            __half2 h0=hz, h1=hz, h2=hz, h3=hz;
            #pragma unroll
            for (int u=0; u<8; ++u) {
                int i0 = sortedS[p+2*u], i1 = sortedS[p+2*u+1];
                int row = half32 ? i1 : i0;
                uint4 q4 = cw4[row*32 + c32];
                const __half2* hh = (const __half2*)&q4;
                h0 = __hadd2(h0, hh[0]); h1 = __hadd2(h1, hh[1]);
                h2 = __hadd2(h2, hh[2]); h3 = __hadd2(h3, hh[3]);
            }
            float2 f0=__half22float2(h0), f1=__half22float2(h1),
                   f2=__half22float2(h2), f3=__half22float2(h3);
            facc[0]+=f0.x; facc[1]+=f0.y; facc[2]+=f1.x; facc[3]+=f1.y;
            facc[4]+=f2.x; facc[5]+=f2.y; facc[6]+=f3.x; facc[7]+=f3.y;
        }
        for (; p+2 <= e2; p += 2) {      // tail pairs in fp32
            int i0 = sortedS[p], i1 = sortedS[p+1];
            int row = half32 ? i1 : i0;
            uint4 q4 = cw4[row*32 + c32];
            const __half2* hh = (const __half2*)&q4;
            float2 f0=__half22float2(hh[0]), f1=__half22float2(hh[1]),
                   f2=__half22float2(hh[2]), f3=__half22float2(hh[3]);
            facc[0]+=f0.x; facc[1]+=f0.y; facc[2]+=f1.x; facc[3]+=f1.y;
            facc[4]+=f2.x; facc[5]+=f2.y; facc[6]+=f3.x; facc[7]+=f3.y;
        }
        if (p < e2 && half32 == 0) {     // leftover single row, lower half only
            uint4 q4 = cw4[sortedS[p]*32 + c32];
            const __half2* hh = (const __half2*)&q4;
            float2 f0=__half22float2(hh[0]), f1=__half22float2(hh[1]),
                   f2=__half22float2(hh[2]), f3=__half22float2(hh[3]);
            facc[0]+=f0.x; facc[1]+=f0.y; facc[2]+=f1.x; facc[3]+=f1.y;
            facc[4]+=f2.x; facc[5]+=f2.y; facc[6]+=f3.x; facc[7]+=f3.y;
        }
        #pragma unroll
        for (int q=0; q<8; ++q) facc[q] += __shfl_xor(facc[q], 32, 64);
        if (half32 == 0) {
            __half2 o0 = __floats2half2_rn(facc[0], facc[1]);
            __half2 o1 = __floats2half2_rn(facc[2], facc[3]);
            __half2 o2 = __floats2half2_rn(facc[4], facc[5]);
            __half2 o3 = __floats2half2_rn(facc[6], facc[7]);
            uint4 pk;
            pk.x = *(unsigned int*)&o0; pk.y = *(unsigned int*)&o1;
            pk.z = *(unsigned int*)&o2; pk.w = *(unsigned int*)&o3;
            ((uint4*)(G + ((long)b*VOCAB + v)*256))[c32] = pk;
        }
    }
}

// mprep: M[(v*256 + o*8 + k)*128 + n] = sum_t emb[v][t+k] * w[(o*121+t)*128+n]
// (conv folded into the xt GEMM: xt = G_flat[1024x6656] @ M[6656x128] + C0).
// grid 832 = v*32+o, 256 threads (n = tid&127, kb = tid>>7 covers k=kb+2q).
// Also accumulates C0[n] = sum_o conv_b[o]*sum_t w[o121+t][n] via atomics.
__global__ __launch_bounds__(256) void k_mprep(
    const float* __restrict__ emb, const float* __restrict__ w,
    const float* __restrict__ conv_b, float* __restrict__ M,
    float* __restrict__ C0)
{
    __shared__ float eS[EMBD];
    int v = blockIdx.x >> 5, o = blockIdx.x & 31;
    int tid = threadIdx.x;
    if (tid < EMBD) eS[tid] = emb[v*EMBD + tid];
    __syncthreads();
    int n = tid & 127, kb = tid >> 7;
    float acc[4] = {0.f, 0.f, 0.f, 0.f};
    float c0 = 0.f;
    const float* wp = w + (long)(o*CLEN)*OUTD + n;
    for (int t2=0; t2<CLEN; ++t2) {
        float wv = wp[(long)t2*OUTD];
        c0 += wv;
        #pragma unroll
        for (int q=0; q<4; ++q) acc[q] += eS[t2 + kb + 2*q] * wv;
    }
    long base = ((long)(v*256 + o*8)) * 128 + n;
    #pragma unroll
    for (int q=0; q<4; ++q) M[base + (long)(kb + 2*q)*128] = acc[q];
    if (v == 0 && kb == 0) atomicAdd(&C0[n], c0 * conv_b[o]);
}

// xtg: xt partials = G[1024 x 6656](fp16) @ M[6656 x 128](fp32).
// grid (64 graph-tiles x 16 K-splits), K-slice 416, 13 chunks of BK=32.
// Register-prefetched staging; partial stores (no atomics) + k_xtg_red.
#define XG_GB  16
#define XG_NS  16
#define XG_K   (VOCAB*256)       // 6656
#define XG_KS  (XG_K/XG_NS)      // 416
#define XG_BK  32
#define XG_NCH (XG_KS/XG_BK)     // 13
__global__ __launch_bounds__(256) void k_xtg(
    const __half* __restrict__ G, const float* __restrict__ M,
    float* __restrict__ xtp)
{
    __shared__ float bS[XG_BK][128];      // 16 KB
    __shared__ __half aS[XG_GB][XG_BK];   // 1 KB
    int b0 = blockIdx.x * XG_GB;
    int ks0 = blockIdx.y * XG_KS;
    int tid = threadIdx.x;
    int g2 = tid >> 5, co = tid & 31;
    int ag = tid >> 4, au = tid & 15;     // aS row / uint col (16 uints = 32 halfs)
    const unsigned int* G32 = (const unsigned int*)G;   // row = 3328 uints
    float breg[16];
    unsigned int areg;
    {
        int k0 = ks0;
        #pragma unroll
        for (int q=0; q<16; ++q) {
            int idx = tid + q*256;
            breg[q] = M[(long)(k0 + (idx>>7))*128 + (idx & 127)];
        }
        areg = G32[(long)(b0+ag)*3328 + (k0>>1) + au];
    }
    float acc[2][4];
    #pragma unroll
    for (int q=0; q<2; ++q)
      #pragma unroll
      for (int p=0; p<4; ++p) acc[q][p] = 0.f;
    for (int ch=0; ch<XG_NCH; ++ch) {
        #pragma unroll
        for (int q=0; q<16; ++q) {
            int idx = tid + q*256;
            bS[idx>>7][idx & 127] = breg[q];
        }
        ((unsigned int*)aS)[ag*16 + au] = areg;
        __syncthreads();
        if (ch+1 < XG_NCH) {
            int k0 = ks0 + (ch+1)*XG_BK;
            #pragma unroll
            for (int q=0; q<16; ++q) {
                int idx = tid + q*256;
                breg[q] = M[(long)(k0 + (idx>>7))*128 + (idx & 127)];
            }
            areg = G32[(long)(b0+ag)*3328 + (k0>>1) + au];
        }
        #pragma unroll
        for (int kk=0; kk<XG_BK; ++kk) {
            float a0 = __half2float(aS[2*g2  ][kk]);
            float a1 = __half2float(aS[2*g2+1][kk]);
            float4 wv = *(const float4*)&bS[kk][co*4];
            acc[0][0]+=a0*wv.x; acc[0][1]+=a0*wv.y;
            acc[0][2]+=a0*wv.z; acc[0][3]+=a0*wv.w;
            acc[1][0]+=a1*wv.x; acc[1][1]+=a1*wv.y;
            acc[1][2]+=a1*wv.z; acc[1][3]+=a1*wv.w;
        }
        __syncthreads();
    }
    #pragma unroll
    for (int q=0; q<2; ++q) {
        int g = b0 + 2*g2 + q;
        float4* dst = (float4*)(xtp + ((long)blockIdx.y*NB + g)*128);
        dst[co] = make_float4(acc[q][0], acc[q][1], acc[q][2], acc[q][3]);
    }
}

// sum the 16 K-split partials + C0 + bias -> xc[:, 128:256)
__global__ __launch_bounds__(256) void k_xtg_red(
    const float* __restrict__ xtp, const float* __restrict__ bias,
    const float* __restrict__ C0, float* __restrict__ xc)
{
    int p = blockIdx.x*256 + threadIdx.x;   // 32768 float4 slots
    int g = p >> 5, c4 = p & 31;
    const float4* src = (const float4*)xtp;
    float4 s = src[(long)g*32 + c4];
    #pragma unroll
    for (int y=1; y<XG_NS; ++y) {
        float4 v = src[((long)y*NB + g)*32 + c4];
        s.x += v.x; s.y += v.y; s.z += v.z; s.w += v.w;
    }
    float4 bv = ((const float4*)bias)[c4];
    float4 cv = ((const float4*)C0)[c4];
    s.x += bv.x + cv.x; s.y += bv.y + cv.y;
    s.z += bv.z + cv.z; s.w += bv.w + cv.w;
    ((float4*)(xc + g*256 + 128))[c4] = s;
}

// ---------------- joint head ----------------
// fc1/fc2: K-split partial-sum GEMMs (no atomics).

#define FC1_NS 4
#define FC1_KR 64    // 256/FC1_NS rows per split
__global__ __launch_bounds__(256) void k_fc1(
    const float* __restrict__ xc, const float* __restrict__ w,
    float* __restrict__ y1p)
{
    __shared__ float xS[4][FC1_KR];
    int b0 = blockIdx.x*4;
    int r0 = blockIdx.y*FC1_KR;
    int n = threadIdx.x;
    xS[n>>6][n&63] = xc[(b0 + (n>>6))*256 + r0 + (n&63)];
    __syncthreads();
    float acc[4][4];   // [graph][m]
    #pragma unroll
    for (int q=0;q<4;++q)
      #pragma unroll
      for (int m=0;m<4;++m) acc[q][m]=0.f;
    for (int r=0; r<FC1_KR; ++r) {
        float x0=xS[0][r], x1=xS[1][r], x2=xS[2][r], x3=xS[3][r];
        #pragma unroll
        for (int m=0; m<4; ++m) {
            float wv = w[(long)(r0+r)*1024 + m*256 + n];
            acc[0][m]+=x0*wv; acc[1][m]+=x1*wv;
            acc[2][m]+=x2*wv; acc[3][m]+=x3*wv;
        }
    }
    long base = ((long)blockIdx.y*NB + b0)*1024;
    #pragma unroll
    for (int q=0; q<4; ++q)
        #pragma unroll
        for (int m=0; m<4; ++m)
            y1p[base + (long)q*1024 + m*256 + n] = acc[q][m];
}

__global__ __launch_bounds__(256) void k_fc1_red(
    const float* __restrict__ y1p, const float* __restrict__ bias,
    float* __restrict__ y)
{
    int p = blockIdx.x*256 + threadIdx.x;   // 262144 float4 slots
    int g = p >> 8, c4 = p & 255;
    const float4* src = (const float4*)y1p;
    float4 s = src[(long)g*256 + c4];
    #pragma unroll
    for (int yq=1; yq<FC1_NS; ++yq) {
        float4 v = src[((long)yq*NB + g)*256 + c4];
        s.x+=v.x; s.y+=v.y; s.z+=v.z; s.w+=v.w;
    }
    float4 bv = ((const float4*)bias)[c4];
    s.x = fmaxf(s.x+bv.x, 0.f); s.y = fmaxf(s.y+bv.y, 0.f);
    s.z = fmaxf(s.z+bv.z, 0.f); s.w = fmaxf(s.w+bv.w, 0.f);
    ((float4*)y)[(long)g*256 + c4] = s;
}

#define FC2_NS 8
#define FC2_KR 128   // 1024/FC2_NS rows per split
__global__ __launch_bounds__(256) void k_fc2(
    const float* __restrict__ y, const float* __restrict__ w,
    float* __restrict__ y2p)
{
    __shared__ float xS[4][FC2_KR];
    int b0 = blockIdx.x*4;
    int r0 = blockIdx.y*FC2_KR;
    int n = threadIdx.x;
    {
        int e1 = n + 256;
        xS[n>>7][n&127]   = y[(b0 + (n>>7))*1024  + r0 + (n&127)];
        xS[e1>>7][e1&127] = y[(b0 + (e1>>7))*1024 + r0 + (e1&127)];
    }
    __syncthreads();
    float acc[4] = {0.f, 0.f, 0.f, 0.f};
    for (int r=0; r<FC2_KR; ++r) {
        float wv = w[(long)(r0+r)*256 + n];
        acc[0]+=xS[0][r]*wv; acc[1]+=xS[1][r]*wv;
        acc[2]+=xS[2][r]*wv; acc[3]+=xS[3][r]*wv;
    }
    long base = ((long)blockIdx.y*NB + b0)*256;
    #pragma unroll
    for (int q=0; q<4; ++q) y2p[base + q*256 + n] = acc[q];
}

__global__ __launch_bounds__(256) void k_fc2_red(
    const float* __restrict__ y2p, const float* __restrict__ bias,
    float* __restrict__ y2)
{
    int p = blockIdx.x*256 + threadIdx.x;   // 65536 float4 slots
    int g = p >> 6, c4 = p & 63;
    const float4* src = (const float4*)y2p;
    float4 s = src[(long)g*64 + c4];
    #pragma unroll
    for (int yq=1; yq<FC2_NS; ++yq) {
        float4 v = src[((long)yq*NB + g)*64 + c4];
        s.x+=v.x; s.y+=v.y; s.z+=v.z; s.w+=v.w;
    }
    float4 bv = ((const float4*)bias)[c4];
    s.x = fmaxf(s.x+bv.x, 0.f); s.y = fmaxf(s.y+bv.y, 0.f);
    s.z = fmaxf(s.z+bv.z, 0.f); s.w = fmaxf(s.w+bv.w, 0.f);
    ((float4*)y2)[(long)g*64 + c4] = s;
}

__global__ __launch_bounds__(256) void k_out(
    const float* __restrict__ y2, const float* __restrict__ w,
    const float* __restrict__ bias, float* __restrict__ out)
{
    int b = blockIdx.x, n = threadIdx.x;
    float v = y2[b*256 + n] * w[n];
    #pragma unroll
    for (int off=32; off; off>>=1) v += __shfl_down(v, off, 64);
    __shared__ float red[4];
    if ((n & 63) == 0) red[n >> 6] = v;
    __syncthreads();
    if (n == 0) out[b] = red[0]+red[1]+red[2]+red[3] + bias[0];
}

// ---------------- launch ----------------

extern "C" void kernel_launch(void* const* d_in, const int* in_sizes, int n_in,
                              void* d_out, int out_size, void* d_ws, size_t ws_size,
                              hipStream_t stream) {
    const float* x      = (const float*)d_in[0];
    const int*   ei     = (const int*)  d_in[1];
    const int*   batch  = (const int*)  d_in[2];
    const int*   target = (const int*)  d_in[3];
    const float* w1a    = (const float*)d_in[4];
    const float* b1a    = (const float*)d_in[5];
    const float* w1b    = (const float*)d_in[6];
    const float* b1b    = (const float*)d_in[7];
    const float* wa     = (const float*)d_in[8];
    const float* ba     = (const float*)d_in[9];
    const float* wb     = (const float*)d_in[10];
    const float* bb     = (const float*)d_in[11];
    const float* gamma  = (const float*)d_in[12];
    const float* beta   = (const float*)d_in[13];
    const float* w_fcxd = (const float*)d_in[14];
    const float* b_fcxd = (const float*)d_in[15];
    const float* emb    = (const float*)d_in[16];
    const float* conv_w = (const float*)d_in[17];
    const float* conv_b = (const float*)d_in[18];
    const float* w_fcxt = (const float*)d_in[19];
    const float* b_fcxt = (const float*)d_in[20];
    const float* w_fc1  = (const float*)d_in[21];
    const float* b_fc1  = (const float*)d_in[22];
    const float* w_fc2  = (const float*)d_in[23];
    const float* b_fc2  = (const float*)d_in[24];
    const float* w_out  = (const float*)d_in[25];
    const float* b_out  = (const float*)d_in[26];

    float* ws      = (float*)d_ws;
    __half* tH     = (__half*)ws;                          // N*32 halfs = 1,048,576 float-slots
    float* z       = ws + 1048576;                         // N*32 floats
    unsigned int* pairs = (unsigned int*)(z + (size_t)N_NODES*DIM);  // E uints
    int*   csr     = (int*)(pairs + N_EDGES);              // E ints
    int*   rowptr  = csr + N_EDGES;                        // N+1 (+pad)
    int*   bktCnt  = rowptr + (N_NODES + 8);               // 256
    int*   bktBase = bktCnt + 256;                         // 257 (+pad)
    int*   bktCur  = bktBase + 264;                        // 256
    float* ss      = (float*)(bktCur + 256);               // 64
    float* hg      = ss + 64;                              // 32768
    float* cwT     = hg + (size_t)NB*DIM;                  // 256000 float-slots (fp16)
    float* cbuf    = cwT + 256000;                         // 3,964,928 floats (M/C0/xtp home)
    float* xc      = cbuf + (size_t)NB*FCX;                // 262144
    float* y1      = xc + (size_t)NB*256;                  // 1048576
    float* y2      = y1 + (size_t)NB*1024;                 // 262144
    float* part    = y2 + (size_t)NB*256;                  // 5 * 16384 floats
    __half* cwTh   = (__half*)cwT;
    __half* Gbuf   = (__half*)z;     // fp16 G [1024][26][256] = 3.41M float-slots:
                                     // spans z + pairs-head (pairs dead post-fillB;
                                     // ends before csr). Dead after k_xtg.
    float* Mbuf    = cbuf;                    // M [6656][128] = 851,968 floats
    float* C0buf   = cbuf + 851968;           // 128 floats
    float* xtp     = cbuf + 860160;           // [16][1024][128] = 2,097,152 floats
                                              // (total 2.96M < 3.96M cbuf region)
    float* y1p     = ws;             // fc1 partials [4][1024][1024] (dead tH/z/pairs)
    float* y2p     = ws + 4194304;   // fc2 partials [8][1024][256] (dead pairs/csr-head)

    // ---- CSR build: bucket sort (coalesced) + fused rowptr/scatter ----
    hipMemsetAsync(bktCnt, 0, 256*sizeof(int), stream);
    k_bhist<<<NBKT, 256, 0, stream>>>(ei, bktCnt);
    k_bscan<<<1, 256, 0, stream>>>(bktCnt, bktBase, bktCur);
    k_bucketA<<<NBKT, 256, 0, stream>>>(ei, bktCur, pairs);
    k_fillB<<<NBKT, 256, 0, stream>>>(bktBase, pairs, rowptr, csr);

    // ---- protein branch: conv folded into GEMM via M ----
    hipMemsetAsync(C0buf, 0, 128*sizeof(float), stream);
    k_cw_transpose<<<1000, 256, 0, stream>>>(conv_w, cwTh);
    k_mprep<<<VOCAB*32, 256, 0, stream>>>(emb, w_fcxt, conv_b, Mbuf, C0buf);
    k_convA<<<2*NB, 256, 0, stream>>>(target, cwTh, Gbuf);
    k_xtg<<<dim3(NB/XG_GB, XG_NS), 256, 0, stream>>>(Gbuf, Mbuf, xtp);
    k_xtg_red<<<(NB*DIM)/256, 256, 0, stream>>>(xtp, b_fcxt, C0buf, xc);

    // ---- GIN layers (per-layer part buffers; BN fused into transform) ----
    hipMemsetAsync(part, 0, 5*NSLICE*64*sizeof(float), stream);
    for (int l=0; l<5; ++l) {
        if (l == 0)
            k_l1_transform<<<N_NODES/256, 256, 0, stream>>>(x, w1a, tH);
        else
            k_transform<<<N_NODES/256, 256, 0, stream>>>(
                z, part + (size_t)(l-1)*NSLICE*64, gamma, beta, l-1,
                wa + (size_t)(l-1)*DIM*DIM, tH);
        const float* bi = (l==0) ? b1a : ba + (size_t)(l-1)*DIM;
        const float* wo = (l==0) ? w1b : wb + (size_t)(l-1)*DIM*DIM;
        const float* bo = (l==0) ? b1b : bb + (size_t)(l-1)*DIM;
        k_gather_mlp<<<N_NODES/32, 256, 0, stream>>>(
            rowptr, csr, tH, bi, wo, bo, z, part + (size_t)l*NSLICE*64);
    }
    k_scaleshift<<<1, 256, 0, stream>>>(part + (size_t)4*NSLICE*64, gamma, beta, 4, ss);

    // ---- pool + drug head ----
    hipMemsetAsync(hg, 0, (size_t)NB*DIM*sizeof(float), stream);
    k_pool<<<N_NODES/32, 256, 0, stream>>>(z, ss, batch, hg);
    k_xd<<<NB, 128, 0, stream>>>(hg, w_fcxd, b_fcxd, xc);

    // ---- joint head (K-split partials + reduce) ----
    k_fc1<<<dim3(NB/4, FC1_NS), 256, 0, stream>>>(xc, w_fc1, y1p);
    k_fc1_red<<<1024, 256, 0, stream>>>(y1p, b_fc1, y1);
    k_fc2<<<dim3(NB/4, FC2_NS), 256, 0, stream>>>(y1, w_fc2, y2p);
    k_fc2_red<<<256, 256, 0, stream>>>(y2p, b_fc2, y2);
    k_out<<<NB, 256, 0, stream>>>(y2, w_out, b_out, (float*)d_out);
}